// Round 1
// baseline (5060.986 us; speedup 1.0000x reference)
//
#include <hip/hip_runtime.h>
#include <math.h>

#define NN 16384
#define NE 131072
#define HDIM 128
#define NRBF 64
#define NL 4

__device__ __forceinline__ float siluf(float x){ return x / (1.0f + expf(-x)); }
__device__ __forceinline__ float cutofff(float d){
  return (d < 10.0f) ? 0.5f*(cosf(d*0.31415926535897932f)+1.0f) : 0.0f;
}

// block of 128 threads (2 waves)
__device__ __forceinline__ float blockReduceSum128(float v, float* sbuf){
  #pragma unroll
  for(int m=1;m<=32;m<<=1) v += __shfl_xor(v, m);
  __syncthreads();                       // protect sbuf reuse across calls
  if((threadIdx.x & 63)==0) sbuf[threadIdx.x>>6] = v;
  __syncthreads();
  return sbuf[0] + sbuf[1];
}

// ---------------- edge geometry ----------------
__global__ void k_edge_geom(const float* __restrict__ pos, const int* __restrict__ snd,
                            const int* __restrict__ rcv, float* __restrict__ ew,
                            float* __restrict__ evec){
  int e = blockIdx.x*blockDim.x + threadIdx.x;
  if(e >= NE) return;
  int s = snd[e], r = rcv[e];
  float dx = pos[r*3+0]-pos[s*3+0];
  float dy = pos[r*3+1]-pos[s*3+1];
  float dz = pos[r*3+2]-pos[s*3+2];
  const float eps = 1e-6f;
  float d = sqrtf((dx+eps)*(dx+eps)+(dy+eps)*(dy+eps)+(dz+eps)*(dz+eps));
  ew[e] = d;
  float mew = (s==r) ? 1.0f : d;
  mew = fmaxf(mew, 0.01f);
  float inv = 1.0f/mew;
  evec[e*3+0]=dx*inv; evec[e*3+1]=dy*inv; evec[e*3+2]=dz*inv;
}

// ---------------- RBF expansion ----------------
__global__ void k_edge_attr(const float* __restrict__ ew, float* __restrict__ attr){
  int idx = blockIdx.x*blockDim.x + threadIdx.x;
  if(idx >= NE*NRBF) return;
  int e = idx >> 6; int r = idx & 63;
  float d = ew[e];
  float start = expf(-10.0f);
  float mean  = start + (1.0f-start)*((float)r/63.0f);
  float tmp = (2.0f/64.0f)*(1.0f-start);
  float beta = 1.0f/(tmp*tmp);
  float c = cutofff(d);
  float t = expf(-0.5f*d) - mean;
  attr[idx] = c * expf(-beta*t*t);
}

// ---------------- neighbor embedding message + scatter ----------------
__global__ void k_nb_scatter(const float* __restrict__ attr, const float* __restrict__ ew,
                             const int* __restrict__ snd, const int* __restrict__ rcv,
                             const int* __restrict__ z, const float* __restrict__ embed2,
                             const float* __restrict__ Wd, const float* __restrict__ bd,
                             float* __restrict__ xnb){
  int e = blockIdx.x; int j = threadIdx.x;
  __shared__ float sa[NRBF];
  if(j < NRBF) sa[j] = attr[e*NRBF + j];
  __syncthreads();
  float acc = bd[j];
  #pragma unroll 8
  for(int r=0;r<NRBF;r++) acc += sa[r]*Wd[r*HDIM+j];
  float C = cutofff(ew[e]);
  int s = snd[e], rc = rcv[e];
  float m = embed2[z[s]*HDIM + j] * acc * C;
  atomicAdd(&xnb[rc*HDIM + j], m);
}

// ---------------- combine: x = concat(embed1[z], xnb) @ Wc + bc ----------------
__global__ void k_combine(const int* __restrict__ z, const float* __restrict__ embed1,
                          const float* __restrict__ xnb, const float* __restrict__ Wc,
                          const float* __restrict__ bc, float* __restrict__ x){
  int n = blockIdx.x; int j = threadIdx.x;
  __shared__ float sx[2*HDIM];
  sx[j]       = embed1[z[n]*HDIM + j];
  sx[HDIM+j]  = xnb[n*HDIM+j];
  __syncthreads();
  float acc = bc[j];
  #pragma unroll 8
  for(int i=0;i<2*HDIM;i++) acc += sx[i]*Wc[i*HDIM+j];
  x[n*HDIM+j] = acc;
}

// ---------------- per-layer node pre: LN, q,k,v, vec projections ----------------
__global__ void k_node_pre(const float* __restrict__ x, const float* __restrict__ vec,
                           const float* __restrict__ lng, const float* __restrict__ lnb,
                           const float* __restrict__ Wq, const float* __restrict__ bq,
                           const float* __restrict__ Wk, const float* __restrict__ bk,
                           const float* __restrict__ Wv, const float* __restrict__ bv,
                           const float* __restrict__ Wvec, const float* __restrict__ cscale,
                           float* __restrict__ q, float* __restrict__ kout,
                           float* __restrict__ v, float* __restrict__ vdot,
                           float* __restrict__ vec3, int l){
  int n = blockIdx.x; int j = threadIdx.x;
  __shared__ float sxn[HDIM];
  __shared__ float svn[3][HDIM];
  __shared__ float sred[2];
  float xv = x[n*HDIM+j];
  float m  = blockReduceSum128(xv, sred) * (1.0f/HDIM);
  float d0 = xv - m;
  float var = blockReduceSum128(d0*d0, sred) * (1.0f/HDIM);
  float xn_ = d0 * rsqrtf(var + 1e-6f) * lng[l*HDIM+j] + lnb[l*HDIM+j];
  sxn[j] = xn_;
  // coors norm
  float v0 = vec[(n*3+0)*HDIM+j], v1 = vec[(n*3+1)*HDIM+j], v2 = vec[(n*3+2)*HDIM+j];
  float ss = v0*v0+v1*v1+v2*v2;
  float inv = rsqrtf(fmaxf(ss, 1e-8f)) * cscale[l];
  svn[0][j]=v0*inv; svn[1][j]=v1*inv; svn[2][j]=v2*inv;
  __syncthreads();

  const float* Wql = Wq + (size_t)l*HDIM*HDIM;
  const float* Wkl = Wk + (size_t)l*HDIM*HDIM;
  float accq = bq[l*HDIM+j];
  float acck = bk[l*HDIM+j];
  #pragma unroll 8
  for(int i=0;i<HDIM;i++){
    float xi = sxn[i];
    accq += xi*Wql[i*HDIM+j];
    acck += xi*Wkl[i*HDIM+j];
  }
  // per-head l2 normalize (16 lanes per head)
  float nq = accq*accq, nk = acck*acck;
  #pragma unroll
  for(int mm=1;mm<=8;mm<<=1){ nq += __shfl_xor(nq, mm); nk += __shfl_xor(nk, mm); }
  accq = accq / (sqrtf(nq)+1e-6f);
  acck = acck / (sqrtf(nk)+1e-6f);
  q[n*HDIM+j]    = accq;
  kout[n*HDIM+j] = acck;

  // v: 384 outputs, 3 per thread
  const float* Wvl = Wv + (size_t)l*HDIM*384;
  float a0=bv[l*384+j], a1=bv[l*384+128+j], a2=bv[l*384+256+j];
  #pragma unroll 8
  for(int i=0;i<HDIM;i++){
    float xi=sxn[i]; const float* w=Wvl+i*384;
    a0+=xi*w[j]; a1+=xi*w[j+128]; a2+=xi*w[j+256];
  }
  v[(size_t)n*384+j]=a0; v[(size_t)n*384+j+128]=a1; v[(size_t)n*384+j+256]=a2;

  // vec projections: vp = vn @ Wvec; vec_dot = sum_sp vp1*vp2; store vp3
  const float* Wvecl = Wvec + (size_t)l*HDIM*384;
  float vd = 0.0f;
  for(int sp=0;sp<3;sp++){
    float p1=0.0f, p2=0.0f, p3=0.0f;
    #pragma unroll 8
    for(int i=0;i<HDIM;i++){
      float vi=svn[sp][i]; const float* w=Wvecl+i*384;
      p1+=vi*w[j]; p2+=vi*w[j+128]; p3+=vi*w[j+256];
    }
    vd += p1*p2;
    vec3[((size_t)n*3+sp)*HDIM+j] = p3;
  }
  vdot[n*HDIM+j] = vd;
}

// ---------------- per-layer edge attention + scatter ----------------
__global__ void k_edge_attn(const float* __restrict__ attr, const float* __restrict__ ew,
                            const float* __restrict__ evec, const int* __restrict__ snd,
                            const int* __restrict__ rcv, const float* __restrict__ q,
                            const float* __restrict__ k, const float* __restrict__ v,
                            const float* __restrict__ vec, const float* __restrict__ Wdk,
                            const float* __restrict__ bdk, const float* __restrict__ Wdv,
                            const float* __restrict__ bdv, float* __restrict__ xagg,
                            float* __restrict__ vecagg, int l){
  int e = blockIdx.x; int j = threadIdx.x;
  __shared__ float sa[NRBF];
  if(j<NRBF) sa[j]=attr[e*NRBF+j];
  __syncthreads();
  int s = snd[e], r = rcv[e];

  const float* Wdkl = Wdk + (size_t)l*NRBF*HDIM;
  float accdk = bdk[l*HDIM+j];
  #pragma unroll 8
  for(int t=0;t<NRBF;t++) accdk += sa[t]*Wdkl[t*HDIM+j];
  float dkv = siluf(accdk);

  float prod = q[r*HDIM+j]*k[s*HDIM+j]*dkv;
  #pragma unroll
  for(int mm=1;mm<=8;mm<<=1) prod += __shfl_xor(prod, mm);
  float C = cutofff(ew[e]);
  float attn = siluf(prod)*C;

  int h = j>>4, dd = j&15;
  int c0 = h*48+dd, c1 = c0+16, c2 = c0+32;
  const float* Wdvl = Wdv + (size_t)l*NRBF*384;
  float b0=bdv[l*384+c0], b1=bdv[l*384+c1], b2=bdv[l*384+c2];
  #pragma unroll 8
  for(int t=0;t<NRBF;t++){
    float a=sa[t]; const float* w=Wdvl+t*384;
    b0+=a*w[c0]; b1+=a*w[c1]; b2+=a*w[c2];
  }
  const float* vs = v + (size_t)s*384;
  float xh = vs[c0]*siluf(b0)*attn;
  float s1 = vs[c1]*siluf(b1);
  float s2 = vs[c2]*siluf(b2);
  atomicAdd(&xagg[r*HDIM+j], xh);
  float ev0=evec[e*3+0], ev1=evec[e*3+1], ev2=evec[e*3+2];
  atomicAdd(&vecagg[((size_t)r*3+0)*HDIM+j], vec[((size_t)s*3+0)*HDIM+j]*s1 + s2*ev0);
  atomicAdd(&vecagg[((size_t)r*3+1)*HDIM+j], vec[((size_t)s*3+1)*HDIM+j]*s1 + s2*ev1);
  atomicAdd(&vecagg[((size_t)r*3+2)*HDIM+j], vec[((size_t)s*3+2)*HDIM+j]*s1 + s2*ev2);
}

// ---------------- per-layer node update ----------------
__global__ void k_node_update(const float* __restrict__ xagg, const float* __restrict__ vdot,
                              const float* __restrict__ vec3, const float* __restrict__ vecagg,
                              const float* __restrict__ Wo, const float* __restrict__ bo,
                              float* __restrict__ x, float* __restrict__ vec, int l){
  int n=blockIdx.x; int j=threadIdx.x;
  __shared__ float sA[HDIM];
  sA[j] = xagg[n*HDIM+j];
  __syncthreads();
  const float* Wol = Wo + (size_t)l*HDIM*384;
  float o1=bo[l*384+j], o2=bo[l*384+128+j], o3=bo[l*384+256+j];
  #pragma unroll 8
  for(int i=0;i<HDIM;i++){
    float a=sA[i]; const float* w=Wol+i*384;
    o1+=a*w[j]; o2+=a*w[j+128]; o3+=a*w[j+256];
  }
  x[n*HDIM+j] += vdot[n*HDIM+j]*o2 + o3;
  for(int sp=0;sp<3;sp++){
    size_t idx=((size_t)n*3+sp)*HDIM+j;
    vec[idx] += vec3[idx]*o1 + vecagg[idx];
  }
}

// ---------------- final layernorm + output ----------------
__global__ void k_final(const float* __restrict__ x, const float* __restrict__ vec,
                        const float* __restrict__ g, const float* __restrict__ b,
                        float* __restrict__ out){
  int n=blockIdx.x; int j=threadIdx.x;
  __shared__ float sred[2];
  float xv=x[n*HDIM+j];
  float m = blockReduceSum128(xv,sred)*(1.0f/HDIM);
  float d0=xv-m;
  float var = blockReduceSum128(d0*d0,sred)*(1.0f/HDIM);
  out[n*HDIM+j] = d0*rsqrtf(var+1e-6f)*g[j]+b[j];
  float* ov = out + (size_t)NN*HDIM;
  for(int sp=0;sp<3;sp++){
    size_t idx=((size_t)n*3+sp)*HDIM+j;
    ov[idx]=vec[idx];
  }
}

extern "C" void kernel_launch(void* const* d_in, const int* in_sizes, int n_in,
                              void* d_out, int out_size, void* d_ws, size_t ws_size,
                              hipStream_t stream){
  const int*   z      = (const int*)  d_in[0];
  const float* pos    = (const float*)d_in[1];
  const int*   snd    = (const int*)  d_in[2];
  const int*   rcv    = (const int*)  d_in[3];
  const float* embed1 = (const float*)d_in[4];
  const float* embed2 = (const float*)d_in[5];
  const float* nbWd   = (const float*)d_in[6];
  const float* nbbd   = (const float*)d_in[7];
  const float* nbWc   = (const float*)d_in[8];
  const float* nbbc   = (const float*)d_in[9];
  const float* lng    = (const float*)d_in[10];
  const float* lnb    = (const float*)d_in[11];
  const float* Wq     = (const float*)d_in[12];
  const float* bq     = (const float*)d_in[13];
  const float* Wk     = (const float*)d_in[14];
  const float* bk     = (const float*)d_in[15];
  const float* Wv     = (const float*)d_in[16];
  const float* bv     = (const float*)d_in[17];
  const float* Wvec   = (const float*)d_in[18];
  const float* Wdk    = (const float*)d_in[19];
  const float* bdk    = (const float*)d_in[20];
  const float* Wdv    = (const float*)d_in[21];
  const float* bdv    = (const float*)d_in[22];
  const float* Wo     = (const float*)d_in[23];
  const float* bo     = (const float*)d_in[24];
  const float* cscale = (const float*)d_in[25];
  const float* lnfg   = (const float*)d_in[26];
  const float* lnfb   = (const float*)d_in[27];
  float* out = (float*)d_out;

  float* ws = (float*)d_ws;
  float* ew    = ws;  ws += NE;
  float* evec  = ws;  ws += 3*NE;
  float* attr  = ws;  ws += (size_t)NE*NRBF;
  float* x     = ws;  ws += (size_t)NN*HDIM;
  float* xagg  = ws;  ws += (size_t)NN*HDIM;    // doubles as x_nb
  float* q     = ws;  ws += (size_t)NN*HDIM;
  float* kbuf  = ws;  ws += (size_t)NN*HDIM;
  float* v     = ws;  ws += (size_t)NN*384;
  float* vdot  = ws;  ws += (size_t)NN*HDIM;
  float* vec3  = ws;  ws += (size_t)NN*384;
  float* vecagg= ws;  ws += (size_t)NN*384;
  float* vec   = ws;  ws += (size_t)NN*384;

  k_edge_geom<<<(NE+255)/256,256,0,stream>>>(pos,snd,rcv,ew,evec);
  k_edge_attr<<<(NE*NRBF+255)/256,256,0,stream>>>(ew,attr);
  hipMemsetAsync(xagg,0,(size_t)NN*HDIM*4,stream);
  k_nb_scatter<<<NE,HDIM,0,stream>>>(attr,ew,snd,rcv,z,embed2,nbWd,nbbd,xagg);
  k_combine<<<NN,HDIM,0,stream>>>(z,embed1,xagg,nbWc,nbbc,x);
  hipMemsetAsync(vec,0,(size_t)NN*384*4,stream);
  for(int l=0;l<NL;l++){
    k_node_pre<<<NN,HDIM,0,stream>>>(x,vec,lng,lnb,Wq,bq,Wk,bk,Wv,bv,Wvec,cscale,
                                     q,kbuf,v,vdot,vec3,l);
    hipMemsetAsync(xagg,0,(size_t)NN*HDIM*4,stream);
    hipMemsetAsync(vecagg,0,(size_t)NN*384*4,stream);
    k_edge_attn<<<NE,HDIM,0,stream>>>(attr,ew,evec,snd,rcv,q,kbuf,v,vec,
                                      Wdk,bdk,Wdv,bdv,xagg,vecagg,l);
    k_node_update<<<NN,HDIM,0,stream>>>(xagg,vdot,vec3,vecagg,Wo,bo,x,vec,l);
  }
  k_final<<<NN,HDIM,0,stream>>>(x,vec,lnfg,lnfb,out);
}

// Round 3
// 2374.226 us; speedup vs baseline: 2.1316x; 2.1316x over previous
//
#include <hip/hip_runtime.h>
#include <math.h>

#define NN 16384
#define NE 131072
#define HDIM 128
#define NRBF 64
#define NL 4
#define EB 64

typedef __attribute__((ext_vector_type(8))) short short8;
typedef __attribute__((ext_vector_type(4))) float f32x4;

__device__ __forceinline__ float siluf(float x){ return x / (1.0f + expf(-x)); }
__device__ __forceinline__ float cutofff(float d){
  return (d < 10.0f) ? 0.5f*(cosf(d*0.31415926535897932f)+1.0f) : 0.0f;
}
__device__ __forceinline__ unsigned short f2bf(float f){
  union{float f; unsigned u;} v; v.f = f;
  unsigned r = v.u + 0x7FFF + ((v.u>>16)&1);
  return (unsigned short)(r>>16);
}
__device__ __forceinline__ float bf2f(unsigned short b){
  union{unsigned u; float f;} v; v.u = ((unsigned)b)<<16;
  return v.f;
}

// ---------------- edge geometry ----------------
__global__ void k_edge_geom(const float* __restrict__ pos, const int* __restrict__ snd,
                            const int* __restrict__ rcv, float* __restrict__ ew,
                            float* __restrict__ evec){
  int e = blockIdx.x*blockDim.x + threadIdx.x;
  if(e >= NE) return;
  int s = snd[e], r = rcv[e];
  float dx = pos[r*3+0]-pos[s*3+0];
  float dy = pos[r*3+1]-pos[s*3+1];
  float dz = pos[r*3+2]-pos[s*3+2];
  const float eps = 1e-6f;
  float d = sqrtf((dx+eps)*(dx+eps)+(dy+eps)*(dy+eps)+(dz+eps)*(dz+eps));
  ew[e] = d;
  float mew = (s==r) ? 1.0f : d;
  mew = fmaxf(mew, 0.01f);
  float inv = 1.0f/mew;
  evec[e*3+0]=dx*inv; evec[e*3+1]=dy*inv; evec[e*3+2]=dz*inv;
}

// ---------------- RBF expansion (bf16 only) ----------------
__global__ void k_edge_attr(const float* __restrict__ ew, unsigned short* __restrict__ abf){
  int idx = blockIdx.x*blockDim.x + threadIdx.x;
  if(idx >= NE*NRBF) return;
  int e = idx >> 6; int r = idx & 63;
  float d = ew[e];
  float start = expf(-10.0f);
  float mean  = start + (1.0f-start)*((float)r/63.0f);
  float tmp = (2.0f/64.0f)*(1.0f-start);
  float beta = 1.0f/(tmp*tmp);
  float c = cutofff(d);
  float t = expf(-0.5f*d) - mean;
  abf[idx] = f2bf(c * expf(-beta*t*t));
}

// ---------------- neighbor embedding, 64 edges/block ----------------
__global__ __launch_bounds__(256) void k_nb_scatter_b(
    const unsigned short* __restrict__ abf, const float* __restrict__ ew,
    const int* __restrict__ snd, const int* __restrict__ rcv,
    const int* __restrict__ z, const float* __restrict__ embed2,
    const float* __restrict__ Wd, const float* __restrict__ bd,
    float* __restrict__ xnb){
  __shared__ float sw[NRBF*HDIM];     // 32 KB
  __shared__ float sattr[EB][NRBF];   // 16 KB
  int t = threadIdx.x; int e0 = blockIdx.x*EB;
  #pragma unroll
  for(int i=0;i<32;i++) sw[i*256+t] = Wd[i*256+t];
  #pragma unroll
  for(int i=0;i<16;i++){
    int idx = i*256+t; int el = idx>>6, rb = idx&63;
    sattr[el][rb] = bf2f(abf[(size_t)(e0+el)*NRBF + rb]);
  }
  __syncthreads();
  int j = t&127, g = t>>7;
  float bdj = bd[j];
  for(int p=0;p<4;p++){
    int eb = g*32 + p*8;
    float acc[8];
    #pragma unroll
    for(int r=0;r<8;r++) acc[r] = bdj;
    for(int rb=0;rb<NRBF;rb++){
      float wv = sw[rb*HDIM + j];
      #pragma unroll
      for(int r=0;r<8;r++) acc[r] += sattr[eb+r][rb]*wv;
    }
    #pragma unroll
    for(int r=0;r<8;r++){
      int e = e0+eb+r;
      float C = cutofff(ew[e]);
      int s = snd[e], rc = rcv[e];
      float m = embed2[(size_t)z[s]*HDIM + j]*acc[r]*C;
      atomicAdd(&xnb[(size_t)rc*HDIM + j], m);
    }
  }
}

// ---------------- combine, 16 nodes/block ----------------
__global__ __launch_bounds__(256) void k_combine_b(
    const int* __restrict__ z, const float* __restrict__ embed1,
    const float* __restrict__ xnb, const float* __restrict__ Wc,
    const float* __restrict__ bc, float* __restrict__ x){
  __shared__ float sx[16][2*HDIM];   // 16 KB
  int t = threadIdx.x; int n0 = blockIdx.x*16;
  #pragma unroll
  for(int i=0;i<16;i++){
    int idx = i*256+t; int nn = idx>>8, c = idx&255;
    int n = n0+nn;
    sx[nn][c] = (c<128) ? embed1[(size_t)z[n]*HDIM + c]
                        : xnb[(size_t)n*HDIM + (c-128)];
  }
  __syncthreads();
  int j = t&127, g = t>>7;
  float bcj = bc[j];
  float acc[8];
  #pragma unroll
  for(int r=0;r<8;r++) acc[r]=bcj;
  for(int i=0;i<2*HDIM;i++){
    float wv = Wc[i*HDIM+j];
    #pragma unroll
    for(int r=0;r<8;r++) acc[r] += sx[2*r+g][i]*wv;
  }
  #pragma unroll
  for(int r=0;r<8;r++) x[(size_t)(n0+2*r+g)*HDIM+j] = acc[r];
}

// ---------------- per-layer weight prep ----------------
__global__ void k_wcvt(const float* __restrict__ Wdk, const float* __restrict__ Wdv,
                       unsigned short* __restrict__ wbT, int l){
  int o = blockIdx.x*blockDim.x + threadIdx.x;
  if(o >= 512*64) return;
  int n = o >> 6, kk = o & 63;
  float v = (n < 128) ? Wdk[(size_t)l*NRBF*HDIM + kk*HDIM + n]
                      : Wdv[(size_t)l*NRBF*384 + kk*384 + (n-128)];
  wbT[o] = f2bf(v);
}
__global__ void k_bcvt(const float* __restrict__ bdk, const float* __restrict__ bdv,
                       float* __restrict__ bias, int l){
  int c = threadIdx.x + blockIdx.x*blockDim.x;
  if(c >= 512) return;
  bias[c] = (c < 128) ? bdk[l*HDIM + c] : bdv[l*384 + (c-128)];
}

// ---------------- fused dk/dv GEMM + attention + scatter, 64 edges/block ------
__global__ __launch_bounds__(256) void k_edge_fused(
    const unsigned short* __restrict__ abf, const unsigned short* __restrict__ wbT,
    const float* __restrict__ bias, const float* __restrict__ ew,
    const float* __restrict__ evec, const int* __restrict__ snd,
    const int* __restrict__ rcv, const float* __restrict__ q,
    const float* __restrict__ k, const float* __restrict__ v,
    const float* __restrict__ vec, float* __restrict__ xagg,
    float* __restrict__ vecagg){
  __shared__ __align__(16) unsigned short BD[512*64];  // 64 KB: B panel, then dkv
  __shared__ float sbias[512];
  __shared__ float sew[EB];
  __shared__ int   ssnd[EB];
  __shared__ int   srcv[EB];
  __shared__ float sev[EB*3];
  int t = threadIdx.x;
  int e0 = blockIdx.x*EB;
  if(t < EB){ sew[t]=ew[e0+t]; ssnd[t]=snd[e0+t]; srcv[t]=rcv[e0+t]; }
  if(t < EB*3) sev[t] = evec[e0*3 + t];
  sbias[t] = bias[t]; sbias[256+t] = bias[256+t];
  // stage B [512][64] bf16, xor-swizzled 16B chunks
  #pragma unroll
  for(int i=0;i<16;i++){
    int idx = i*256+t; int n = idx>>3, kc = idx&7;
    short8 val = *(const short8*)(wbT + n*64 + kc*8);
    *(short8*)((char*)BD + n*128 + ((kc ^ (n&7))<<4)) = val;
  }
  int w = t>>6, l = t&63, lr = l&15, lg = l>>4;
  const unsigned short* arow = abf + (size_t)(e0 + w*16 + lr)*NRBF;
  short8 a0 = *(const short8*)(arow + lg*8);
  short8 a1 = *(const short8*)(arow + 32 + lg*8);
  __syncthreads();
  unsigned pk[64];
  #pragma unroll
  for(int nt=0; nt<32; nt++){
    int n = nt*16 + lr;
    const char* bp = (const char*)BD + n*128;
    short8 b0 = *(const short8*)(bp + (((lg  ) ^ (n&7))<<4));
    short8 b1 = *(const short8*)(bp + (((4+lg) ^ (n&7))<<4));
    f32x4 acc = {0.f,0.f,0.f,0.f};
    acc = __builtin_amdgcn_mfma_f32_16x16x32_bf16(a0,b0,acc,0,0,0);
    acc = __builtin_amdgcn_mfma_f32_16x16x32_bf16(a1,b1,acc,0,0,0);
    float bs = sbias[n];
    pk[nt*2+0] = ((unsigned)f2bf(siluf(acc[1]+bs))<<16) | f2bf(siluf(acc[0]+bs));
    pk[nt*2+1] = ((unsigned)f2bf(siluf(acc[3]+bs))<<16) | f2bf(siluf(acc[2]+bs));
  }
  __syncthreads();    // all B reads complete before overwrite
  // write dkv[el][512] bf16 into BD, row-swizzled
  #pragma unroll
  for(int nt=0; nt<32; nt++){
    int n = nt*16+lr;
    #pragma unroll
    for(int rr=0;rr<4;rr++){
      int el = w*16 + lg*4 + rr;
      unsigned short val = (unsigned short)(pk[nt*2 + (rr>>1)] >> ((rr&1)*16));
      *(unsigned short*)((char*)BD + el*1024 + ((n*2) ^ ((el&7)<<4))) = val;
    }
  }
  __syncthreads();
  // phase 3: per wave, 16 edges x 2 j-halves
  for(int it=0; it<32; it++){
    int el = w*16 + (it>>1);
    int jj = (it&1)*64 + l;
    int s = ssnd[el], r = srcv[el];
    const char* dbase = (const char*)BD + el*1024;
    int sw_ = (el&7)<<4;
    float dkj = bf2f(*(const unsigned short*)(dbase + ((jj*2)^sw_)));
    float prod = q[(size_t)r*HDIM+jj]*k[(size_t)s*HDIM+jj]*dkj;
    #pragma unroll
    for(int mm=1;mm<=8;mm<<=1) prod += __shfl_xor(prod, mm);
    float C = cutofff(sew[el]);
    float attn = siluf(prod)*C;
    int h = jj>>4, dd = jj&15;
    int c0 = h*48+dd, c1 = c0+16, c2 = c0+32;
    float b0 = bf2f(*(const unsigned short*)(dbase + (((128+c0)*2)^sw_)));
    float b1 = bf2f(*(const unsigned short*)(dbase + (((128+c1)*2)^sw_)));
    float b2 = bf2f(*(const unsigned short*)(dbase + (((128+c2)*2)^sw_)));
    const float* vs = v + (size_t)s*384;
    float xh = vs[c0]*b0*attn;
    float s1 = vs[c1]*b1;
    float s2 = vs[c2]*b2;
    atomicAdd(&xagg[(size_t)r*HDIM+jj], xh);
    float ev0=sev[el*3+0], ev1=sev[el*3+1], ev2=sev[el*3+2];
    atomicAdd(&vecagg[((size_t)r*3+0)*HDIM+jj], vec[((size_t)s*3+0)*HDIM+jj]*s1 + s2*ev0);
    atomicAdd(&vecagg[((size_t)r*3+1)*HDIM+jj], vec[((size_t)s*3+1)*HDIM+jj]*s1 + s2*ev1);
    atomicAdd(&vecagg[((size_t)r*3+2)*HDIM+jj], vec[((size_t)s*3+2)*HDIM+jj]*s1 + s2*ev2);
  }
}

// ---------------- per-layer node pre, 16 nodes/block ----------------
__global__ __launch_bounds__(256) void k_node_pre_b(
    const float* __restrict__ x, const float* __restrict__ vec,
    const float* __restrict__ lng, const float* __restrict__ lnb,
    const float* __restrict__ Wq, const float* __restrict__ bq,
    const float* __restrict__ Wk, const float* __restrict__ bk,
    const float* __restrict__ Wv, const float* __restrict__ bv,
    const float* __restrict__ Wvec, const float* __restrict__ cscale,
    float* __restrict__ q, float* __restrict__ kout,
    float* __restrict__ v, float* __restrict__ vdot,
    float* __restrict__ vec3, int l){
  __shared__ float sxn[16][HDIM];        // 8 KB
  __shared__ float svn[3][16][HDIM];     // 24 KB
  int t = threadIdx.x; int n0 = blockIdx.x*16;
  int w = t>>6, lane = t&63;
  float cs = cscale[l];
  float g0 = lng[l*HDIM+lane], g1 = lng[l*HDIM+64+lane];
  float be0 = lnb[l*HDIM+lane], be1 = lnb[l*HDIM+64+lane];
  for(int rr=0; rr<4; rr++){
    int nn = w*4+rr; int n = n0+nn;
    float x0 = x[(size_t)n*HDIM+lane], x1 = x[(size_t)n*HDIM+64+lane];
    float sum = x0+x1;
    #pragma unroll
    for(int m=1;m<=32;m<<=1) sum += __shfl_xor(sum,m);
    float mean = sum*(1.f/128.f);
    float d0 = x0-mean, d1 = x1-mean;
    float vs = d0*d0+d1*d1;
    #pragma unroll
    for(int m=1;m<=32;m<<=1) vs += __shfl_xor(vs,m);
    float rstd = rsqrtf(vs*(1.f/128.f)+1e-6f);
    sxn[nn][lane]    = d0*rstd*g0 + be0;
    sxn[nn][64+lane] = d1*rstd*g1 + be1;
    float va0 = vec[((size_t)n*3+0)*HDIM+lane], vb0 = vec[((size_t)n*3+0)*HDIM+64+lane];
    float va1 = vec[((size_t)n*3+1)*HDIM+lane], vb1 = vec[((size_t)n*3+1)*HDIM+64+lane];
    float va2 = vec[((size_t)n*3+2)*HDIM+lane], vb2 = vec[((size_t)n*3+2)*HDIM+64+lane];
    float iA = rsqrtf(fmaxf(va0*va0+va1*va1+va2*va2,1e-8f))*cs;
    float iB = rsqrtf(fmaxf(vb0*vb0+vb1*vb1+vb2*vb2,1e-8f))*cs;
    svn[0][nn][lane]=va0*iA; svn[0][nn][64+lane]=vb0*iB;
    svn[1][nn][lane]=va1*iA; svn[1][nn][64+lane]=vb1*iB;
    svn[2][nn][lane]=va2*iA; svn[2][nn][64+lane]=vb2*iB;
  }
  __syncthreads();
  int j = t&127, g = t>>7;
  const float* Wql = Wq + (size_t)l*HDIM*HDIM;
  const float* Wkl = Wk + (size_t)l*HDIM*HDIM;
  const float* Wvl = Wv + (size_t)l*HDIM*384;
  float aq[8], ak[8], av0[8], av1[8], av2[8];
  {
    float bqj = bq[l*HDIM+j], bkj = bk[l*HDIM+j];
    float b0 = bv[l*384+j], b1 = bv[l*384+128+j], b2 = bv[l*384+256+j];
    #pragma unroll
    for(int r=0;r<8;r++){ aq[r]=bqj; ak[r]=bkj; av0[r]=b0; av1[r]=b1; av2[r]=b2; }
  }
  for(int i=0;i<HDIM;i++){
    float wq = Wql[i*HDIM+j], wk = Wkl[i*HDIM+j];
    float w0 = Wvl[i*384+j], w1 = Wvl[i*384+128+j], w2 = Wvl[i*384+256+j];
    #pragma unroll
    for(int r=0;r<8;r++){
      float xi = sxn[2*r+g][i];
      aq[r]+=xi*wq; ak[r]+=xi*wk; av0[r]+=xi*w0; av1[r]+=xi*w1; av2[r]+=xi*w2;
    }
  }
  #pragma unroll
  for(int r=0;r<8;r++){
    float nq = aq[r]*aq[r], nk = ak[r]*ak[r];
    #pragma unroll
    for(int mm=1;mm<=8;mm<<=1){ nq += __shfl_xor(nq,mm); nk += __shfl_xor(nk,mm); }
    float qv = aq[r]/(sqrtf(nq)+1e-6f);
    float kv = ak[r]/(sqrtf(nk)+1e-6f);
    int n = n0+2*r+g;
    q[(size_t)n*HDIM+j]=qv; kout[(size_t)n*HDIM+j]=kv;
    v[(size_t)n*384+j]=av0[r]; v[(size_t)n*384+128+j]=av1[r]; v[(size_t)n*384+256+j]=av2[r];
  }
  const float* Wvecl = Wvec + (size_t)l*HDIM*384;
  float vd[8];
  #pragma unroll
  for(int r=0;r<8;r++) vd[r]=0.f;
  for(int sp=0;sp<3;sp++){
    float p1[8],p2[8],p3[8];
    #pragma unroll
    for(int r=0;r<8;r++){ p1[r]=0.f;p2[r]=0.f;p3[r]=0.f; }
    for(int i=0;i<HDIM;i++){
      float w0=Wvecl[i*384+j], w1=Wvecl[i*384+128+j], w2=Wvecl[i*384+256+j];
      #pragma unroll
      for(int r=0;r<8;r++){
        float vi = svn[sp][2*r+g][i];
        p1[r]+=vi*w0; p2[r]+=vi*w1; p3[r]+=vi*w2;
      }
    }
    #pragma unroll
    for(int r=0;r<8;r++){
      vd[r] += p1[r]*p2[r];
      vec3[((size_t)(n0+2*r+g)*3+sp)*HDIM+j] = p3[r];
    }
  }
  #pragma unroll
  for(int r=0;r<8;r++) vdot[(size_t)(n0+2*r+g)*HDIM+j] = vd[r];
}

// ---------------- per-layer node update, 16 nodes/block ----------------
__global__ __launch_bounds__(256) void k_node_update_b(
    const float* __restrict__ xagg, const float* __restrict__ vdot,
    const float* __restrict__ vec3, const float* __restrict__ vecagg,
    const float* __restrict__ Wo, const float* __restrict__ bo,
    float* __restrict__ x, float* __restrict__ vec, int l){
  __shared__ float sA[16][HDIM];
  int t = threadIdx.x; int n0 = blockIdx.x*16;
  #pragma unroll
  for(int i=0;i<8;i++){
    int idx = i*256+t; int nn = idx>>7, j2 = idx&127;
    sA[nn][j2] = xagg[(size_t)(n0+nn)*HDIM + j2];
  }
  __syncthreads();
  int j = t&127, g = t>>7;
  const float* Wol = Wo + (size_t)l*HDIM*384;
  float o1[8],o2[8],o3[8];
  {
    float b1=bo[l*384+j], b2=bo[l*384+128+j], b3=bo[l*384+256+j];
    #pragma unroll
    for(int r=0;r<8;r++){ o1[r]=b1;o2[r]=b2;o3[r]=b3; }
  }
  for(int i=0;i<HDIM;i++){
    float w0=Wol[i*384+j], w1=Wol[i*384+128+j], w2=Wol[i*384+256+j];
    #pragma unroll
    for(int r=0;r<8;r++){
      float a = sA[2*r+g][i];
      o1[r]+=a*w0; o2[r]+=a*w1; o3[r]+=a*w2;
    }
  }
  #pragma unroll
  for(int r=0;r<8;r++){
    int n = n0+2*r+g;
    x[(size_t)n*HDIM+j] += vdot[(size_t)n*HDIM+j]*o2[r] + o3[r];
    #pragma unroll
    for(int sp=0;sp<3;sp++){
      size_t idx=((size_t)n*3+sp)*HDIM+j;
      vec[idx] += vec3[idx]*o1[r] + vecagg[idx];
    }
  }
}

// ---------------- final layernorm + output ----------------
__global__ void k_final(const float* __restrict__ x, const float* __restrict__ vec,
                        const float* __restrict__ g, const float* __restrict__ b,
                        float* __restrict__ out){
  int n=blockIdx.x; int t=threadIdx.x;   // 64 threads
  float x0=x[(size_t)n*HDIM+t], x1=x[(size_t)n*HDIM+64+t];
  float sum=x0+x1;
  #pragma unroll
  for(int m=1;m<=32;m<<=1) sum += __shfl_xor(sum,m);
  float mean=sum*(1.f/128.f);
  float d0=x0-mean, d1=x1-mean;
  float vs=d0*d0+d1*d1;
  #pragma unroll
  for(int m=1;m<=32;m<<=1) vs += __shfl_xor(vs,m);
  float rstd=rsqrtf(vs*(1.f/128.f)+1e-6f);
  out[(size_t)n*HDIM+t]    = d0*rstd*g[t]+b[t];
  out[(size_t)n*HDIM+64+t] = d1*rstd*g[64+t]+b[64+t];
  float* ov = out + (size_t)NN*HDIM;
  for(int sp=0;sp<3;sp++){
    size_t idx=((size_t)n*3+sp)*HDIM;
    ov[idx+t]    = vec[idx+t];
    ov[idx+64+t] = vec[idx+64+t];
  }
}

extern "C" void kernel_launch(void* const* d_in, const int* in_sizes, int n_in,
                              void* d_out, int out_size, void* d_ws, size_t ws_size,
                              hipStream_t stream){
  const int*   z      = (const int*)  d_in[0];
  const float* pos    = (const float*)d_in[1];
  const int*   snd    = (const int*)  d_in[2];
  const int*   rcv    = (const int*)  d_in[3];
  const float* embed1 = (const float*)d_in[4];
  const float* embed2 = (const float*)d_in[5];
  const float* nbWd   = (const float*)d_in[6];
  const float* nbbd   = (const float*)d_in[7];
  const float* nbWc   = (const float*)d_in[8];
  const float* nbbc   = (const float*)d_in[9];
  const float* lng    = (const float*)d_in[10];
  const float* lnb    = (const float*)d_in[11];
  const float* Wq     = (const float*)d_in[12];
  const float* bq     = (const float*)d_in[13];
  const float* Wk     = (const float*)d_in[14];
  const float* bk     = (const float*)d_in[15];
  const float* Wv     = (const float*)d_in[16];
  const float* bv     = (const float*)d_in[17];
  const float* Wvec   = (const float*)d_in[18];
  const float* Wdk    = (const float*)d_in[19];
  const float* bdk    = (const float*)d_in[20];
  const float* Wdv    = (const float*)d_in[21];
  const float* bdv    = (const float*)d_in[22];
  const float* Wo     = (const float*)d_in[23];
  const float* bo     = (const float*)d_in[24];
  const float* cscale = (const float*)d_in[25];
  const float* lnfg   = (const float*)d_in[26];
  const float* lnfb   = (const float*)d_in[27];
  float* out = (float*)d_out;

  float* ws = (float*)d_ws;
  float* ew    = ws;  ws += NE;
  float* evec  = ws;  ws += 3*NE;
  float* x     = ws;  ws += (size_t)NN*HDIM;
  float* xagg  = ws;  ws += (size_t)NN*HDIM;
  float* q     = ws;  ws += (size_t)NN*HDIM;
  float* kbuf  = ws;  ws += (size_t)NN*HDIM;
  float* v     = ws;  ws += (size_t)NN*384;
  float* vdot  = ws;  ws += (size_t)NN*HDIM;
  float* vec3  = ws;  ws += (size_t)NN*384;
  float* vecagg= ws;  ws += (size_t)NN*384;
  float* vec   = ws;  ws += (size_t)NN*384;
  float* bias512 = ws; ws += 512;
  unsigned short* abf = (unsigned short*)ws;          // NE*64 bf16 (16.8 MB)
  unsigned short* wbT = abf + (size_t)NE*NRBF;        // 512*64 bf16

  k_edge_geom<<<(NE+255)/256,256,0,stream>>>(pos,snd,rcv,ew,evec);
  k_edge_attr<<<(NE*NRBF)/256,256,0,stream>>>(ew,abf);
  hipMemsetAsync(xagg,0,(size_t)NN*HDIM*4,stream);
  k_nb_scatter_b<<<NE/EB,256,0,stream>>>(abf,ew,snd,rcv,z,embed2,nbWd,nbbd,xagg);
  k_combine_b<<<NN/16,256,0,stream>>>(z,embed1,xagg,nbWc,nbbc,x);
  hipMemsetAsync(vec,0,(size_t)NN*384*4,stream);
  for(int l=0;l<NL;l++){
    k_wcvt<<<(512*64)/256,256,0,stream>>>(Wdk,Wdv,wbT,l);
    k_bcvt<<<2,256,0,stream>>>(bdk,bdv,bias512,l);
    k_node_pre_b<<<NN/16,256,0,stream>>>(x,vec,lng,lnb,Wq,bq,Wk,bk,Wv,bv,Wvec,cscale,
                                         q,kbuf,v,vdot,vec3,l);
    hipMemsetAsync(xagg,0,(size_t)NN*HDIM*4,stream);
    hipMemsetAsync(vecagg,0,(size_t)NN*384*4,stream);
    k_edge_fused<<<NE/EB,256,0,stream>>>(abf,wbT,bias512,ew,evec,snd,rcv,
                                         q,kbuf,v,vec,xagg,vecagg);
    k_node_update_b<<<NN/16,256,0,stream>>>(xagg,vdot,vec3,vecagg,Wo,bo,x,vec,l);
  }
  k_final<<<NN,64,0,stream>>>(x,vec,lnfg,lnfb,out);
}

// Round 4
// 2045.885 us; speedup vs baseline: 2.4737x; 1.1605x over previous
//
#include <hip/hip_runtime.h>
#include <math.h>

#define NN 16384
#define NE 131072
#define HDIM 128
#define NRBF 64
#define NL 4
#define EB 64
#define CHN 4096            // nodes per chunk
#define MAXCE 36864         // max edges per chunk (576 blocks * 64)

typedef __attribute__((ext_vector_type(8))) short short8;
typedef __attribute__((ext_vector_type(4))) float f32x4;

__device__ __forceinline__ float siluf(float x){ return x / (1.0f + expf(-x)); }
__device__ __forceinline__ float cutofff(float d){
  return (d < 10.0f) ? 0.5f*(cosf(d*0.31415926535897932f)+1.0f) : 0.0f;
}
__device__ __forceinline__ unsigned short f2bf(float f){
  union{float f; unsigned u;} v; v.f = f;
  unsigned r = v.u + 0x7FFF + ((v.u>>16)&1);
  return (unsigned short)(r>>16);
}
__device__ __forceinline__ float bf2f(unsigned short b){
  union{unsigned u; float f;} v; v.u = ((unsigned)b)<<16;
  return v.f;
}
__device__ __forceinline__ float rbff(float d, int r){
  const float start = expf(-10.0f);
  const float tmp = (2.0f/64.0f)*(1.0f-start);
  const float beta = 1.0f/(tmp*tmp);
  float mean = start + (1.0f-start)*((float)r*(1.0f/63.0f));
  float t = expf(-0.5f*d) - mean;
  return cutofff(d)*expf(-beta*t*t);
}

// ---------------- edge geometry ----------------
__global__ void k_edge_geom(const float* __restrict__ pos, const int* __restrict__ snd,
                            const int* __restrict__ rcv, float* __restrict__ ew,
                            float* __restrict__ evec){
  int e = blockIdx.x*blockDim.x + threadIdx.x;
  if(e >= NE) return;
  int s = snd[e], r = rcv[e];
  float dx = pos[r*3+0]-pos[s*3+0];
  float dy = pos[r*3+1]-pos[s*3+1];
  float dz = pos[r*3+2]-pos[s*3+2];
  const float eps = 1e-6f;
  float d = sqrtf((dx+eps)*(dx+eps)+(dy+eps)*(dy+eps)+(dz+eps)*(dz+eps));
  ew[e] = d;
  float mew = (s==r) ? 1.0f : d;
  mew = fmaxf(mew, 0.01f);
  float inv = 1.0f/mew;
  evec[e*3+0]=dx*inv; evec[e*3+1]=dy*inv; evec[e*3+2]=dz*inv;
}

// ---------------- CSR build ----------------
__global__ void k_hist(const int* __restrict__ rcv, int* __restrict__ deg){
  int e = blockIdx.x*256+threadIdx.x;
  if(e<NE) atomicAdd(&deg[rcv[e]],1);
}
__global__ __launch_bounds__(1024) void k_scan(const int* __restrict__ deg,
                                               int* __restrict__ off, int* __restrict__ cursor){
  __shared__ int part[1024];
  int t=threadIdx.x;
  int loc[16]; int s=0;
  #pragma unroll
  for(int i=0;i<16;i++){ loc[i]=s; s+=deg[t*16+i]; }
  part[t]=s; __syncthreads();
  for(int d=1;d<1024;d<<=1){
    int v=(t>=d)?part[t-d]:0; __syncthreads(); part[t]+=v; __syncthreads();
  }
  int excl = (t>0)?part[t-1]:0;
  #pragma unroll
  for(int i=0;i<16;i++){ int o=excl+loc[i]; off[t*16+i]=o; cursor[t*16+i]=o; }
  if(t==1023) off[NN]=part[1023];
}
__global__ void k_scatter(const int* __restrict__ rcv, int* __restrict__ cursor,
                          int* __restrict__ eidx){
  int e = blockIdx.x*256+threadIdx.x; if(e>=NE) return;
  int p = atomicAdd(&cursor[rcv[e]],1);
  eidx[p]=e;
}
__global__ void k_permute(const int* __restrict__ eidx, const float* __restrict__ ew,
                          const float* __restrict__ evec, const int* __restrict__ snd,
                          float* __restrict__ ews, float* __restrict__ cw,
                          float* __restrict__ evs, int* __restrict__ snds){
  int i = blockIdx.x*256+threadIdx.x; if(i>=NE) return;
  int e = eidx[i];
  float d = ew[e];
  ews[i]=d; cw[i]=cutofff(d);
  evs[i*3+0]=evec[e*3+0]; evs[i*3+1]=evec[e*3+1]; evs[i*3+2]=evec[e*3+2];
  snds[i]=snd[e];
}

// ---------------- neighbor embedding, 64 edges/block (RBF inline) ----------------
__global__ __launch_bounds__(256) void k_nb_scatter_b(
    const float* __restrict__ ew,
    const int* __restrict__ snd, const int* __restrict__ rcv,
    const int* __restrict__ z, const float* __restrict__ embed2,
    const float* __restrict__ Wd, const float* __restrict__ bd,
    float* __restrict__ xnb){
  __shared__ float sw[NRBF*HDIM];
  __shared__ float sattr[EB][NRBF];
  int t = threadIdx.x; int e0 = blockIdx.x*EB;
  #pragma unroll
  for(int i=0;i<32;i++) sw[i*256+t] = Wd[i*256+t];
  #pragma unroll
  for(int i=0;i<16;i++){
    int idx = i*256+t; int el = idx>>6, rb = idx&63;
    sattr[el][rb] = rbff(ew[e0+el], rb);
  }
  __syncthreads();
  int j = t&127, g = t>>7;
  float bdj = bd[j];
  for(int p=0;p<4;p++){
    int eb = g*32 + p*8;
    float acc[8];
    #pragma unroll
    for(int r=0;r<8;r++) acc[r] = bdj;
    for(int rb=0;rb<NRBF;rb++){
      float wv = sw[rb*HDIM + j];
      #pragma unroll
      for(int r=0;r<8;r++) acc[r] += sattr[eb+r][rb]*wv;
    }
    #pragma unroll
    for(int r=0;r<8;r++){
      int e = e0+eb+r;
      float C = cutofff(ew[e]);
      int s = snd[e], rc = rcv[e];
      float m = embed2[(size_t)z[s]*HDIM + j]*acc[r]*C;
      atomicAdd(&xnb[(size_t)rc*HDIM + j], m);
    }
  }
}

// ---------------- combine, 16 nodes/block ----------------
__global__ __launch_bounds__(256) void k_combine_b(
    const int* __restrict__ z, const float* __restrict__ embed1,
    const float* __restrict__ xnb, const float* __restrict__ Wc,
    const float* __restrict__ bc, float* __restrict__ x){
  __shared__ float sx[16][2*HDIM];
  int t = threadIdx.x; int n0 = blockIdx.x*16;
  #pragma unroll
  for(int i=0;i<16;i++){
    int idx = i*256+t; int nn = idx>>8, c = idx&255;
    int n = n0+nn;
    sx[nn][c] = (c<128) ? embed1[(size_t)z[n]*HDIM + c]
                        : xnb[(size_t)n*HDIM + (c-128)];
  }
  __syncthreads();
  int j = t&127, g = t>>7;
  float bcj = bc[j];
  float acc[8];
  #pragma unroll
  for(int r=0;r<8;r++) acc[r]=bcj;
  for(int i=0;i<2*HDIM;i++){
    float wv = Wc[i*HDIM+j];
    #pragma unroll
    for(int r=0;r<8;r++) acc[r] += sx[2*r+g][i]*wv;
  }
  #pragma unroll
  for(int r=0;r<8;r++) x[(size_t)(n0+2*r+g)*HDIM+j] = acc[r];
}

// ---------------- per-layer weight prep ----------------
__global__ void k_wcvt(const float* __restrict__ Wdk, const float* __restrict__ Wdv,
                       unsigned short* __restrict__ wbT, int l){
  int o = blockIdx.x*blockDim.x + threadIdx.x;
  if(o >= 512*64) return;
  int n = o >> 6, kk = o & 63;
  float v = (n < 128) ? Wdk[(size_t)l*NRBF*HDIM + kk*HDIM + n]
                      : Wdv[(size_t)l*NRBF*384 + kk*384 + (n-128)];
  wbT[o] = f2bf(v);
}
__global__ void k_bcvt(const float* __restrict__ bdk, const float* __restrict__ bdv,
                       float* __restrict__ bias, int l){
  int c = threadIdx.x + blockIdx.x*blockDim.x;
  if(c >= 512) return;
  bias[c] = (c < 128) ? bdk[l*HDIM + c] : bdv[l*384 + (c-128)];
}

// ---------------- chunked dk/dv GEMM over sorted edges ----------------
__global__ __launch_bounds__(256) void k_dkv_chunk(const float* __restrict__ ews,
    const unsigned short* __restrict__ wbT, const float* __restrict__ bias,
    const int* __restrict__ off, unsigned short* __restrict__ dkvc, int c){
  __shared__ __align__(16) unsigned short BD[512*64];
  __shared__ float sbias[512];
  int t = threadIdx.x;
  int base = off[c*CHN], cnt = off[(c+1)*CHN]-base;
  int e0 = blockIdx.x*64;
  if(e0 >= cnt) return;
  sbias[t]=bias[t]; sbias[256+t]=bias[256+t];
  #pragma unroll
  for(int i=0;i<16;i++){
    int idx=i*256+t; int n=idx>>3, kc=idx&7;
    short8 val = *(const short8*)(wbT + n*64 + kc*8);
    *(short8*)((char*)BD + n*128 + ((kc ^ (n&7))<<4)) = val;
  }
  int w=t>>6, l=t&63, lr=l&15, lg=l>>4;
  int row = w*16+lr;
  float d = (e0+row<cnt) ? ews[base+e0+row] : 1e9f;
  short8 a0, a1;
  {
    float edm = expf(-0.5f*d);
    float Cc = cutofff(d);
    const float start = expf(-10.0f);
    const float tmp = (2.0f/64.0f)*(1.0f-start);
    const float beta = 1.0f/(tmp*tmp);
    #pragma unroll
    for(int si=0;si<8;si++){
      float m0 = start + (1.0f-start)*((float)(lg*8+si)*(1.0f/63.0f));
      float m1 = start + (1.0f-start)*((float)(32+lg*8+si)*(1.0f/63.0f));
      float t0 = edm-m0, t1 = edm-m1;
      a0[si] = (short)f2bf(Cc*expf(-beta*t0*t0));
      a1[si] = (short)f2bf(Cc*expf(-beta*t1*t1));
    }
  }
  __syncthreads();
  unsigned pk[64];
  #pragma unroll
  for(int nt=0;nt<32;nt++){
    int n=nt*16+lr;
    const char* bp=(const char*)BD + n*128;
    short8 b0 = *(const short8*)(bp + (((lg  )^(n&7))<<4));
    short8 b1 = *(const short8*)(bp + (((4+lg)^(n&7))<<4));
    f32x4 acc={0.f,0.f,0.f,0.f};
    acc = __builtin_amdgcn_mfma_f32_16x16x32_bf16(a0,b0,acc,0,0,0);
    acc = __builtin_amdgcn_mfma_f32_16x16x32_bf16(a1,b1,acc,0,0,0);
    float bs=sbias[n];
    pk[nt*2+0] = ((unsigned)f2bf(siluf(acc[1]+bs))<<16)|f2bf(siluf(acc[0]+bs));
    pk[nt*2+1] = ((unsigned)f2bf(siluf(acc[3]+bs))<<16)|f2bf(siluf(acc[2]+bs));
  }
  __syncthreads();
  #pragma unroll
  for(int nt=0;nt<32;nt++){
    int n=nt*16+lr;
    #pragma unroll
    for(int rr=0;rr<4;rr++){
      int el = w*16+lg*4+rr;
      BD[el*512+n] = (unsigned short)(pk[nt*2+(rr>>1)]>>((rr&1)*16));
    }
  }
  __syncthreads();
  const short8* src=(const short8*)BD;
  short8* dst=(short8*)(dkvc + (size_t)e0*512);
  #pragma unroll
  for(int i=0;i<16;i++) dst[i*256+t]=src[i*256+t];
}

// ---------------- gather sweep: 4 nodes/block, no atomics ----------------
__global__ __launch_bounds__(128) void k_sweep(const float* __restrict__ q,
    const unsigned short* __restrict__ kbf, const unsigned short* __restrict__ vbf,
    const float* __restrict__ vec, const float* __restrict__ cw,
    const float* __restrict__ evs, const int* __restrict__ snds,
    const int* __restrict__ off, const unsigned short* __restrict__ dkvc,
    float* __restrict__ xagg, float* __restrict__ vecagg, int c){
  int j = threadIdx.x;
  int n0 = c*CHN + blockIdx.x*4;
  int base = off[c*CHN];
  int hc0 = (j>>4)*48 + (j&15);
  for(int nn=0;nn<4;nn++){
    int node = n0+nn;
    float qj = q[(size_t)node*HDIM+j];
    float xacc=0.f, va0=0.f, va1=0.f, va2=0.f;
    int ib=off[node], ie=off[node+1];
    for(int i=ib;i<ie;i++){
      int s = snds[i];
      const unsigned short* dr = dkvc + (size_t)(i-base)*512;
      float dk = bf2f(dr[j]);
      float prod = qj*bf2f(kbf[(size_t)s*HDIM+j])*dk;
      #pragma unroll
      for(int mm=1;mm<=8;mm<<=1) prod += __shfl_xor(prod,mm);
      float attn = siluf(prod)*cw[i];
      float b0=bf2f(dr[128+hc0]), b1=bf2f(dr[144+hc0]), b2=bf2f(dr[160+hc0]);
      const unsigned short* vs=vbf+(size_t)s*384;
      float vv0=bf2f(vs[hc0]), vv1=bf2f(vs[hc0+16]), vv2=bf2f(vs[hc0+32]);
      xacc += vv0*b0*attn;
      float s1v=vv1*b1, s2v=vv2*b2;
      va0 += vec[((size_t)s*3+0)*HDIM+j]*s1v + s2v*evs[i*3+0];
      va1 += vec[((size_t)s*3+1)*HDIM+j]*s1v + s2v*evs[i*3+1];
      va2 += vec[((size_t)s*3+2)*HDIM+j]*s1v + s2v*evs[i*3+2];
    }
    xagg[(size_t)node*HDIM+j]=xacc;
    vecagg[((size_t)node*3+0)*HDIM+j]=va0;
    vecagg[((size_t)node*3+1)*HDIM+j]=va1;
    vecagg[((size_t)node*3+2)*HDIM+j]=va2;
  }
}

// ---------------- per-layer node pre, 16 nodes/block ----------------
__global__ __launch_bounds__(256) void k_node_pre_b(
    const float* __restrict__ x, const float* __restrict__ vec,
    const float* __restrict__ lng, const float* __restrict__ lnb,
    const float* __restrict__ Wq, const float* __restrict__ bq,
    const float* __restrict__ Wk, const float* __restrict__ bk,
    const float* __restrict__ Wv, const float* __restrict__ bv,
    const float* __restrict__ Wvec, const float* __restrict__ cscale,
    float* __restrict__ q, unsigned short* __restrict__ kbf,
    unsigned short* __restrict__ vbf, float* __restrict__ vdot,
    float* __restrict__ vec3, int l){
  __shared__ float sxn[16][HDIM];
  __shared__ float svn[3][16][HDIM];
  int t = threadIdx.x; int n0 = blockIdx.x*16;
  int w = t>>6, lane = t&63;
  float cs = cscale[l];
  float g0 = lng[l*HDIM+lane], g1 = lng[l*HDIM+64+lane];
  float be0 = lnb[l*HDIM+lane], be1 = lnb[l*HDIM+64+lane];
  for(int rr=0; rr<4; rr++){
    int nn = w*4+rr; int n = n0+nn;
    float x0 = x[(size_t)n*HDIM+lane], x1 = x[(size_t)n*HDIM+64+lane];
    float sum = x0+x1;
    #pragma unroll
    for(int m=1;m<=32;m<<=1) sum += __shfl_xor(sum,m);
    float mean = sum*(1.f/128.f);
    float d0 = x0-mean, d1 = x1-mean;
    float vs = d0*d0+d1*d1;
    #pragma unroll
    for(int m=1;m<=32;m<<=1) vs += __shfl_xor(vs,m);
    float rstd = rsqrtf(vs*(1.f/128.f)+1e-6f);
    sxn[nn][lane]    = d0*rstd*g0 + be0;
    sxn[nn][64+lane] = d1*rstd*g1 + be1;
    float va0 = vec[((size_t)n*3+0)*HDIM+lane], vb0 = vec[((size_t)n*3+0)*HDIM+64+lane];
    float va1 = vec[((size_t)n*3+1)*HDIM+lane], vb1 = vec[((size_t)n*3+1)*HDIM+64+lane];
    float va2 = vec[((size_t)n*3+2)*HDIM+lane], vb2 = vec[((size_t)n*3+2)*HDIM+64+lane];
    float iA = rsqrtf(fmaxf(va0*va0+va1*va1+va2*va2,1e-8f))*cs;
    float iB = rsqrtf(fmaxf(vb0*vb0+vb1*vb1+vb2*vb2,1e-8f))*cs;
    svn[0][nn][lane]=va0*iA; svn[0][nn][64+lane]=vb0*iB;
    svn[1][nn][lane]=va1*iA; svn[1][nn][64+lane]=vb1*iB;
    svn[2][nn][lane]=va2*iA; svn[2][nn][64+lane]=vb2*iB;
  }
  __syncthreads();
  int j = t&127, g = t>>7;
  const float* Wql = Wq + (size_t)l*HDIM*HDIM;
  const float* Wkl = Wk + (size_t)l*HDIM*HDIM;
  const float* Wvl = Wv + (size_t)l*HDIM*384;
  float aq[8], ak[8], av0[8], av1[8], av2[8];
  {
    float bqj = bq[l*HDIM+j], bkj = bk[l*HDIM+j];
    float b0 = bv[l*384+j], b1 = bv[l*384+128+j], b2 = bv[l*384+256+j];
    #pragma unroll
    for(int r=0;r<8;r++){ aq[r]=bqj; ak[r]=bkj; av0[r]=b0; av1[r]=b1; av2[r]=b2; }
  }
  for(int i=0;i<HDIM;i++){
    float wq = Wql[i*HDIM+j], wk = Wkl[i*HDIM+j];
    float w0 = Wvl[i*384+j], w1 = Wvl[i*384+128+j], w2 = Wvl[i*384+256+j];
    #pragma unroll
    for(int r=0;r<8;r++){
      float xi = sxn[2*r+g][i];
      aq[r]+=xi*wq; ak[r]+=xi*wk; av0[r]+=xi*w0; av1[r]+=xi*w1; av2[r]+=xi*w2;
    }
  }
  #pragma unroll
  for(int r=0;r<8;r++){
    float nq = aq[r]*aq[r], nk = ak[r]*ak[r];
    #pragma unroll
    for(int mm=1;mm<=8;mm<<=1){ nq += __shfl_xor(nq,mm); nk += __shfl_xor(nk,mm); }
    float qv = aq[r]/(sqrtf(nq)+1e-6f);
    float kv = ak[r]/(sqrtf(nk)+1e-6f);
    int n = n0+2*r+g;
    q[(size_t)n*HDIM+j]=qv;
    kbf[(size_t)n*HDIM+j]=f2bf(kv);
    vbf[(size_t)n*384+j]=f2bf(av0[r]);
    vbf[(size_t)n*384+128+j]=f2bf(av1[r]);
    vbf[(size_t)n*384+256+j]=f2bf(av2[r]);
  }
  const float* Wvecl = Wvec + (size_t)l*HDIM*384;
  float vd[8];
  #pragma unroll
  for(int r=0;r<8;r++) vd[r]=0.f;
  for(int sp=0;sp<3;sp++){
    float p1[8],p2[8],p3[8];
    #pragma unroll
    for(int r=0;r<8;r++){ p1[r]=0.f;p2[r]=0.f;p3[r]=0.f; }
    for(int i=0;i<HDIM;i++){
      float w0=Wvecl[i*384+j], w1=Wvecl[i*384+128+j], w2=Wvecl[i*384+256+j];
      #pragma unroll
      for(int r=0;r<8;r++){
        float vi = svn[sp][2*r+g][i];
        p1[r]+=vi*w0; p2[r]+=vi*w1; p3[r]+=vi*w2;
      }
    }
    #pragma unroll
    for(int r=0;r<8;r++){
      vd[r] += p1[r]*p2[r];
      vec3[((size_t)(n0+2*r+g)*3+sp)*HDIM+j] = p3[r];
    }
  }
  #pragma unroll
  for(int r=0;r<8;r++) vdot[(size_t)(n0+2*r+g)*HDIM+j] = vd[r];
}

// ---------------- per-layer node update, 16 nodes/block ----------------
__global__ __launch_bounds__(256) void k_node_update_b(
    const float* __restrict__ xagg, const float* __restrict__ vdot,
    const float* __restrict__ vec3, const float* __restrict__ vecagg,
    const float* __restrict__ Wo, const float* __restrict__ bo,
    float* __restrict__ x, float* __restrict__ vec, int l){
  __shared__ float sA[16][HDIM];
  int t = threadIdx.x; int n0 = blockIdx.x*16;
  #pragma unroll
  for(int i=0;i<8;i++){
    int idx = i*256+t; int nn = idx>>7, j2 = idx&127;
    sA[nn][j2] = xagg[(size_t)(n0+nn)*HDIM + j2];
  }
  __syncthreads();
  int j = t&127, g = t>>7;
  const float* Wol = Wo + (size_t)l*HDIM*384;
  float o1[8],o2[8],o3[8];
  {
    float b1=bo[l*384+j], b2=bo[l*384+128+j], b3=bo[l*384+256+j];
    #pragma unroll
    for(int r=0;r<8;r++){ o1[r]=b1;o2[r]=b2;o3[r]=b3; }
  }
  for(int i=0;i<HDIM;i++){
    float w0=Wol[i*384+j], w1=Wol[i*384+128+j], w2=Wol[i*384+256+j];
    #pragma unroll
    for(int r=0;r<8;r++){
      float a = sA[2*r+g][i];
      o1[r]+=a*w0; o2[r]+=a*w1; o3[r]+=a*w2;
    }
  }
  #pragma unroll
  for(int r=0;r<8;r++){
    int n = n0+2*r+g;
    x[(size_t)n*HDIM+j] += vdot[(size_t)n*HDIM+j]*o2[r] + o3[r];
    #pragma unroll
    for(int sp=0;sp<3;sp++){
      size_t idx=((size_t)n*3+sp)*HDIM+j;
      vec[idx] += vec3[idx]*o1[r] + vecagg[idx];
    }
  }
}

// ---------------- final layernorm + output ----------------
__global__ void k_final(const float* __restrict__ x, const float* __restrict__ vec,
                        const float* __restrict__ g, const float* __restrict__ b,
                        float* __restrict__ out){
  int n=blockIdx.x; int t=threadIdx.x;
  float x0=x[(size_t)n*HDIM+t], x1=x[(size_t)n*HDIM+64+t];
  float sum=x0+x1;
  #pragma unroll
  for(int m=1;m<=32;m<<=1) sum += __shfl_xor(sum,m);
  float mean=sum*(1.f/128.f);
  float d0=x0-mean, d1=x1-mean;
  float vs=d0*d0+d1*d1;
  #pragma unroll
  for(int m=1;m<=32;m<<=1) vs += __shfl_xor(vs,m);
  float rstd=rsqrtf(vs*(1.f/128.f)+1e-6f);
  out[(size_t)n*HDIM+t]    = d0*rstd*g[t]+b[t];
  out[(size_t)n*HDIM+64+t] = d1*rstd*g[64+t]+b[64+t];
  float* ov = out + (size_t)NN*HDIM;
  for(int sp=0;sp<3;sp++){
    size_t idx=((size_t)n*3+sp)*HDIM;
    ov[idx+t]    = vec[idx+t];
    ov[idx+64+t] = vec[idx+64+t];
  }
}

extern "C" void kernel_launch(void* const* d_in, const int* in_sizes, int n_in,
                              void* d_out, int out_size, void* d_ws, size_t ws_size,
                              hipStream_t stream){
  const int*   z      = (const int*)  d_in[0];
  const float* pos    = (const float*)d_in[1];
  const int*   snd    = (const int*)  d_in[2];
  const int*   rcv    = (const int*)  d_in[3];
  const float* embed1 = (const float*)d_in[4];
  const float* embed2 = (const float*)d_in[5];
  const float* nbWd   = (const float*)d_in[6];
  const float* nbbd   = (const float*)d_in[7];
  const float* nbWc   = (const float*)d_in[8];
  const float* nbbc   = (const float*)d_in[9];
  const float* lng    = (const float*)d_in[10];
  const float* lnb    = (const float*)d_in[11];
  const float* Wq     = (const float*)d_in[12];
  const float* bq     = (const float*)d_in[13];
  const float* Wk     = (const float*)d_in[14];
  const float* bk     = (const float*)d_in[15];
  const float* Wv     = (const float*)d_in[16];
  const float* bv     = (const float*)d_in[17];
  const float* Wvec   = (const float*)d_in[18];
  const float* Wdk    = (const float*)d_in[19];
  const float* bdk    = (const float*)d_in[20];
  const float* Wdv    = (const float*)d_in[21];
  const float* bdv    = (const float*)d_in[22];
  const float* Wo     = (const float*)d_in[23];
  const float* bo     = (const float*)d_in[24];
  const float* cscale = (const float*)d_in[25];
  const float* lnfg   = (const float*)d_in[26];
  const float* lnfb   = (const float*)d_in[27];
  float* out = (float*)d_out;

  float* ws = (float*)d_ws;
  float* ew    = ws;  ws += NE;
  float* evec  = ws;  ws += 3*NE;
  float* ews   = ws;  ws += NE;
  float* cw    = ws;  ws += NE;
  float* evs   = ws;  ws += 3*NE;
  float* x     = ws;  ws += (size_t)NN*HDIM;
  float* xagg  = ws;  ws += (size_t)NN*HDIM;
  float* q     = ws;  ws += (size_t)NN*HDIM;
  float* vdot  = ws;  ws += (size_t)NN*HDIM;
  float* vec3  = ws;  ws += (size_t)NN*384;
  float* vecagg= ws;  ws += (size_t)NN*384;
  float* vec   = ws;  ws += (size_t)NN*384;
  float* bias512 = ws; ws += 512;
  int* deg    = (int*)ws; ws += NN;
  int* off    = (int*)ws; ws += NN+8;
  int* cursor = (int*)ws; ws += NN;
  int* eidx   = (int*)ws; ws += NE;
  int* snds   = (int*)ws; ws += NE;
  unsigned short* kbf  = (unsigned short*)ws;              // NN*128 bf16
  unsigned short* vbf  = kbf + (size_t)NN*HDIM;            // NN*384 bf16
  unsigned short* wbT  = vbf + (size_t)NN*384;             // 512*64 bf16
  unsigned short* dkvc = wbT + 512*64;                     // MAXCE*512 bf16 (~38 MB)

  k_edge_geom<<<(NE+255)/256,256,0,stream>>>(pos,snd,rcv,ew,evec);
  hipMemsetAsync(deg,0,NN*4,stream);
  k_hist<<<NE/256,256,0,stream>>>(rcv,deg);
  k_scan<<<1,1024,0,stream>>>(deg,off,cursor);
  k_scatter<<<NE/256,256,0,stream>>>(rcv,cursor,eidx);
  k_permute<<<NE/256,256,0,stream>>>(eidx,ew,evec,snd,ews,cw,evs,snds);
  hipMemsetAsync(xagg,0,(size_t)NN*HDIM*4,stream);
  k_nb_scatter_b<<<NE/EB,256,0,stream>>>(ew,snd,rcv,z,embed2,nbWd,nbbd,xagg);
  k_combine_b<<<NN/16,256,0,stream>>>(z,embed1,xagg,nbWc,nbbc,x);
  hipMemsetAsync(vec,0,(size_t)NN*384*4,stream);
  for(int l=0;l<NL;l++){
    k_wcvt<<<(512*64)/256,256,0,stream>>>(Wdk,Wdv,wbT,l);
    k_bcvt<<<2,256,0,stream>>>(bdk,bdv,bias512,l);
    k_node_pre_b<<<NN/16,256,0,stream>>>(x,vec,lng,lnb,Wq,bq,Wk,bk,Wv,bv,Wvec,cscale,
                                         q,kbf,vbf,vdot,vec3,l);
    for(int c=0;c<4;c++){
      k_dkv_chunk<<<MAXCE/64,256,0,stream>>>(ews,wbT,bias512,off,dkvc,c);
      k_sweep<<<CHN/4,128,0,stream>>>(q,kbf,vbf,vec,cw,evs,snds,off,dkvc,
                                      xagg,vecagg,c);
    }
    k_node_update_b<<<NN/16,256,0,stream>>>(xagg,vdot,vec3,vecagg,Wo,bo,x,vec,l);
  }
  k_final<<<NN,64,0,stream>>>(x,vec,lnfg,lnfb,out);
}

// Round 5
// 1442.434 us; speedup vs baseline: 3.5086x; 1.4184x over previous
//
#include <hip/hip_runtime.h>
#include <math.h>

#define NN 16384
#define NE 131072
#define HDIM 128
#define NRBF 64
#define NL 4
#define CHN 4096            // nodes per chunk
#define MAXCE 36864         // max edges per chunk

typedef __attribute__((ext_vector_type(8))) short short8;
typedef __attribute__((ext_vector_type(4))) float f32x4;

__device__ __forceinline__ float siluf(float x){ return x / (1.0f + expf(-x)); }
__device__ __forceinline__ float cutofff(float d){
  return (d < 10.0f) ? 0.5f*(cosf(d*0.31415926535897932f)+1.0f) : 0.0f;
}
__device__ __forceinline__ unsigned short f2bf(float f){
  union{float f; unsigned u;} v; v.f = f;
  unsigned r = v.u + 0x7FFF + ((v.u>>16)&1);
  return (unsigned short)(r>>16);
}
__device__ __forceinline__ float bf2f(unsigned short b){
  union{unsigned u; float f;} v; v.u = ((unsigned)b)<<16;
  return v.f;
}

// ---------------- edge geometry ----------------
__global__ void k_edge_geom(const float* __restrict__ pos, const int* __restrict__ snd,
                            const int* __restrict__ rcv, float* __restrict__ ew,
                            float* __restrict__ evec){
  int e = blockIdx.x*blockDim.x + threadIdx.x;
  if(e >= NE) return;
  int s = snd[e], r = rcv[e];
  float dx = pos[r*3+0]-pos[s*3+0];
  float dy = pos[r*3+1]-pos[s*3+1];
  float dz = pos[r*3+2]-pos[s*3+2];
  const float eps = 1e-6f;
  float d = sqrtf((dx+eps)*(dx+eps)+(dy+eps)*(dy+eps)+(dz+eps)*(dz+eps));
  ew[e] = d;
  float mew = (s==r) ? 1.0f : d;
  mew = fmaxf(mew, 0.01f);
  float inv = 1.0f/mew;
  evec[e*3+0]=dx*inv; evec[e*3+1]=dy*inv; evec[e*3+2]=dz*inv;
}

// ---------------- CSR build ----------------
__global__ void k_hist(const int* __restrict__ rcv, int* __restrict__ deg){
  int e = blockIdx.x*256+threadIdx.x;
  if(e<NE) atomicAdd(&deg[rcv[e]],1);
}
__global__ __launch_bounds__(1024) void k_scan(const int* __restrict__ deg,
                                               int* __restrict__ off, int* __restrict__ cursor){
  __shared__ int part[1024];
  int t=threadIdx.x;
  int loc[16]; int s=0;
  #pragma unroll
  for(int i=0;i<16;i++){ loc[i]=s; s+=deg[t*16+i]; }
  part[t]=s; __syncthreads();
  for(int d=1;d<1024;d<<=1){
    int v=(t>=d)?part[t-d]:0; __syncthreads(); part[t]+=v; __syncthreads();
  }
  int excl = (t>0)?part[t-1]:0;
  #pragma unroll
  for(int i=0;i<16;i++){ int o=excl+loc[i]; off[t*16+i]=o; cursor[t*16+i]=o; }
  if(t==1023) off[NN]=part[1023];
}
__global__ void k_scatter(const int* __restrict__ rcv, int* __restrict__ cursor,
                          int* __restrict__ eidx){
  int e = blockIdx.x*256+threadIdx.x; if(e>=NE) return;
  int p = atomicAdd(&cursor[rcv[e]],1);
  eidx[p]=e;
}
__global__ void k_permute(const int* __restrict__ eidx, const float* __restrict__ ew,
                          const float* __restrict__ evec, const int* __restrict__ snd,
                          float* __restrict__ ews, float* __restrict__ cw,
                          float* __restrict__ evs, int* __restrict__ snds){
  int i = blockIdx.x*256+threadIdx.x; if(i>=NE) return;
  int e = eidx[i];
  float d = ew[e];
  ews[i]=d; cw[i]=cutofff(d);
  evs[i*3+0]=evec[e*3+0]; evs[i*3+1]=evec[e*3+1]; evs[i*3+2]=evec[e*3+2];
  snds[i]=snd[e];
}

// ---------------- weight transposes to bf16 ----------------
__global__ void k_cvt_nbT(const float* __restrict__ Wd, unsigned short* __restrict__ dst){
  int o = blockIdx.x*256+threadIdx.x; if(o>=HDIM*NRBF) return;
  int n=o>>6, k=o&63;
  dst[o] = f2bf(Wd[k*HDIM+n]);
}
__global__ void k_cvt_qkvT(const float* __restrict__ Wq, const float* __restrict__ Wk,
                           const float* __restrict__ Wv, unsigned short* __restrict__ dst){
  int o = blockIdx.x*256+threadIdx.x;
  if(o >= 4*640*128) return;
  int l = o/81920; int rem = o - l*81920;
  int n = rem>>7, k = rem&127;
  float v;
  if(n<128)      v = Wq[(size_t)l*16384 + k*128 + n];
  else if(n<256) v = Wk[(size_t)l*16384 + k*128 + (n-128)];
  else           v = Wv[(size_t)l*49152 + k*384 + (n-256)];
  dst[o]=f2bf(v);
}
__global__ void k_cvtT(const float* __restrict__ src, unsigned short* __restrict__ dst, int NC){
  int o = blockIdx.x*256+threadIdx.x;
  int tot = 4*NC*128; if(o>=tot) return;
  int l = o/(NC*128); int rem = o - l*NC*128;
  int n = rem>>7, k = rem&127;
  dst[o] = f2bf(src[(size_t)l*128*NC + k*NC + n]);
}
__global__ void k_wcvt(const float* __restrict__ Wdk, const float* __restrict__ Wdv,
                       unsigned short* __restrict__ wbT, int l){
  int o = blockIdx.x*blockDim.x + threadIdx.x;
  if(o >= 512*64) return;
  int n = o >> 6, kk = o & 63;
  float v = (n < 128) ? Wdk[(size_t)l*NRBF*HDIM + kk*HDIM + n]
                      : Wdv[(size_t)l*NRBF*384 + kk*384 + (n-128)];
  wbT[o] = f2bf(v);
}
__global__ void k_bcvt(const float* __restrict__ bdk, const float* __restrict__ bdv,
                       float* __restrict__ bias, int l){
  int c = threadIdx.x + blockIdx.x*blockDim.x;
  if(c >= 512) return;
  bias[c] = (c < 128) ? bdk[l*HDIM + c] : bdv[l*384 + (c-128)];
}

// ---------------- neighbor-embedding GEMM over sorted edges (no atomics) -----
__global__ __launch_bounds__(256) void k_nb_gemm(const float* __restrict__ ews,
    const float* __restrict__ cw, const int* __restrict__ snds,
    const int* __restrict__ z, const float* __restrict__ embed2,
    const unsigned short* __restrict__ nbT, const float* __restrict__ bd,
    unsigned short* __restrict__ msgc){
  __shared__ __align__(16) unsigned short Bl[HDIM*64];
  int t = threadIdx.x;
  int e0 = blockIdx.x*64;
  #pragma unroll
  for(int i=0;i<4;i++){
    int idx=i*256+t; int n=idx>>3, kc=idx&7;
    short8 val = *(const short8*)(nbT + n*64 + kc*8);
    *(short8*)((char*)Bl + n*128 + ((kc ^ (n&7))<<4)) = val;
  }
  int w=t>>6, l=t&63, lr=l&15, lg=l>>4;
  float d = ews[e0 + w*16 + lr];
  short8 a0, a1;
  {
    float edm = expf(-0.5f*d);
    float Cc = cutofff(d);
    const float start = expf(-10.0f);
    const float tmp = (2.0f/64.0f)*(1.0f-start);
    const float beta = 1.0f/(tmp*tmp);
    #pragma unroll
    for(int si=0;si<8;si++){
      float m0 = start + (1.0f-start)*((float)(lg*8+si)*(1.0f/63.0f));
      float m1 = start + (1.0f-start)*((float)(32+lg*8+si)*(1.0f/63.0f));
      float t0 = edm-m0, t1 = edm-m1;
      a0[si] = (short)f2bf(Cc*expf(-beta*t0*t0));
      a1[si] = (short)f2bf(Cc*expf(-beta*t1*t1));
    }
  }
  int sr[4]; float Cr[4]; int zz[4];
  #pragma unroll
  for(int r=0;r<4;r++){
    int i = e0 + w*16 + lg*4 + r;
    sr[r]=snds[i]; Cr[r]=cw[i]; zz[r]=z[sr[r]];
  }
  __syncthreads();
  #pragma unroll
  for(int nt=0;nt<8;nt++){
    int n=nt*16+lr;
    const char* bp=(const char*)Bl + n*128;
    short8 b0 = *(const short8*)(bp + (((lg  )^(n&7))<<4));
    short8 b1 = *(const short8*)(bp + (((4+lg)^(n&7))<<4));
    f32x4 acc={0.f,0.f,0.f,0.f};
    acc = __builtin_amdgcn_mfma_f32_16x16x32_bf16(a0,b0,acc,0,0,0);
    acc = __builtin_amdgcn_mfma_f32_16x16x32_bf16(a1,b1,acc,0,0,0);
    float bdn = bd[n];
    #pragma unroll
    for(int r=0;r<4;r++){
      float m = (acc[r]+bdn)*Cr[r]*embed2[(size_t)zz[r]*HDIM+n];
      msgc[(size_t)(e0+w*16+lg*4+r)*HDIM + n] = f2bf(m);
    }
  }
}
__global__ void k_nb_sweep(const int* __restrict__ off,
                           const unsigned short* __restrict__ msgc,
                           float* __restrict__ xnb){
  int j = threadIdx.x;                 // 128
  int n0 = blockIdx.x*8;
  for(int nn=0;nn<8;nn++){
    int node=n0+nn;
    float acc=0.f;
    int ib=off[node], ie=off[node+1];
    for(int i=ib;i<ie;i++) acc += bf2f(msgc[(size_t)i*HDIM+j]);
    xnb[(size_t)node*HDIM+j]=acc;
  }
}

// ---------------- combine, 16 nodes/block ----------------
__global__ __launch_bounds__(256) void k_combine_b(
    const int* __restrict__ z, const float* __restrict__ embed1,
    const float* __restrict__ xnb, const float* __restrict__ Wc,
    const float* __restrict__ bc, float* __restrict__ x){
  __shared__ float sx[16][2*HDIM];
  int t = threadIdx.x; int n0 = blockIdx.x*16;
  #pragma unroll
  for(int i=0;i<16;i++){
    int idx = i*256+t; int nn = idx>>8, c = idx&255;
    int n = n0+nn;
    sx[nn][c] = (c<128) ? embed1[(size_t)z[n]*HDIM + c]
                        : xnb[(size_t)n*HDIM + (c-128)];
  }
  __syncthreads();
  int j = t&127, g = t>>7;
  float bcj = bc[j];
  float acc[8];
  #pragma unroll
  for(int r=0;r<8;r++) acc[r]=bcj;
  for(int i=0;i<2*HDIM;i++){
    float wv = Wc[i*HDIM+j];
    #pragma unroll
    for(int r=0;r<8;r++) acc[r] += sx[2*r+g][i]*wv;
  }
  #pragma unroll
  for(int r=0;r<8;r++) x[(size_t)(n0+2*r+g)*HDIM+j] = acc[r];
}

// ---------------- node pre: LN/coorsnorm + MFMA GEMMs, 32 nodes/block ---------
__global__ __launch_bounds__(256) void k_node_pre_m(
    const float* __restrict__ x, const float* __restrict__ vec,
    const float* __restrict__ lng, const float* __restrict__ lnb,
    const float* __restrict__ bq, const float* __restrict__ bk,
    const float* __restrict__ bv, const unsigned short* __restrict__ WqkvT,
    const unsigned short* __restrict__ WvecT, const float* __restrict__ cscale,
    unsigned short* __restrict__ qbf, unsigned short* __restrict__ kbf,
    unsigned short* __restrict__ vbf, float* __restrict__ vdot,
    float* __restrict__ vec3, int l){
  __shared__ unsigned short sxn[32][HDIM];
  __shared__ unsigned short svn[3][32][HDIM];
  int t = threadIdx.x, w = t>>6, lane = t&63;
  int n0 = blockIdx.x*32;
  float cs = cscale[l];
  float g0 = lng[l*HDIM+lane], g1 = lng[l*HDIM+64+lane];
  float be0 = lnb[l*HDIM+lane], be1 = lnb[l*HDIM+64+lane];
  for(int rr=0; rr<8; rr++){
    int nn = w*8+rr; int n = n0+nn;
    float x0 = x[(size_t)n*HDIM+lane], x1 = x[(size_t)n*HDIM+64+lane];
    float sum = x0+x1;
    #pragma unroll
    for(int m=1;m<=32;m<<=1) sum += __shfl_xor(sum,m);
    float mean = sum*(1.f/128.f);
    float d0 = x0-mean, d1 = x1-mean;
    float vs = d0*d0+d1*d1;
    #pragma unroll
    for(int m=1;m<=32;m<<=1) vs += __shfl_xor(vs,m);
    float rstd = rsqrtf(vs*(1.f/128.f)+1e-6f);
    sxn[nn][lane]    = f2bf(d0*rstd*g0 + be0);
    sxn[nn][64+lane] = f2bf(d1*rstd*g1 + be1);
    float va0 = vec[((size_t)n*3+0)*HDIM+lane], vb0 = vec[((size_t)n*3+0)*HDIM+64+lane];
    float va1 = vec[((size_t)n*3+1)*HDIM+lane], vb1 = vec[((size_t)n*3+1)*HDIM+64+lane];
    float va2 = vec[((size_t)n*3+2)*HDIM+lane], vb2 = vec[((size_t)n*3+2)*HDIM+64+lane];
    float iA = rsqrtf(fmaxf(va0*va0+va1*va1+va2*va2,1e-8f))*cs;
    float iB = rsqrtf(fmaxf(vb0*vb0+vb1*vb1+vb2*vb2,1e-8f))*cs;
    svn[0][nn][lane]=f2bf(va0*iA); svn[0][nn][64+lane]=f2bf(vb0*iB);
    svn[1][nn][lane]=f2bf(va1*iA); svn[1][nn][64+lane]=f2bf(vb1*iB);
    svn[2][nn][lane]=f2bf(va2*iA); svn[2][nn][64+lane]=f2bf(vb2*iB);
  }
  __syncthreads();
  int lr = lane&15, lg = lane>>4;
  int mt = w>>1, par = w&1;
  int rbase = mt*16;
  short8 a1[4];
  #pragma unroll
  for(int kk=0;kk<4;kk++) a1[kk] = *(const short8*)&sxn[rbase+lr][kk*32+lg*8];
  short8 a2[3][4];
  #pragma unroll
  for(int sp=0;sp<3;sp++)
    #pragma unroll
    for(int kk=0;kk<4;kk++) a2[sp][kk] = *(const short8*)&svn[sp][rbase+lr][kk*32+lg*8];

  const unsigned short* Bq = WqkvT + (size_t)l*640*128;
  for(int jj=0;jj<20;jj++){
    int j = jj*2+par;
    int col = j*16+lr;
    const unsigned short* bp = Bq + (size_t)col*128 + lg*8;
    f32x4 acc={0.f,0.f,0.f,0.f};
    #pragma unroll
    for(int kk=0;kk<4;kk++) acc = __builtin_amdgcn_mfma_f32_16x16x32_bf16(a1[kk], *(const short8*)(bp+kk*32), acc, 0,0,0);
    if(j < 16){
      float bias = (j<8) ? bq[l*HDIM+col] : bk[l*HDIM+col-128];
      float vv[4], s2[4];
      #pragma unroll
      for(int r=0;r<4;r++){ vv[r]=acc[r]+bias; s2[r]=vv[r]*vv[r]; }
      #pragma unroll
      for(int mm=1;mm<=8;mm<<=1){
        #pragma unroll
        for(int r=0;r<4;r++) s2[r] += __shfl_xor(s2[r],mm);
      }
      #pragma unroll
      for(int r=0;r<4;r++){
        int node = n0+rbase+lg*4+r;
        float vn_ = vv[r]/(sqrtf(s2[r])+1e-6f);
        if(j<8) qbf[(size_t)node*HDIM+col]     = f2bf(vn_);
        else    kbf[(size_t)node*HDIM+col-128] = f2bf(vn_);
      }
    } else {
      int c = col-256;
      float bias = bv[l*384+c];
      #pragma unroll
      for(int r=0;r<4;r++){
        int node = n0+rbase+lg*4+r;
        vbf[(size_t)node*384+c] = f2bf(acc[r]+bias);
      }
    }
  }
  const unsigned short* Bv = WvecT + (size_t)l*384*128;
  for(int jj=0;jj<4;jj++){
    int j = jj*2+par;
    int col = j*16+lr;
    short8 b1[4],b2[4],b3[4];
    #pragma unroll
    for(int kk=0;kk<4;kk++){
      b1[kk] = *(const short8*)(Bv + (size_t)(col    )*128 + kk*32+lg*8);
      b2[kk] = *(const short8*)(Bv + (size_t)(col+128)*128 + kk*32+lg*8);
      b3[kk] = *(const short8*)(Bv + (size_t)(col+256)*128 + kk*32+lg*8);
    }
    f32x4 vd={0.f,0.f,0.f,0.f};
    #pragma unroll
    for(int sp=0;sp<3;sp++){
      f32x4 p1={0.f,0.f,0.f,0.f}, p2={0.f,0.f,0.f,0.f}, p3={0.f,0.f,0.f,0.f};
      #pragma unroll
      for(int kk=0;kk<4;kk++){
        p1 = __builtin_amdgcn_mfma_f32_16x16x32_bf16(a2[sp][kk], b1[kk], p1, 0,0,0);
        p2 = __builtin_amdgcn_mfma_f32_16x16x32_bf16(a2[sp][kk], b2[kk], p2, 0,0,0);
        p3 = __builtin_amdgcn_mfma_f32_16x16x32_bf16(a2[sp][kk], b3[kk], p3, 0,0,0);
      }
      #pragma unroll
      for(int r=0;r<4;r++){
        vd[r] += p1[r]*p2[r];
        int node = n0+rbase+lg*4+r;
        vec3[((size_t)node*3+sp)*HDIM+col] = p3[r];
      }
    }
    #pragma unroll
    for(int r=0;r<4;r++){
      int node = n0+rbase+lg*4+r;
      vdot[(size_t)node*HDIM+col] = vd[r];
    }
  }
}

// ---------------- chunked dk/dv GEMM over sorted edges ----------------
__global__ __launch_bounds__(256) void k_dkv_chunk(const float* __restrict__ ews,
    const unsigned short* __restrict__ wbT, const float* __restrict__ bias,
    const int* __restrict__ off, unsigned short* __restrict__ dkvc, int c){
  __shared__ __align__(16) unsigned short BD[512*64];
  __shared__ float sbias[512];
  int t = threadIdx.x;
  int base = off[c*CHN], cnt = off[(c+1)*CHN]-base;
  int e0 = blockIdx.x*64;
  if(e0 >= cnt) return;
  sbias[t]=bias[t]; sbias[256+t]=bias[256+t];
  #pragma unroll
  for(int i=0;i<16;i++){
    int idx=i*256+t; int n=idx>>3, kc=idx&7;
    short8 val = *(const short8*)(wbT + n*64 + kc*8);
    *(short8*)((char*)BD + n*128 + ((kc ^ (n&7))<<4)) = val;
  }
  int w=t>>6, l=t&63, lr=l&15, lg=l>>4;
  int row = w*16+lr;
  float d = (e0+row<cnt) ? ews[base+e0+row] : 1e9f;
  short8 a0, a1;
  {
    float edm = expf(-0.5f*d);
    float Cc = cutofff(d);
    const float start = expf(-10.0f);
    const float tmp = (2.0f/64.0f)*(1.0f-start);
    const float beta = 1.0f/(tmp*tmp);
    #pragma unroll
    for(int si=0;si<8;si++){
      float m0 = start + (1.0f-start)*((float)(lg*8+si)*(1.0f/63.0f));
      float m1 = start + (1.0f-start)*((float)(32+lg*8+si)*(1.0f/63.0f));
      float t0 = edm-m0, t1 = edm-m1;
      a0[si] = (short)f2bf(Cc*expf(-beta*t0*t0));
      a1[si] = (short)f2bf(Cc*expf(-beta*t1*t1));
    }
  }
  __syncthreads();
  unsigned pk[64];
  #pragma unroll
  for(int nt=0;nt<32;nt++){
    int n=nt*16+lr;
    const char* bp=(const char*)BD + n*128;
    short8 b0 = *(const short8*)(bp + (((lg  )^(n&7))<<4));
    short8 b1 = *(const short8*)(bp + (((4+lg)^(n&7))<<4));
    f32x4 acc={0.f,0.f,0.f,0.f};
    acc = __builtin_amdgcn_mfma_f32_16x16x32_bf16(a0,b0,acc,0,0,0);
    acc = __builtin_amdgcn_mfma_f32_16x16x32_bf16(a1,b1,acc,0,0,0);
    float bs=sbias[n];
    pk[nt*2+0] = ((unsigned)f2bf(siluf(acc[1]+bs))<<16)|f2bf(siluf(acc[0]+bs));
    pk[nt*2+1] = ((unsigned)f2bf(siluf(acc[3]+bs))<<16)|f2bf(siluf(acc[2]+bs));
  }
  __syncthreads();
  #pragma unroll
  for(int nt=0;nt<32;nt++){
    int n=nt*16+lr;
    #pragma unroll
    for(int rr=0;rr<4;rr++){
      int el = w*16+lg*4+rr;
      BD[el*512+n] = (unsigned short)(pk[nt*2+(rr>>1)]>>((rr&1)*16));
    }
  }
  __syncthreads();
  const short8* src=(const short8*)BD;
  short8* dst=(short8*)(dkvc + (size_t)e0*512);
  #pragma unroll
  for(int i=0;i<16;i++) dst[i*256+t]=src[i*256+t];
}

// ---------------- gather sweep: 4 nodes/block, no atomics ----------------
__global__ __launch_bounds__(128) void k_sweep(const unsigned short* __restrict__ qbf,
    const unsigned short* __restrict__ kbf, const unsigned short* __restrict__ vbf,
    const unsigned short* __restrict__ vecbf, const float* __restrict__ cw,
    const float* __restrict__ evs, const int* __restrict__ snds,
    const int* __restrict__ off, const unsigned short* __restrict__ dkvc,
    unsigned short* __restrict__ xaggbf, float* __restrict__ vecagg, int c){
  int j = threadIdx.x;
  int n0 = c*CHN + blockIdx.x*4;
  int base = off[c*CHN];
  int hc0 = (j>>4)*48 + (j&15);
  for(int nn=0;nn<4;nn++){
    int node = n0+nn;
    float qj = bf2f(qbf[(size_t)node*HDIM+j]);
    float xacc=0.f, va0=0.f, va1=0.f, va2=0.f;
    int ib=off[node], ie=off[node+1];
    for(int i=ib;i<ie;i++){
      int s = snds[i];
      const unsigned short* dr = dkvc + (size_t)(i-base)*512;
      float dk = bf2f(dr[j]);
      float prod = qj*bf2f(kbf[(size_t)s*HDIM+j])*dk;
      #pragma unroll
      for(int mm=1;mm<=8;mm<<=1) prod += __shfl_xor(prod,mm);
      float attn = siluf(prod)*cw[i];
      float b0=bf2f(dr[128+hc0]), b1=bf2f(dr[144+hc0]), b2=bf2f(dr[160+hc0]);
      const unsigned short* vs=vbf+(size_t)s*384;
      float vv0=bf2f(vs[hc0]), vv1=bf2f(vs[hc0+16]), vv2=bf2f(vs[hc0+32]);
      xacc += vv0*b0*attn;
      float s1v=vv1*b1, s2v=vv2*b2;
      va0 += bf2f(vecbf[((size_t)s*3+0)*HDIM+j])*s1v + s2v*evs[i*3+0];
      va1 += bf2f(vecbf[((size_t)s*3+1)*HDIM+j])*s1v + s2v*evs[i*3+1];
      va2 += bf2f(vecbf[((size_t)s*3+2)*HDIM+j])*s1v + s2v*evs[i*3+2];
    }
    xaggbf[(size_t)node*HDIM+j]=f2bf(xacc);
    vecagg[((size_t)node*3+0)*HDIM+j]=va0;
    vecagg[((size_t)node*3+1)*HDIM+j]=va1;
    vecagg[((size_t)node*3+2)*HDIM+j]=va2;
  }
}

// ---------------- node update: MFMA, 32 nodes/block ----------------
__global__ __launch_bounds__(256) void k_node_update_m(
    const unsigned short* __restrict__ xaggbf, const float* __restrict__ vdot,
    const float* __restrict__ vec3, const float* __restrict__ vecagg,
    const unsigned short* __restrict__ WoT, const float* __restrict__ bo,
    float* __restrict__ x, float* __restrict__ vec,
    unsigned short* __restrict__ vecbf, int l){
  int t = threadIdx.x, w = t>>6, lane = t&63;
  int n0 = blockIdx.x*32;
  int lr = lane&15, lg = lane>>4;
  int mt = w>>1, par = w&1;
  int rbase = mt*16;
  short8 a[4];
  #pragma unroll
  for(int kk=0;kk<4;kk++)
    a[kk] = *(const short8*)&xaggbf[(size_t)(n0+rbase+lr)*HDIM + kk*32+lg*8];
  const unsigned short* Bo = WoT + (size_t)l*384*128;
  for(int jj=0;jj<4;jj++){
    int j = jj*2+par;
    int col = j*16+lr;
    f32x4 ac1={0.f,0.f,0.f,0.f}, ac2={0.f,0.f,0.f,0.f}, ac3={0.f,0.f,0.f,0.f};
    #pragma unroll
    for(int kk=0;kk<4;kk++){
      ac1 = __builtin_amdgcn_mfma_f32_16x16x32_bf16(a[kk], *(const short8*)(Bo+(size_t)(col    )*128+kk*32+lg*8), ac1, 0,0,0);
      ac2 = __builtin_amdgcn_mfma_f32_16x16x32_bf16(a[kk], *(const short8*)(Bo+(size_t)(col+128)*128+kk*32+lg*8), ac2, 0,0,0);
      ac3 = __builtin_amdgcn_mfma_f32_16x16x32_bf16(a[kk], *(const short8*)(Bo+(size_t)(col+256)*128+kk*32+lg*8), ac3, 0,0,0);
    }
    float b1=bo[l*384+col], b2=bo[l*384+128+col], b3=bo[l*384+256+col];
    #pragma unroll
    for(int r=0;r<4;r++){
      int node = n0+rbase+lg*4+r;
      float o1=ac1[r]+b1, o2=ac2[r]+b2, o3=ac3[r]+b3;
      size_t xi = (size_t)node*HDIM+col;
      x[xi] += vdot[xi]*o2 + o3;
      #pragma unroll
      for(int sp=0;sp<3;sp++){
        size_t idx=((size_t)node*3+sp)*HDIM+col;
        float nv = vec[idx] + vec3[idx]*o1 + vecagg[idx];
        vec[idx]=nv; vecbf[idx]=f2bf(nv);
      }
    }
  }
}

// ---------------- final layernorm + output ----------------
__global__ void k_final(const float* __restrict__ x, const float* __restrict__ vec,
                        const float* __restrict__ g, const float* __restrict__ b,
                        float* __restrict__ out){
  int n=blockIdx.x; int t=threadIdx.x;
  float x0=x[(size_t)n*HDIM+t], x1=x[(size_t)n*HDIM+64+t];
  float sum=x0+x1;
  #pragma unroll
  for(int m=1;m<=32;m<<=1) sum += __shfl_xor(sum,m);
  float mean=sum*(1.f/128.f);
  float d0=x0-mean, d1=x1-mean;
  float vs=d0*d0+d1*d1;
  #pragma unroll
  for(int m=1;m<=32;m<<=1) vs += __shfl_xor(vs,m);
  float rstd=rsqrtf(vs*(1.f/128.f)+1e-6f);
  out[(size_t)n*HDIM+t]    = d0*rstd*g[t]+b[t];
  out[(size_t)n*HDIM+64+t] = d1*rstd*g[64+t]+b[64+t];
  float* ov = out + (size_t)NN*HDIM;
  for(int sp=0;sp<3;sp++){
    size_t idx=((size_t)n*3+sp)*HDIM;
    ov[idx+t]    = vec[idx+t];
    ov[idx+64+t] = vec[idx+64+t];
  }
}

extern "C" void kernel_launch(void* const* d_in, const int* in_sizes, int n_in,
                              void* d_out, int out_size, void* d_ws, size_t ws_size,
                              hipStream_t stream){
  const int*   z      = (const int*)  d_in[0];
  const float* pos    = (const float*)d_in[1];
  const int*   snd    = (const int*)  d_in[2];
  const int*   rcv    = (const int*)  d_in[3];
  const float* embed1 = (const float*)d_in[4];
  const float* embed2 = (const float*)d_in[5];
  const float* nbWd   = (const float*)d_in[6];
  const float* nbbd   = (const float*)d_in[7];
  const float* nbWc   = (const float*)d_in[8];
  const float* nbbc   = (const float*)d_in[9];
  const float* lng    = (const float*)d_in[10];
  const float* lnb    = (const float*)d_in[11];
  const float* Wq     = (const float*)d_in[12];
  const float* bq     = (const float*)d_in[13];
  const float* Wk     = (const float*)d_in[14];
  const float* bk     = (const float*)d_in[15];
  const float* Wv     = (const float*)d_in[16];
  const float* bv     = (const float*)d_in[17];
  const float* Wvec   = (const float*)d_in[18];
  const float* Wdk    = (const float*)d_in[19];
  const float* bdk    = (const float*)d_in[20];
  const float* Wdv    = (const float*)d_in[21];
  const float* bdv    = (const float*)d_in[22];
  const float* Wo     = (const float*)d_in[23];
  const float* bo     = (const float*)d_in[24];
  const float* cscale = (const float*)d_in[25];
  const float* lnfg   = (const float*)d_in[26];
  const float* lnfb   = (const float*)d_in[27];
  float* out = (float*)d_out;

  float* ws = (float*)d_ws;
  // big alias region: ew+evec (geom) -> msgc (nb) -> dkvc (layers)
  unsigned short* region = (unsigned short*)ws;  ws += (size_t)MAXCE*512/2;  // 37.75 MB
  float* ew   = (float*)region;
  float* evec = ew + NE;
  unsigned short* msgc = region;
  unsigned short* dkvc = region;

  float* ews   = ws;  ws += NE;
  float* cw    = ws;  ws += NE;
  float* evs   = ws;  ws += 3*NE;
  float* x     = ws;  ws += (size_t)NN*HDIM;
  float* vdot  = ws;  ws += (size_t)NN*HDIM;   // doubles as xnb pre-layers
  float* vec3  = ws;  ws += (size_t)NN*384;
  float* vecagg= ws;  ws += (size_t)NN*384;
  float* vec   = ws;  ws += (size_t)NN*384;
  float* bias512 = ws; ws += 512;
  int* deg    = (int*)ws; ws += NN;
  int* off    = (int*)ws; ws += NN+8;
  int* cursor = (int*)ws; ws += NN;
  int* eidx   = (int*)ws; ws += NE;
  int* snds   = (int*)ws; ws += NE;
  unsigned short* qbf   = (unsigned short*)ws;
  unsigned short* kbf   = qbf  + (size_t)NN*HDIM;
  unsigned short* vbf   = kbf  + (size_t)NN*HDIM;
  unsigned short* vecbf = vbf  + (size_t)NN*384;
  unsigned short* xaggbf= vecbf+ (size_t)NN*384;
  unsigned short* WqkvT = xaggbf+(size_t)NN*HDIM;
  unsigned short* WvecT = WqkvT + (size_t)4*640*128;
  unsigned short* WoT   = WvecT + (size_t)4*384*128;
  unsigned short* nbT   = WoT   + (size_t)4*384*128;
  unsigned short* wbT   = nbT   + (size_t)HDIM*NRBF;

  float* xnb = vdot;

  k_edge_geom<<<(NE+255)/256,256,0,stream>>>(pos,snd,rcv,ew,evec);
  hipMemsetAsync(deg,0,NN*4,stream);
  k_hist<<<NE/256,256,0,stream>>>(rcv,deg);
  k_scan<<<1,1024,0,stream>>>(deg,off,cursor);
  k_scatter<<<NE/256,256,0,stream>>>(rcv,cursor,eidx);
  k_permute<<<NE/256,256,0,stream>>>(eidx,ew,evec,snd,ews,cw,evs,snds);
  k_cvt_nbT<<<(HDIM*NRBF)/256,256,0,stream>>>(nbWd,nbT);
  k_nb_gemm<<<NE/64,256,0,stream>>>(ews,cw,snds,z,embed2,nbT,nbbd,msgc);
  k_nb_sweep<<<NN/8,128,0,stream>>>(off,msgc,xnb);
  k_combine_b<<<NN/16,256,0,stream>>>(z,embed1,xnb,nbWc,nbbc,x);
  hipMemsetAsync(vec,0,(size_t)NN*384*4,stream);
  hipMemsetAsync(vecbf,0,(size_t)NN*384*2,stream);
  k_cvt_qkvT<<<(4*640*128)/256,256,0,stream>>>(Wq,Wk,Wv,WqkvT);
  k_cvtT<<<(4*384*128)/256,256,0,stream>>>(Wvec,WvecT,384);
  k_cvtT<<<(4*384*128)/256,256,0,stream>>>(Wo,WoT,384);
  for(int l=0;l<NL;l++){
    k_wcvt<<<(512*64)/256,256,0,stream>>>(Wdk,Wdv,wbT,l);
    k_bcvt<<<2,256,0,stream>>>(bdk,bdv,bias512,l);
    k_node_pre_m<<<NN/32,256,0,stream>>>(x,vec,lng,lnb,bq,bk,bv,WqkvT,WvecT,cscale,
                                         qbf,kbf,vbf,vdot,vec3,l);
    for(int c=0;c<4;c++){
      k_dkv_chunk<<<MAXCE/64,256,0,stream>>>(ews,wbT,bias512,off,dkvc,c);
      k_sweep<<<CHN/4,128,0,stream>>>(qbf,kbf,vbf,vecbf,cw,evs,snds,off,dkvc,
                                      xaggbf,vecagg,c);
    }
    k_node_update_m<<<NN/32,256,0,stream>>>(xaggbf,vdot,vec3,vecagg,WoT,bo,x,vec,vecbf,l);
  }
  k_final<<<NN,64,0,stream>>>(x,vec,lnfg,lnfb,out);
}

// Round 6
// 1047.748 us; speedup vs baseline: 4.8303x; 1.3767x over previous
//
#include <hip/hip_runtime.h>
#include <math.h>

#define NN 16384
#define NE 131072
#define HDIM 128
#define NRBF 64
#define NL 4

typedef __attribute__((ext_vector_type(8))) short short8;
typedef __attribute__((ext_vector_type(4))) float f32x4;

__device__ __forceinline__ float siluf(float x){ return x / (1.0f + expf(-x)); }
__device__ __forceinline__ float cutofff(float d){
  return (d < 10.0f) ? 0.5f*(cosf(d*0.31415926535897932f)+1.0f) : 0.0f;
}
__device__ __forceinline__ unsigned short f2bf(float f){
  union{float f; unsigned u;} v; v.f = f;
  unsigned r = v.u + 0x7FFF + ((v.u>>16)&1);
  return (unsigned short)(r>>16);
}
__device__ __forceinline__ float bf2f(unsigned short b){
  union{unsigned u; float f;} v; v.u = ((unsigned)b)<<16;
  return v.f;
}

// ---------------- edge geometry ----------------
__global__ void k_edge_geom(const float* __restrict__ pos, const int* __restrict__ snd,
                            const int* __restrict__ rcv, float* __restrict__ ew,
                            float* __restrict__ evec){
  int e = blockIdx.x*blockDim.x + threadIdx.x;
  if(e >= NE) return;
  int s = snd[e], r = rcv[e];
  float dx = pos[r*3+0]-pos[s*3+0];
  float dy = pos[r*3+1]-pos[s*3+1];
  float dz = pos[r*3+2]-pos[s*3+2];
  const float eps = 1e-6f;
  float d = sqrtf((dx+eps)*(dx+eps)+(dy+eps)*(dy+eps)+(dz+eps)*(dz+eps));
  ew[e] = d;
  float mew = (s==r) ? 1.0f : d;
  mew = fmaxf(mew, 0.01f);
  float inv = 1.0f/mew;
  evec[e*3+0]=dx*inv; evec[e*3+1]=dy*inv; evec[e*3+2]=dz*inv;
}

// ---------------- CSR build ----------------
__global__ void k_hist(const int* __restrict__ rcv, int* __restrict__ deg){
  int e = blockIdx.x*256+threadIdx.x;
  if(e<NE) atomicAdd(&deg[rcv[e]],1);
}
__global__ __launch_bounds__(1024) void k_scan(const int* __restrict__ deg,
                                               int* __restrict__ off, int* __restrict__ cursor){
  __shared__ int part[1024];
  int t=threadIdx.x;
  int loc[16]; int s=0;
  #pragma unroll
  for(int i=0;i<16;i++){ loc[i]=s; s+=deg[t*16+i]; }
  part[t]=s; __syncthreads();
  for(int d=1;d<1024;d<<=1){
    int v=(t>=d)?part[t-d]:0; __syncthreads(); part[t]+=v; __syncthreads();
  }
  int excl = (t>0)?part[t-1]:0;
  #pragma unroll
  for(int i=0;i<16;i++){ int o=excl+loc[i]; off[t*16+i]=o; cursor[t*16+i]=o; }
  if(t==1023) off[NN]=part[1023];
}
__global__ void k_scatter(const int* __restrict__ rcv, int* __restrict__ cursor,
                          int* __restrict__ eidx){
  int e = blockIdx.x*256+threadIdx.x; if(e>=NE) return;
  int p = atomicAdd(&cursor[rcv[e]],1);
  eidx[p]=e;
}
__global__ void k_permute(const int* __restrict__ eidx, const float* __restrict__ ew,
                          const float* __restrict__ evec, const int* __restrict__ snd,
                          const int* __restrict__ rcv,
                          float* __restrict__ ews, float* __restrict__ cw,
                          float* __restrict__ evs, int* __restrict__ snds,
                          int* __restrict__ rcvs){
  int i = blockIdx.x*256+threadIdx.x; if(i>=NE) return;
  int e = eidx[i];
  float d = ew[e];
  ews[i]=d; cw[i]=cutofff(d);
  evs[i*3+0]=evec[e*3+0]; evs[i*3+1]=evec[e*3+1]; evs[i*3+2]=evec[e*3+2];
  snds[i]=snd[e]; rcvs[i]=rcv[e];
}

// ---------------- weight transposes to bf16 ----------------
__global__ void k_cvt_nbT(const float* __restrict__ Wd, unsigned short* __restrict__ dst){
  int o = blockIdx.x*256+threadIdx.x; if(o>=HDIM*NRBF) return;
  int n=o>>6, k=o&63;
  dst[o] = f2bf(Wd[k*HDIM+n]);
}
__global__ void k_cvt_qkvT(const float* __restrict__ Wq, const float* __restrict__ Wk,
                           const float* __restrict__ Wv, unsigned short* __restrict__ dst){
  int o = blockIdx.x*256+threadIdx.x;
  if(o >= 4*640*128) return;
  int l = o/81920; int rem = o - l*81920;
  int n = rem>>7, k = rem&127;
  float v;
  if(n<128)      v = Wq[(size_t)l*16384 + k*128 + n];
  else if(n<256) v = Wk[(size_t)l*16384 + k*128 + (n-128)];
  else           v = Wv[(size_t)l*49152 + k*384 + (n-256)];
  dst[o]=f2bf(v);
}
__global__ void k_cvtT(const float* __restrict__ src, unsigned short* __restrict__ dst, int NC){
  int o = blockIdx.x*256+threadIdx.x;
  int tot = 4*NC*128; if(o>=tot) return;
  int l = o/(NC*128); int rem = o - l*NC*128;
  int n = rem>>7, k = rem&127;
  dst[o] = f2bf(src[(size_t)l*128*NC + k*NC + n]);
}
__global__ void k_wcvt4(const float* __restrict__ Wdk, const float* __restrict__ Wdv,
                        unsigned short* __restrict__ wbT4){
  int o = blockIdx.x*blockDim.x + threadIdx.x;
  if(o >= 4*512*64) return;
  int l = o >> 15; int rem = o & 32767;
  int n = rem >> 6, kk = rem & 63;
  float v = (n < 128) ? Wdk[(size_t)l*NRBF*HDIM + kk*HDIM + n]
                      : Wdv[(size_t)l*NRBF*384 + kk*384 + (n-128)];
  wbT4[o] = f2bf(v);
}
__global__ void k_bcvt4(const float* __restrict__ bdk, const float* __restrict__ bdv,
                        float* __restrict__ bias4){
  int o = threadIdx.x + blockIdx.x*blockDim.x;
  if(o >= 4*512) return;
  int l = o >> 9, c = o & 511;
  bias4[o] = (c < 128) ? bdk[l*HDIM + c] : bdv[l*384 + (c-128)];
}

// ---------------- neighbor-embedding GEMM over sorted edges (no atomics) -----
__global__ __launch_bounds__(256) void k_nb_gemm(const float* __restrict__ ews,
    const float* __restrict__ cw, const int* __restrict__ snds,
    const int* __restrict__ z, const float* __restrict__ embed2,
    const unsigned short* __restrict__ nbT, const float* __restrict__ bd,
    unsigned short* __restrict__ msgc){
  __shared__ __align__(16) unsigned short Bl[HDIM*64];
  int t = threadIdx.x;
  int e0 = blockIdx.x*64;
  #pragma unroll
  for(int i=0;i<4;i++){
    int idx=i*256+t; int n=idx>>3, kc=idx&7;
    short8 val = *(const short8*)(nbT + n*64 + kc*8);
    *(short8*)((char*)Bl + n*128 + ((kc ^ (n&7))<<4)) = val;
  }
  int w=t>>6, l=t&63, lr=l&15, lg=l>>4;
  float d = ews[e0 + w*16 + lr];
  short8 a0, a1;
  {
    float edm = expf(-0.5f*d);
    float Cc = cutofff(d);
    const float start = expf(-10.0f);
    const float tmp = (2.0f/64.0f)*(1.0f-start);
    const float beta = 1.0f/(tmp*tmp);
    #pragma unroll
    for(int si=0;si<8;si++){
      float m0 = start + (1.0f-start)*((float)(lg*8+si)*(1.0f/63.0f));
      float m1 = start + (1.0f-start)*((float)(32+lg*8+si)*(1.0f/63.0f));
      float t0 = edm-m0, t1 = edm-m1;
      a0[si] = (short)f2bf(Cc*expf(-beta*t0*t0));
      a1[si] = (short)f2bf(Cc*expf(-beta*t1*t1));
    }
  }
  int sr[4]; float Cr[4]; int zz[4];
  #pragma unroll
  for(int r=0;r<4;r++){
    int i = e0 + w*16 + lg*4 + r;
    sr[r]=snds[i]; Cr[r]=cw[i]; zz[r]=z[sr[r]];
  }
  __syncthreads();
  #pragma unroll
  for(int nt=0;nt<8;nt++){
    int n=nt*16+lr;
    const char* bp=(const char*)Bl + n*128;
    short8 b0 = *(const short8*)(bp + (((lg  )^(n&7))<<4));
    short8 b1 = *(const short8*)(bp + (((4+lg)^(n&7))<<4));
    f32x4 acc={0.f,0.f,0.f,0.f};
    acc = __builtin_amdgcn_mfma_f32_16x16x32_bf16(a0,b0,acc,0,0,0);
    acc = __builtin_amdgcn_mfma_f32_16x16x32_bf16(a1,b1,acc,0,0,0);
    float bdn = bd[n];
    #pragma unroll
    for(int r=0;r<4;r++){
      float m = (acc[r]+bdn)*Cr[r]*embed2[(size_t)zz[r]*HDIM+n];
      msgc[(size_t)(e0+w*16+lg*4+r)*HDIM + n] = f2bf(m);
    }
  }
}
__global__ void k_nb_sweep(const int* __restrict__ off,
                           const unsigned short* __restrict__ msgc,
                           float* __restrict__ xnb){
  int j = threadIdx.x;                 // 128
  int n0 = blockIdx.x*8;
  for(int nn=0;nn<8;nn++){
    int node=n0+nn;
    float acc=0.f;
    int ib=off[node], ie=off[node+1];
    for(int i=ib;i<ie;i++) acc += bf2f(msgc[(size_t)i*HDIM+j]);
    xnb[(size_t)node*HDIM+j]=acc;
  }
}

// ---------------- combine, 16 nodes/block ----------------
__global__ __launch_bounds__(256) void k_combine_b(
    const int* __restrict__ z, const float* __restrict__ embed1,
    const float* __restrict__ xnb, const float* __restrict__ Wc,
    const float* __restrict__ bc, float* __restrict__ x){
  __shared__ float sx[16][2*HDIM];
  int t = threadIdx.x; int n0 = blockIdx.x*16;
  #pragma unroll
  for(int i=0;i<16;i++){
    int idx = i*256+t; int nn = idx>>8, c = idx&255;
    int n = n0+nn;
    sx[nn][c] = (c<128) ? embed1[(size_t)z[n]*HDIM + c]
                        : xnb[(size_t)n*HDIM + (c-128)];
  }
  __syncthreads();
  int j = t&127, g = t>>7;
  float bcj = bc[j];
  float acc[8];
  #pragma unroll
  for(int r=0;r<8;r++) acc[r]=bcj;
  for(int i=0;i<2*HDIM;i++){
    float wv = Wc[i*HDIM+j];
    #pragma unroll
    for(int r=0;r<8;r++) acc[r] += sx[2*r+g][i]*wv;
  }
  #pragma unroll
  for(int r=0;r<8;r++) x[(size_t)(n0+2*r+g)*HDIM+j] = acc[r];
}

// ---------------- node pre: LN/coorsnorm + MFMA GEMMs, 32 nodes/block ---------
#define PADR 136   // 128 + 8 ushorts (16B) pad -> 272B row stride
__global__ __launch_bounds__(256) void k_node_pre_m(
    const float* __restrict__ x, const float* __restrict__ vec,
    const float* __restrict__ lng, const float* __restrict__ lnb,
    const float* __restrict__ bq, const float* __restrict__ bk,
    const float* __restrict__ bv, const unsigned short* __restrict__ WqkvT,
    const unsigned short* __restrict__ WvecT, const float* __restrict__ cscale,
    unsigned short* __restrict__ qbf, unsigned short* __restrict__ kbf,
    unsigned short* __restrict__ vbf, float* __restrict__ vdot,
    float* __restrict__ vec3, int l){
  __shared__ unsigned short sxn[32][PADR];
  __shared__ unsigned short svn[3][32][PADR];
  int t = threadIdx.x, w = t>>6, lane = t&63;
  int n0 = blockIdx.x*32;
  float cs = cscale[l];
  float g0 = lng[l*HDIM+lane], g1 = lng[l*HDIM+64+lane];
  float be0 = lnb[l*HDIM+lane], be1 = lnb[l*HDIM+64+lane];
  for(int rr=0; rr<8; rr++){
    int nn = w*8+rr; int n = n0+nn;
    float x0 = x[(size_t)n*HDIM+lane], x1 = x[(size_t)n*HDIM+64+lane];
    float sum = x0+x1;
    #pragma unroll
    for(int m=1;m<=32;m<<=1) sum += __shfl_xor(sum,m);
    float mean = sum*(1.f/128.f);
    float d0 = x0-mean, d1 = x1-mean;
    float vs = d0*d0+d1*d1;
    #pragma unroll
    for(int m=1;m<=32;m<<=1) vs += __shfl_xor(vs,m);
    float rstd = rsqrtf(vs*(1.f/128.f)+1e-6f);
    sxn[nn][lane]    = f2bf(d0*rstd*g0 + be0);
    sxn[nn][64+lane] = f2bf(d1*rstd*g1 + be1);
    float va0 = vec[((size_t)n*3+0)*HDIM+lane], vb0 = vec[((size_t)n*3+0)*HDIM+64+lane];
    float va1 = vec[((size_t)n*3+1)*HDIM+lane], vb1 = vec[((size_t)n*3+1)*HDIM+64+lane];
    float va2 = vec[((size_t)n*3+2)*HDIM+lane], vb2 = vec[((size_t)n*3+2)*HDIM+64+lane];
    float iA = rsqrtf(fmaxf(va0*va0+va1*va1+va2*va2,1e-8f))*cs;
    float iB = rsqrtf(fmaxf(vb0*vb0+vb1*vb1+vb2*vb2,1e-8f))*cs;
    svn[0][nn][lane]=f2bf(va0*iA); svn[0][nn][64+lane]=f2bf(vb0*iB);
    svn[1][nn][lane]=f2bf(va1*iA); svn[1][nn][64+lane]=f2bf(vb1*iB);
    svn[2][nn][lane]=f2bf(va2*iA); svn[2][nn][64+lane]=f2bf(vb2*iB);
  }
  __syncthreads();
  int lr = lane&15, lg = lane>>4;
  int mt = w>>1, par = w&1;
  int rbase = mt*16;
  short8 a1[4];
  #pragma unroll
  for(int kk=0;kk<4;kk++) a1[kk] = *(const short8*)&sxn[rbase+lr][kk*32+lg*8];
  short8 a2[3][4];
  #pragma unroll
  for(int sp=0;sp<3;sp++)
    #pragma unroll
    for(int kk=0;kk<4;kk++) a2[sp][kk] = *(const short8*)&svn[sp][rbase+lr][kk*32+lg*8];

  const unsigned short* Bq = WqkvT + (size_t)l*640*128;
  for(int jj=0;jj<20;jj++){
    int j = jj*2+par;
    int col = j*16+lr;
    const unsigned short* bp = Bq + (size_t)col*128 + lg*8;
    f32x4 acc={0.f,0.f,0.f,0.f};
    #pragma unroll
    for(int kk=0;kk<4;kk++) acc = __builtin_amdgcn_mfma_f32_16x16x32_bf16(a1[kk], *(const short8*)(bp+kk*32), acc, 0,0,0);
    if(j < 16){
      float bias = (j<8) ? bq[l*HDIM+col] : bk[l*HDIM+col-128];
      float vv[4], s2[4];
      #pragma unroll
      for(int r=0;r<4;r++){ vv[r]=acc[r]+bias; s2[r]=vv[r]*vv[r]; }
      #pragma unroll
      for(int mm=1;mm<=8;mm<<=1){
        #pragma unroll
        for(int r=0;r<4;r++) s2[r] += __shfl_xor(s2[r],mm);
      }
      #pragma unroll
      for(int r=0;r<4;r++){
        int node = n0+rbase+lg*4+r;
        float vn_ = vv[r]/(sqrtf(s2[r])+1e-6f);
        if(j<8) qbf[(size_t)node*HDIM+col]     = f2bf(vn_);
        else    kbf[(size_t)node*HDIM+col-128] = f2bf(vn_);
      }
    } else {
      int c = col-256;
      float bias = bv[l*384+c];
      #pragma unroll
      for(int r=0;r<4;r++){
        int node = n0+rbase+lg*4+r;
        vbf[(size_t)node*384+c] = f2bf(acc[r]+bias);
      }
    }
  }
  const unsigned short* Bv = WvecT + (size_t)l*384*128;
  for(int jj=0;jj<4;jj++){
    int j = jj*2+par;
    int col = j*16+lr;
    short8 b1[4],b2[4],b3[4];
    #pragma unroll
    for(int kk=0;kk<4;kk++){
      b1[kk] = *(const short8*)(Bv + (size_t)(col    )*128 + kk*32+lg*8);
      b2[kk] = *(const short8*)(Bv + (size_t)(col+128)*128 + kk*32+lg*8);
      b3[kk] = *(const short8*)(Bv + (size_t)(col+256)*128 + kk*32+lg*8);
    }
    f32x4 vd={0.f,0.f,0.f,0.f};
    #pragma unroll
    for(int sp=0;sp<3;sp++){
      f32x4 p1={0.f,0.f,0.f,0.f}, p2={0.f,0.f,0.f,0.f}, p3={0.f,0.f,0.f,0.f};
      #pragma unroll
      for(int kk=0;kk<4;kk++){
        p1 = __builtin_amdgcn_mfma_f32_16x16x32_bf16(a2[sp][kk], b1[kk], p1, 0,0,0);
        p2 = __builtin_amdgcn_mfma_f32_16x16x32_bf16(a2[sp][kk], b2[kk], p2, 0,0,0);
        p3 = __builtin_amdgcn_mfma_f32_16x16x32_bf16(a2[sp][kk], b3[kk], p3, 0,0,0);
      }
      #pragma unroll
      for(int r=0;r<4;r++){
        vd[r] += p1[r]*p2[r];
        int node = n0+rbase+lg*4+r;
        vec3[((size_t)node*3+sp)*HDIM+col] = p3[r];
      }
    }
    #pragma unroll
    for(int r=0;r<4;r++){
      int node = n0+rbase+lg*4+r;
      vdot[(size_t)node*HDIM+col] = vd[r];
    }
  }
}

// ------- fused dk/dv GEMM + attention + segmented scatter, 64 sorted edges ----
__global__ __launch_bounds__(256) void k_edge_fused2(
    const float* __restrict__ ews, const float* __restrict__ cw,
    const float* __restrict__ evs, const int* __restrict__ snds,
    const int* __restrict__ rcvs,
    const unsigned short* __restrict__ qbf, const unsigned short* __restrict__ kbf,
    const unsigned short* __restrict__ vbf, const unsigned short* __restrict__ vecbf,
    const unsigned short* __restrict__ wbT, const float* __restrict__ bias,
    float* __restrict__ xagg, float* __restrict__ vecagg){
  __shared__ __align__(16) unsigned short BD[512*64];   // 64 KB: B panel -> dkv
  __shared__ float sbias[512];
  __shared__ float scw[64];
  __shared__ float sev[64*3];
  __shared__ int   ssnd[64];
  __shared__ int   srcv[64];
  int t = threadIdx.x;
  int e0 = blockIdx.x*64;
  if(t < 64){ scw[t]=cw[e0+t]; ssnd[t]=snds[e0+t]; srcv[t]=rcvs[e0+t]; }
  if(t < 192) sev[t] = evs[e0*3 + t];
  sbias[t]=bias[t]; sbias[256+t]=bias[256+t];
  #pragma unroll
  for(int i=0;i<16;i++){
    int idx=i*256+t; int n=idx>>3, kc=idx&7;
    short8 val = *(const short8*)(wbT + n*64 + kc*8);
    *(short8*)((char*)BD + n*128 + ((kc ^ (n&7))<<4)) = val;
  }
  int w=t>>6, l=t&63, lr=l&15, lg=l>>4;
  float d = ews[e0 + w*16 + lr];
  short8 a0, a1;
  {
    float edm = expf(-0.5f*d);
    float Cc = cutofff(d);
    const float start = expf(-10.0f);
    const float tmp = (2.0f/64.0f)*(1.0f-start);
    const float beta = 1.0f/(tmp*tmp);
    #pragma unroll
    for(int si=0;si<8;si++){
      float m0 = start + (1.0f-start)*((float)(lg*8+si)*(1.0f/63.0f));
      float m1 = start + (1.0f-start)*((float)(32+lg*8+si)*(1.0f/63.0f));
      float t0 = edm-m0, t1 = edm-m1;
      a0[si] = (short)f2bf(Cc*expf(-beta*t0*t0));
      a1[si] = (short)f2bf(Cc*expf(-beta*t1*t1));
    }
  }
  __syncthreads();
  unsigned pk[64];
  #pragma unroll
  for(int nt=0;nt<32;nt++){
    int n=nt*16+lr;
    const char* bp=(const char*)BD + n*128;
    short8 b0 = *(const short8*)(bp + (((lg  )^(n&7))<<4));
    short8 b1 = *(const short8*)(bp + (((4+lg)^(n&7))<<4));
    f32x4 acc={0.f,0.f,0.f,0.f};
    acc = __builtin_amdgcn_mfma_f32_16x16x32_bf16(a0,b0,acc,0,0,0);
    acc = __builtin_amdgcn_mfma_f32_16x16x32_bf16(a1,b1,acc,0,0,0);
    float bs=sbias[n];
    pk[nt*2+0] = ((unsigned)f2bf(siluf(acc[1]+bs))<<16)|f2bf(siluf(acc[0]+bs));
    pk[nt*2+1] = ((unsigned)f2bf(siluf(acc[3]+bs))<<16)|f2bf(siluf(acc[2]+bs));
  }
  __syncthreads();
  // write dkv[el][512] bf16 into BD, row-swizzled (R3-verified scheme)
  #pragma unroll
  for(int nt=0;nt<32;nt++){
    int n=nt*16+lr;
    #pragma unroll
    for(int rr=0;rr<4;rr++){
      int el = w*16+lg*4+rr;
      unsigned short val = (unsigned short)(pk[nt*2+(rr>>1)]>>((rr&1)*16));
      *(unsigned short*)((char*)BD + el*1024 + ((n*2) ^ ((el&7)<<4))) = val;
    }
  }
  __syncthreads();
  // phase 3: wave sweeps its 16 consecutive sorted edges; segmented reduction
  for(int half=0; half<2; half++){
    int jj = half*64 + l;
    int hc0 = (jj>>4)*48 + (jj&15);
    float ax=0.f, va0=0.f, va1=0.f, va2=0.f;
    int cur = srcv[w*16];
    int interior = 0;
    for(int e=0;e<16;e++){
      int el = w*16+e;
      int r = srcv[el];
      if(r != cur){
        if(interior){
          xagg[(size_t)cur*HDIM+jj]=ax;
          vecagg[((size_t)cur*3+0)*HDIM+jj]=va0;
          vecagg[((size_t)cur*3+1)*HDIM+jj]=va1;
          vecagg[((size_t)cur*3+2)*HDIM+jj]=va2;
        } else {
          atomicAdd(&xagg[(size_t)cur*HDIM+jj],ax);
          atomicAdd(&vecagg[((size_t)cur*3+0)*HDIM+jj],va0);
          atomicAdd(&vecagg[((size_t)cur*3+1)*HDIM+jj],va1);
          atomicAdd(&vecagg[((size_t)cur*3+2)*HDIM+jj],va2);
        }
        ax=va0=va1=va2=0.f; cur=r; interior=1;
      }
      int s = ssnd[el];
      const char* dbase = (const char*)BD + el*1024;
      int sw_ = (el&7)<<4;
      float dk = bf2f(*(const unsigned short*)(dbase + ((jj*2)^sw_)));
      float prod = bf2f(qbf[(size_t)r*HDIM+jj])*bf2f(kbf[(size_t)s*HDIM+jj])*dk;
      #pragma unroll
      for(int mm=1;mm<=8;mm<<=1) prod += __shfl_xor(prod, mm);
      float attn = siluf(prod)*scw[el];
      float b0 = bf2f(*(const unsigned short*)(dbase + (((128+hc0)*2)^sw_)));
      float b1 = bf2f(*(const unsigned short*)(dbase + (((144+hc0)*2)^sw_)));
      float b2 = bf2f(*(const unsigned short*)(dbase + (((160+hc0)*2)^sw_)));
      const unsigned short* vs = vbf + (size_t)s*384;
      float vv0=bf2f(vs[hc0]), vv1=bf2f(vs[hc0+16]), vv2=bf2f(vs[hc0+32]);
      ax += vv0*b0*attn;
      float s1v=vv1*b1, s2v=vv2*b2;
      va0 += bf2f(vecbf[((size_t)s*3+0)*HDIM+jj])*s1v + s2v*sev[el*3+0];
      va1 += bf2f(vecbf[((size_t)s*3+1)*HDIM+jj])*s1v + s2v*sev[el*3+1];
      va2 += bf2f(vecbf[((size_t)s*3+2)*HDIM+jj])*s1v + s2v*sev[el*3+2];
    }
    atomicAdd(&xagg[(size_t)cur*HDIM+jj],ax);
    atomicAdd(&vecagg[((size_t)cur*3+0)*HDIM+jj],va0);
    atomicAdd(&vecagg[((size_t)cur*3+1)*HDIM+jj],va1);
    atomicAdd(&vecagg[((size_t)cur*3+2)*HDIM+jj],va2);
  }
}

// ---------------- node update: MFMA, 32 nodes/block ----------------
__global__ __launch_bounds__(256) void k_node_update_m(
    const float* __restrict__ xagg, const float* __restrict__ vdot,
    const float* __restrict__ vec3, const float* __restrict__ vecagg,
    const unsigned short* __restrict__ WoT, const float* __restrict__ bo,
    float* __restrict__ x, float* __restrict__ vec,
    unsigned short* __restrict__ vecbf, int l){
  __shared__ unsigned short sxa[32][PADR];
  int t = threadIdx.x, w = t>>6, lane = t&63;
  int n0 = blockIdx.x*32;
  #pragma unroll
  for(int i=0;i<16;i++){
    int idx = i*256+t; int nn = idx>>7, j2 = idx&127;
    sxa[nn][j2] = f2bf(xagg[(size_t)(n0+nn)*HDIM + j2]);
  }
  __syncthreads();
  int lr = lane&15, lg = lane>>4;
  int mt = w>>1, par = w&1;
  int rbase = mt*16;
  short8 a[4];
  #pragma unroll
  for(int kk=0;kk<4;kk++)
    a[kk] = *(const short8*)&sxa[rbase+lr][kk*32+lg*8];
  const unsigned short* Bo = WoT + (size_t)l*384*128;
  for(int jj=0;jj<4;jj++){
    int j = jj*2+par;
    int col = j*16+lr;
    f32x4 ac1={0.f,0.f,0.f,0.f}, ac2={0.f,0.f,0.f,0.f}, ac3={0.f,0.f,0.f,0.f};
    #pragma unroll
    for(int kk=0;kk<4;kk++){
      ac1 = __builtin_amdgcn_mfma_f32_16x16x32_bf16(a[kk], *(const short8*)(Bo+(size_t)(col    )*128+kk*32+lg*8), ac1, 0,0,0);
      ac2 = __builtin_amdgcn_mfma_f32_16x16x32_bf16(a[kk], *(const short8*)(Bo+(size_t)(col+128)*128+kk*32+lg*8), ac2, 0,0,0);
      ac3 = __builtin_amdgcn_mfma_f32_16x16x32_bf16(a[kk], *(const short8*)(Bo+(size_t)(col+256)*128+kk*32+lg*8), ac3, 0,0,0);
    }
    float b1=bo[l*384+col], b2=bo[l*384+128+col], b3=bo[l*384+256+col];
    #pragma unroll
    for(int r=0;r<4;r++){
      int node = n0+rbase+lg*4+r;
      float o1=ac1[r]+b1, o2=ac2[r]+b2, o3=ac3[r]+b3;
      size_t xi = (size_t)node*HDIM+col;
      x[xi] += vdot[xi]*o2 + o3;
      #pragma unroll
      for(int sp=0;sp<3;sp++){
        size_t idx=((size_t)node*3+sp)*HDIM+col;
        float nv = vec[idx] + vec3[idx]*o1 + vecagg[idx];
        vec[idx]=nv; vecbf[idx]=f2bf(nv);
      }
    }
  }
}

// ---------------- final layernorm + output ----------------
__global__ void k_final(const float* __restrict__ x, const float* __restrict__ vec,
                        const float* __restrict__ g, const float* __restrict__ b,
                        float* __restrict__ out){
  int n=blockIdx.x; int t=threadIdx.x;
  float x0=x[(size_t)n*HDIM+t], x1=x[(size_t)n*HDIM+64+t];
  float sum=x0+x1;
  #pragma unroll
  for(int m=1;m<=32;m<<=1) sum += __shfl_xor(sum,m);
  float mean=sum*(1.f/128.f);
  float d0=x0-mean, d1=x1-mean;
  float vs=d0*d0+d1*d1;
  #pragma unroll
  for(int m=1;m<=32;m<<=1) vs += __shfl_xor(vs,m);
  float rstd=rsqrtf(vs*(1.f/128.f)+1e-6f);
  out[(size_t)n*HDIM+t]    = d0*rstd*g[t]+b[t];
  out[(size_t)n*HDIM+64+t] = d1*rstd*g[64+t]+b[64+t];
  float* ov = out + (size_t)NN*HDIM;
  for(int sp=0;sp<3;sp++){
    size_t idx=((size_t)n*3+sp)*HDIM;
    ov[idx+t]    = vec[idx+t];
    ov[idx+64+t] = vec[idx+64+t];
  }
}

extern "C" void kernel_launch(void* const* d_in, const int* in_sizes, int n_in,
                              void* d_out, int out_size, void* d_ws, size_t ws_size,
                              hipStream_t stream){
  const int*   z      = (const int*)  d_in[0];
  const float* pos    = (const float*)d_in[1];
  const int*   snd    = (const int*)  d_in[2];
  const int*   rcv    = (const int*)  d_in[3];
  const float* embed1 = (const float*)d_in[4];
  const float* embed2 = (const float*)d_in[5];
  const float* nbWd   = (const float*)d_in[6];
  const float* nbbd   = (const float*)d_in[7];
  const float* nbWc   = (const float*)d_in[8];
  const float* nbbc   = (const float*)d_in[9];
  const float* lng    = (const float*)d_in[10];
  const float* lnb    = (const float*)d_in[11];
  const float* Wq     = (const float*)d_in[12];
  const float* bq     = (const float*)d_in[13];
  const float* Wk     = (const float*)d_in[14];
  const float* bk     = (const float*)d_in[15];
  const float* Wv     = (const float*)d_in[16];
  const float* bv     = (const float*)d_in[17];
  const float* Wvec   = (const float*)d_in[18];
  const float* Wdk    = (const float*)d_in[19];
  const float* bdk    = (const float*)d_in[20];
  const float* Wdv    = (const float*)d_in[21];
  const float* bdv    = (const float*)d_in[22];
  const float* Wo     = (const float*)d_in[23];
  const float* bo     = (const float*)d_in[24];
  const float* cscale = (const float*)d_in[25];
  const float* lnfg   = (const float*)d_in[26];
  const float* lnfb   = (const float*)d_in[27];
  float* out = (float*)d_out;

  float* ws = (float*)d_ws;
  // alias region: ew+evec (geometry) -> msgc (nb stage)
  unsigned short* region = (unsigned short*)ws;  ws += (size_t)NE*HDIM/2;  // 33.5 MB
  float* ew   = (float*)region;
  float* evec = ew + NE;
  unsigned short* msgc = region;

  float* ews   = ws;  ws += NE;
  float* cw    = ws;  ws += NE;
  float* evs   = ws;  ws += 3*NE;
  float* x     = ws;  ws += (size_t)NN*HDIM;
  float* vdot  = ws;  ws += (size_t)NN*HDIM;   // doubles as xnb pre-layers
  float* xagg  = ws;  ws += (size_t)NN*HDIM;
  float* vec3  = ws;  ws += (size_t)NN*384;
  float* vecagg= ws;  ws += (size_t)NN*384;
  float* vec   = ws;  ws += (size_t)NN*384;
  float* bias4 = ws;  ws += 4*512;
  int* deg    = (int*)ws; ws += NN;
  int* off    = (int*)ws; ws += NN+8;
  int* cursor = (int*)ws; ws += NN;
  int* eidx   = (int*)ws; ws += NE;
  int* snds   = (int*)ws; ws += NE;
  int* rcvs   = (int*)ws; ws += NE;
  unsigned short* qbf   = (unsigned short*)ws;
  unsigned short* kbf   = qbf  + (size_t)NN*HDIM;
  unsigned short* vbf   = kbf  + (size_t)NN*HDIM;
  unsigned short* vecbf = vbf  + (size_t)NN*384;
  unsigned short* WqkvT = vecbf+ (size_t)NN*384;
  unsigned short* WvecT = WqkvT + (size_t)4*640*128;
  unsigned short* WoT   = WvecT + (size_t)4*384*128;
  unsigned short* nbT   = WoT   + (size_t)4*384*128;
  unsigned short* wbT4  = nbT   + (size_t)HDIM*NRBF;

  float* xnb = vdot;

  k_edge_geom<<<(NE+255)/256,256,0,stream>>>(pos,snd,rcv,ew,evec);
  hipMemsetAsync(deg,0,NN*4,stream);
  k_hist<<<NE/256,256,0,stream>>>(rcv,deg);
  k_scan<<<1,1024,0,stream>>>(deg,off,cursor);
  k_scatter<<<NE/256,256,0,stream>>>(rcv,cursor,eidx);
  k_permute<<<NE/256,256,0,stream>>>(eidx,ew,evec,snd,rcv,ews,cw,evs,snds,rcvs);
  k_cvt_nbT<<<(HDIM*NRBF)/256,256,0,stream>>>(nbWd,nbT);
  k_nb_gemm<<<NE/64,256,0,stream>>>(ews,cw,snds,z,embed2,nbT,nbbd,msgc);
  k_nb_sweep<<<NN/8,128,0,stream>>>(off,msgc,xnb);
  k_combine_b<<<NN/16,256,0,stream>>>(z,embed1,xnb,nbWc,nbbc,x);
  hipMemsetAsync(vec,0,(size_t)NN*384*4,stream);
  hipMemsetAsync(vecbf,0,(size_t)NN*384*2,stream);
  k_cvt_qkvT<<<(4*640*128)/256,256,0,stream>>>(Wq,Wk,Wv,WqkvT);
  k_cvtT<<<(4*384*128)/256,256,0,stream>>>(Wvec,WvecT,384);
  k_cvtT<<<(4*384*128)/256,256,0,stream>>>(Wo,WoT,384);
  k_wcvt4<<<(4*512*64)/256,256,0,stream>>>(Wdk,Wdv,wbT4);
  k_bcvt4<<<8,256,0,stream>>>(bdk,bdv,bias4);
  for(int l=0;l<NL;l++){
    k_node_pre_m<<<NN/32,256,0,stream>>>(x,vec,lng,lnb,bq,bk,bv,WqkvT,WvecT,cscale,
                                         qbf,kbf,vbf,vdot,vec3,l);
    hipMemsetAsync(xagg,0,(size_t)NN*HDIM*4,stream);
    hipMemsetAsync(vecagg,0,(size_t)NN*384*4,stream);
    k_edge_fused2<<<NE/64,256,0,stream>>>(ews,cw,evs,snds,rcvs,qbf,kbf,vbf,vecbf,
                                          wbT4 + (size_t)l*512*64, bias4 + l*512,
                                          xagg,vecagg);
    k_node_update_m<<<NN/32,256,0,stream>>>(xagg,vdot,vec3,vecagg,WoT,bo,x,vec,vecbf,l);
  }
  k_final<<<NN,64,0,stream>>>(x,vec,lnfg,lnfb,out);
}

// Round 7
// 929.300 us; speedup vs baseline: 5.4460x; 1.1275x over previous
//
#include <hip/hip_runtime.h>
#include <math.h>

#define NN 16384
#define NE 131072
#define HDIM 128
#define NRBF 64
#define NL 4

typedef __attribute__((ext_vector_type(8))) short short8;
typedef __attribute__((ext_vector_type(4))) float f32x4;
typedef __attribute__((ext_vector_type(2))) float f32x2;

__device__ __forceinline__ float siluf(float x){ return x / (1.0f + expf(-x)); }
__device__ __forceinline__ float cutofff(float d){
  return (d < 10.0f) ? 0.5f*(cosf(d*0.31415926535897932f)+1.0f) : 0.0f;
}
__device__ __forceinline__ unsigned short f2bf(float f){
  union{float f; unsigned u;} v; v.f = f;
  unsigned r = v.u + 0x7FFF + ((v.u>>16)&1);
  return (unsigned short)(r>>16);
}
__device__ __forceinline__ float bf2f(unsigned short b){
  union{unsigned u; float f;} v; v.u = ((unsigned)b)<<16;
  return v.f;
}
__device__ __forceinline__ float bflo(unsigned u){
  union{unsigned x; float f;} v; v.x = u<<16; return v.f;
}
__device__ __forceinline__ float bfhi(unsigned u){
  union{unsigned x; float f;} v; v.x = u & 0xffff0000u; return v.f;
}

// ---------------- edge geometry ----------------
__global__ void k_edge_geom(const float* __restrict__ pos, const int* __restrict__ snd,
                            const int* __restrict__ rcv, float* __restrict__ ew,
                            float* __restrict__ evec){
  int e = blockIdx.x*blockDim.x + threadIdx.x;
  if(e >= NE) return;
  int s = snd[e], r = rcv[e];
  float dx = pos[r*3+0]-pos[s*3+0];
  float dy = pos[r*3+1]-pos[s*3+1];
  float dz = pos[r*3+2]-pos[s*3+2];
  const float eps = 1e-6f;
  float d = sqrtf((dx+eps)*(dx+eps)+(dy+eps)*(dy+eps)+(dz+eps)*(dz+eps));
  ew[e] = d;
  float mew = (s==r) ? 1.0f : d;
  mew = fmaxf(mew, 0.01f);
  float inv = 1.0f/mew;
  evec[e*3+0]=dx*inv; evec[e*3+1]=dy*inv; evec[e*3+2]=dz*inv;
}

// ---------------- CSR build ----------------
__global__ void k_hist(const int* __restrict__ rcv, int* __restrict__ deg){
  int e = blockIdx.x*256+threadIdx.x;
  if(e<NE) atomicAdd(&deg[rcv[e]],1);
}
__global__ __launch_bounds__(1024) void k_scan(const int* __restrict__ deg,
                                               int* __restrict__ off, int* __restrict__ cursor){
  __shared__ int part[1024];
  int t=threadIdx.x;
  int loc[16]; int s=0;
  #pragma unroll
  for(int i=0;i<16;i++){ loc[i]=s; s+=deg[t*16+i]; }
  part[t]=s; __syncthreads();
  for(int d=1;d<1024;d<<=1){
    int v=(t>=d)?part[t-d]:0; __syncthreads(); part[t]+=v; __syncthreads();
  }
  int excl = (t>0)?part[t-1]:0;
  #pragma unroll
  for(int i=0;i<16;i++){ int o=excl+loc[i]; off[t*16+i]=o; cursor[t*16+i]=o; }
  if(t==1023) off[NN]=part[1023];
}
__global__ void k_scatter(const int* __restrict__ rcv, int* __restrict__ cursor,
                          int* __restrict__ eidx){
  int e = blockIdx.x*256+threadIdx.x; if(e>=NE) return;
  int p = atomicAdd(&cursor[rcv[e]],1);
  eidx[p]=e;
}
__global__ void k_permute(const int* __restrict__ eidx, const float* __restrict__ ew,
                          const float* __restrict__ evec, const int* __restrict__ snd,
                          const int* __restrict__ rcv,
                          float* __restrict__ ews, float* __restrict__ cw,
                          float* __restrict__ evs, int* __restrict__ snds,
                          int* __restrict__ rcvs){
  int i = blockIdx.x*256+threadIdx.x; if(i>=NE) return;
  int e = eidx[i];
  float d = ew[e];
  ews[i]=d; cw[i]=cutofff(d);
  evs[i*3+0]=evec[e*3+0]; evs[i*3+1]=evec[e*3+1]; evs[i*3+2]=evec[e*3+2];
  snds[i]=snd[e]; rcvs[i]=rcv[e];
}

// ---------------- weight transposes to bf16 ----------------
__global__ void k_cvt_nbT(const float* __restrict__ Wd, unsigned short* __restrict__ dst){
  int o = blockIdx.x*256+threadIdx.x; if(o>=HDIM*NRBF) return;
  int n=o>>6, k=o&63;
  dst[o] = f2bf(Wd[k*HDIM+n]);
}
__global__ void k_cvt_qkvT(const float* __restrict__ Wq, const float* __restrict__ Wk,
                           const float* __restrict__ Wv, unsigned short* __restrict__ dst){
  int o = blockIdx.x*256+threadIdx.x;
  if(o >= 4*640*128) return;
  int l = o/81920; int rem = o - l*81920;
  int n = rem>>7, k = rem&127;
  float v;
  if(n<128)      v = Wq[(size_t)l*16384 + k*128 + n];
  else if(n<256) v = Wk[(size_t)l*16384 + k*128 + (n-128)];
  else           v = Wv[(size_t)l*49152 + k*384 + (n-256)];
  dst[o]=f2bf(v);
}
__global__ void k_cvtT(const float* __restrict__ src, unsigned short* __restrict__ dst, int NC){
  int o = blockIdx.x*256+threadIdx.x;
  int tot = 4*NC*128; if(o>=tot) return;
  int l = o/(NC*128); int rem = o - l*NC*128;
  int n = rem>>7, k = rem&127;
  dst[o] = f2bf(src[(size_t)l*128*NC + k*NC + n]);
}
__global__ void k_wcvt4(const float* __restrict__ Wdk, const float* __restrict__ Wdv,
                        unsigned short* __restrict__ wbT4){
  int o = blockIdx.x*blockDim.x + threadIdx.x;
  if(o >= 4*512*64) return;
  int l = o >> 15; int rem = o & 32767;
  int n = rem >> 6, kk = rem & 63;
  float v = (n < 128) ? Wdk[(size_t)l*NRBF*HDIM + kk*HDIM + n]
                      : Wdv[(size_t)l*NRBF*384 + kk*384 + (n-128)];
  wbT4[o] = f2bf(v);
}
__global__ void k_bcvt4(const float* __restrict__ bdk, const float* __restrict__ bdv,
                        float* __restrict__ bias4){
  int o = threadIdx.x + blockIdx.x*blockDim.x;
  if(o >= 4*512) return;
  int l = o >> 9, c = o & 511;
  bias4[o] = (c < 128) ? bdk[l*HDIM + c] : bdv[l*384 + (c-128)];
}

// ---------------- neighbor-embedding GEMM over sorted edges (no atomics) -----
__global__ __launch_bounds__(256) void k_nb_gemm(const float* __restrict__ ews,
    const float* __restrict__ cw, const int* __restrict__ snds,
    const int* __restrict__ z, const float* __restrict__ embed2,
    const unsigned short* __restrict__ nbT, const float* __restrict__ bd,
    unsigned short* __restrict__ msgc){
  __shared__ __align__(16) unsigned short Bl[HDIM*64];
  int t = threadIdx.x;
  int e0 = blockIdx.x*64;
  #pragma unroll
  for(int i=0;i<4;i++){
    int idx=i*256+t; int n=idx>>3, kc=idx&7;
    short8 val = *(const short8*)(nbT + n*64 + kc*8);
    *(short8*)((char*)Bl + n*128 + ((kc ^ (n&7))<<4)) = val;
  }
  int w=t>>6, l=t&63, lr=l&15, lg=l>>4;
  float d = ews[e0 + w*16 + lr];
  short8 a0, a1;
  {
    float edm = expf(-0.5f*d);
    float Cc = cutofff(d);
    const float start = expf(-10.0f);
    const float tmp = (2.0f/64.0f)*(1.0f-start);
    const float beta = 1.0f/(tmp*tmp);
    #pragma unroll
    for(int si=0;si<8;si++){
      float m0 = start + (1.0f-start)*((float)(lg*8+si)*(1.0f/63.0f));
      float m1 = start + (1.0f-start)*((float)(32+lg*8+si)*(1.0f/63.0f));
      float t0 = edm-m0, t1 = edm-m1;
      a0[si] = (short)f2bf(Cc*expf(-beta*t0*t0));
      a1[si] = (short)f2bf(Cc*expf(-beta*t1*t1));
    }
  }
  int sr[4]; float Cr[4]; int zz[4];
  #pragma unroll
  for(int r=0;r<4;r++){
    int i = e0 + w*16 + lg*4 + r;
    sr[r]=snds[i]; Cr[r]=cw[i]; zz[r]=z[sr[r]];
  }
  __syncthreads();
  #pragma unroll
  for(int nt=0;nt<8;nt++){
    int n=nt*16+lr;
    const char* bp=(const char*)Bl + n*128;
    short8 b0 = *(const short8*)(bp + (((lg  )^(n&7))<<4));
    short8 b1 = *(const short8*)(bp + (((4+lg)^(n&7))<<4));
    f32x4 acc={0.f,0.f,0.f,0.f};
    acc = __builtin_amdgcn_mfma_f32_16x16x32_bf16(a0,b0,acc,0,0,0);
    acc = __builtin_amdgcn_mfma_f32_16x16x32_bf16(a1,b1,acc,0,0,0);
    float bdn = bd[n];
    #pragma unroll
    for(int r=0;r<4;r++){
      float m = (acc[r]+bdn)*Cr[r]*embed2[(size_t)zz[r]*HDIM+n];
      msgc[(size_t)(e0+w*16+lg*4+r)*HDIM + n] = f2bf(m);
    }
  }
}
__global__ void k_nb_sweep(const int* __restrict__ off,
                           const unsigned short* __restrict__ msgc,
                           float* __restrict__ xnb){
  int j = threadIdx.x;                 // 128
  int n0 = blockIdx.x*8;
  for(int nn=0;nn<8;nn++){
    int node=n0+nn;
    float acc=0.f;
    int ib=off[node], ie=off[node+1];
    for(int i=ib;i<ie;i++) acc += bf2f(msgc[(size_t)i*HDIM+j]);
    xnb[(size_t)node*HDIM+j]=acc;
  }
}

// ---------------- combine, 16 nodes/block ----------------
__global__ __launch_bounds__(256) void k_combine_b(
    const int* __restrict__ z, const float* __restrict__ embed1,
    const float* __restrict__ xnb, const float* __restrict__ Wc,
    const float* __restrict__ bc, float* __restrict__ x){
  __shared__ float sx[16][2*HDIM];
  int t = threadIdx.x; int n0 = blockIdx.x*16;
  #pragma unroll
  for(int i=0;i<16;i++){
    int idx = i*256+t; int nn = idx>>8, c = idx&255;
    int n = n0+nn;
    sx[nn][c] = (c<128) ? embed1[(size_t)z[n]*HDIM + c]
                        : xnb[(size_t)n*HDIM + (c-128)];
  }
  __syncthreads();
  int j = t&127, g = t>>7;
  float bcj = bc[j];
  float acc[8];
  #pragma unroll
  for(int r=0;r<8;r++) acc[r]=bcj;
  for(int i=0;i<2*HDIM;i++){
    float wv = Wc[i*HDIM+j];
    #pragma unroll
    for(int r=0;r<8;r++) acc[r] += sx[2*r+g][i]*wv;
  }
  #pragma unroll
  for(int r=0;r<8;r++) x[(size_t)(n0+2*r+g)*HDIM+j] = acc[r];
}

// ---------------- node pre: LN/coorsnorm + MFMA GEMMs, 32 nodes/block ---------
#define PADR 136   // 128 + 8 ushorts pad
__global__ __launch_bounds__(256) void k_node_pre_m(
    const float* __restrict__ x, const float* __restrict__ vec,
    const float* __restrict__ lng, const float* __restrict__ lnb,
    const float* __restrict__ bq, const float* __restrict__ bk,
    const float* __restrict__ bv, const unsigned short* __restrict__ WqkvT,
    const unsigned short* __restrict__ WvecT, const float* __restrict__ cscale,
    unsigned short* __restrict__ qbf, unsigned short* __restrict__ kbf,
    unsigned short* __restrict__ vbf, float* __restrict__ vdot,
    float* __restrict__ vec3, int l){
  __shared__ unsigned short sxn[32][PADR];
  __shared__ unsigned short svn[3][32][PADR];
  int t = threadIdx.x, w = t>>6, lane = t&63;
  int n0 = blockIdx.x*32;
  float cs = cscale[l];
  float g0 = lng[l*HDIM+lane], g1 = lng[l*HDIM+64+lane];
  float be0 = lnb[l*HDIM+lane], be1 = lnb[l*HDIM+64+lane];
  for(int rr=0; rr<8; rr++){
    int nn = w*8+rr; int n = n0+nn;
    float x0 = x[(size_t)n*HDIM+lane], x1 = x[(size_t)n*HDIM+64+lane];
    float sum = x0+x1;
    #pragma unroll
    for(int m=1;m<=32;m<<=1) sum += __shfl_xor(sum,m);
    float mean = sum*(1.f/128.f);
    float d0 = x0-mean, d1 = x1-mean;
    float vs = d0*d0+d1*d1;
    #pragma unroll
    for(int m=1;m<=32;m<<=1) vs += __shfl_xor(vs,m);
    float rstd = rsqrtf(vs*(1.f/128.f)+1e-6f);
    sxn[nn][lane]    = f2bf(d0*rstd*g0 + be0);
    sxn[nn][64+lane] = f2bf(d1*rstd*g1 + be1);
    float va0 = vec[((size_t)n*3+0)*HDIM+lane], vb0 = vec[((size_t)n*3+0)*HDIM+64+lane];
    float va1 = vec[((size_t)n*3+1)*HDIM+lane], vb1 = vec[((size_t)n*3+1)*HDIM+64+lane];
    float va2 = vec[((size_t)n*3+2)*HDIM+lane], vb2 = vec[((size_t)n*3+2)*HDIM+64+lane];
    float iA = rsqrtf(fmaxf(va0*va0+va1*va1+va2*va2,1e-8f))*cs;
    float iB = rsqrtf(fmaxf(vb0*vb0+vb1*vb1+vb2*vb2,1e-8f))*cs;
    svn[0][nn][lane]=f2bf(va0*iA); svn[0][nn][64+lane]=f2bf(vb0*iB);
    svn[1][nn][lane]=f2bf(va1*iA); svn[1][nn][64+lane]=f2bf(vb1*iB);
    svn[2][nn][lane]=f2bf(va2*iA); svn[2][nn][64+lane]=f2bf(vb2*iB);
  }
  __syncthreads();
  int lr = lane&15, lg = lane>>4;
  int mt = w>>1, par = w&1;
  int rbase = mt*16;
  short8 a1[4];
  #pragma unroll
  for(int kk=0;kk<4;kk++) a1[kk] = *(const short8*)&sxn[rbase+lr][kk*32+lg*8];
  short8 a2[3][4];
  #pragma unroll
  for(int sp=0;sp<3;sp++)
    #pragma unroll
    for(int kk=0;kk<4;kk++) a2[sp][kk] = *(const short8*)&svn[sp][rbase+lr][kk*32+lg*8];

  const unsigned short* Bq = WqkvT + (size_t)l*640*128;
  for(int jj=0;jj<20;jj++){
    int j = jj*2+par;
    int col = j*16+lr;
    const unsigned short* bp = Bq + (size_t)col*128 + lg*8;
    f32x4 acc={0.f,0.f,0.f,0.f};
    #pragma unroll
    for(int kk=0;kk<4;kk++) acc = __builtin_amdgcn_mfma_f32_16x16x32_bf16(a1[kk], *(const short8*)(bp+kk*32), acc, 0,0,0);
    if(j < 16){
      float bias = (j<8) ? bq[l*HDIM+col] : bk[l*HDIM+col-128];
      float vv[4], s2[4];
      #pragma unroll
      for(int r=0;r<4;r++){ vv[r]=acc[r]+bias; s2[r]=vv[r]*vv[r]; }
      #pragma unroll
      for(int mm=1;mm<=8;mm<<=1){
        #pragma unroll
        for(int r=0;r<4;r++) s2[r] += __shfl_xor(s2[r],mm);
      }
      #pragma unroll
      for(int r=0;r<4;r++){
        int node = n0+rbase+lg*4+r;
        float vn_ = vv[r]/(sqrtf(s2[r])+1e-6f);
        if(j<8) qbf[(size_t)node*HDIM+col]     = f2bf(vn_);
        else    kbf[(size_t)node*HDIM+col-128] = f2bf(vn_);
      }
    } else {
      int c = col-256;
      float bias = bv[l*384+c];
      #pragma unroll
      for(int r=0;r<4;r++){
        int node = n0+rbase+lg*4+r;
        vbf[(size_t)node*384+c] = f2bf(acc[r]+bias);
      }
    }
  }
  const unsigned short* Bv = WvecT + (size_t)l*384*128;
  for(int jj=0;jj<4;jj++){
    int j = jj*2+par;
    int col = j*16+lr;
    short8 b1[4],b2[4],b3[4];
    #pragma unroll
    for(int kk=0;kk<4;kk++){
      b1[kk] = *(const short8*)(Bv + (size_t)(col    )*128 + kk*32+lg*8);
      b2[kk] = *(const short8*)(Bv + (size_t)(col+128)*128 + kk*32+lg*8);
      b3[kk] = *(const short8*)(Bv + (size_t)(col+256)*128 + kk*32+lg*8);
    }
    f32x4 vd={0.f,0.f,0.f,0.f};
    #pragma unroll
    for(int sp=0;sp<3;sp++){
      f32x4 p1={0.f,0.f,0.f,0.f}, p2={0.f,0.f,0.f,0.f}, p3={0.f,0.f,0.f,0.f};
      #pragma unroll
      for(int kk=0;kk<4;kk++){
        p1 = __builtin_amdgcn_mfma_f32_16x16x32_bf16(a2[sp][kk], b1[kk], p1, 0,0,0);
        p2 = __builtin_amdgcn_mfma_f32_16x16x32_bf16(a2[sp][kk], b2[kk], p2, 0,0,0);
        p3 = __builtin_amdgcn_mfma_f32_16x16x32_bf16(a2[sp][kk], b3[kk], p3, 0,0,0);
      }
      #pragma unroll
      for(int r=0;r<4;r++){
        vd[r] += p1[r]*p2[r];
        int node = n0+rbase+lg*4+r;
        vec3[((size_t)node*3+sp)*HDIM+col] = p3[r];
      }
    }
    #pragma unroll
    for(int r=0;r<4;r++){
      int node = n0+rbase+lg*4+r;
      vdot[(size_t)node*HDIM+col] = vd[r];
    }
  }
}

// ------- fused dk/dv GEMM + attention + segmented scatter, 64 sorted edges ----
__global__ __launch_bounds__(256) void k_edge_fused2(
    const float* __restrict__ ews, const float* __restrict__ cw,
    const float* __restrict__ evs, const int* __restrict__ snds,
    const int* __restrict__ rcvs,
    const unsigned short* __restrict__ qbf, const unsigned short* __restrict__ kbf,
    const unsigned short* __restrict__ vbf, const unsigned short* __restrict__ vecbf,
    const unsigned short* __restrict__ wbT, const float* __restrict__ bias,
    float* __restrict__ xagg, float* __restrict__ vecagg){
  __shared__ __align__(16) unsigned short BD[512*64];   // 64 KB: B panel -> dkv
  __shared__ float sbias[512];
  __shared__ float scw[64];
  __shared__ float sev[64*3];
  __shared__ int   ssnd[64];
  __shared__ int   srcv[64];
  int t = threadIdx.x;
  int e0 = blockIdx.x*64;
  if(t < 64){ scw[t]=cw[e0+t]; ssnd[t]=snds[e0+t]; srcv[t]=rcvs[e0+t]; }
  if(t < 192) sev[t] = evs[e0*3 + t];
  sbias[t]=bias[t]; sbias[256+t]=bias[256+t];
  #pragma unroll
  for(int i=0;i<16;i++){
    int idx=i*256+t; int n=idx>>3, kc=idx&7;
    short8 val = *(const short8*)(wbT + n*64 + kc*8);
    *(short8*)((char*)BD + n*128 + ((kc ^ (n&7))<<4)) = val;
  }
  int w=t>>6, l=t&63, lr=l&15, lg=l>>4;
  float d = ews[e0 + w*16 + lr];
  short8 a0, a1;
  {
    float edm = expf(-0.5f*d);
    float Cc = cutofff(d);
    const float start = expf(-10.0f);
    const float tmp = (2.0f/64.0f)*(1.0f-start);
    const float beta = 1.0f/(tmp*tmp);
    #pragma unroll
    for(int si=0;si<8;si++){
      float m0 = start + (1.0f-start)*((float)(lg*8+si)*(1.0f/63.0f));
      float m1 = start + (1.0f-start)*((float)(32+lg*8+si)*(1.0f/63.0f));
      float t0 = edm-m0, t1 = edm-m1;
      a0[si] = (short)f2bf(Cc*expf(-beta*t0*t0));
      a1[si] = (short)f2bf(Cc*expf(-beta*t1*t1));
    }
  }
  __syncthreads();
  unsigned pk[64];
  #pragma unroll
  for(int nt=0;nt<32;nt++){
    int n=nt*16+lr;
    const char* bp=(const char*)BD + n*128;
    short8 b0 = *(const short8*)(bp + (((lg  )^(n&7))<<4));
    short8 b1 = *(const short8*)(bp + (((4+lg)^(n&7))<<4));
    f32x4 acc={0.f,0.f,0.f,0.f};
    acc = __builtin_amdgcn_mfma_f32_16x16x32_bf16(a0,b0,acc,0,0,0);
    acc = __builtin_amdgcn_mfma_f32_16x16x32_bf16(a1,b1,acc,0,0,0);
    float bs=sbias[n];
    pk[nt*2+0] = ((unsigned)f2bf(siluf(acc[1]+bs))<<16)|f2bf(siluf(acc[0]+bs));
    pk[nt*2+1] = ((unsigned)f2bf(siluf(acc[3]+bs))<<16)|f2bf(siluf(acc[2]+bs));
  }
  __syncthreads();
  // write dkv[el][512] bf16 into BD, row-swizzled
  #pragma unroll
  for(int nt=0;nt<32;nt++){
    int n=nt*16+lr;
    #pragma unroll
    for(int rr=0;rr<4;rr++){
      int el = w*16+lg*4+rr;
      unsigned short val = (unsigned short)(pk[nt*2+(rr>>1)]>>((rr&1)*16));
      *(unsigned short*)((char*)BD + el*1024 + ((n*2) ^ ((el&7)<<4))) = val;
    }
  }
  __syncthreads();
  // phase 3: 2 j's per lane (j0=2l, j0+1), one pass over 16 sorted edges
  {
    int j0 = 2*l;
    int hc0 = (l>>3)*48 + (j0&15);
    float ax0=0.f, ax1=0.f;
    float va00=0.f,va01=0.f, va10=0.f,va11=0.f, va20=0.f,va21=0.f;
    int cur = srcv[w*16];
    unsigned qd = *(const unsigned*)&qbf[(size_t)cur*HDIM + j0];
    int interior = 0;
    for(int e=0;e<16;e++){
      int el = w*16+e;
      int r = srcv[el];
      if(r != cur){
        if(interior){
          *(f32x2*)&xagg[(size_t)cur*HDIM+j0] = (f32x2){ax0,ax1};
          *(f32x2*)&vecagg[((size_t)cur*3+0)*HDIM+j0] = (f32x2){va00,va01};
          *(f32x2*)&vecagg[((size_t)cur*3+1)*HDIM+j0] = (f32x2){va10,va11};
          *(f32x2*)&vecagg[((size_t)cur*3+2)*HDIM+j0] = (f32x2){va20,va21};
        } else {
          atomicAdd(&xagg[(size_t)cur*HDIM+j0],ax0);
          atomicAdd(&xagg[(size_t)cur*HDIM+j0+1],ax1);
          atomicAdd(&vecagg[((size_t)cur*3+0)*HDIM+j0],va00);
          atomicAdd(&vecagg[((size_t)cur*3+0)*HDIM+j0+1],va01);
          atomicAdd(&vecagg[((size_t)cur*3+1)*HDIM+j0],va10);
          atomicAdd(&vecagg[((size_t)cur*3+1)*HDIM+j0+1],va11);
          atomicAdd(&vecagg[((size_t)cur*3+2)*HDIM+j0],va20);
          atomicAdd(&vecagg[((size_t)cur*3+2)*HDIM+j0+1],va21);
        }
        ax0=ax1=va00=va01=va10=va11=va20=va21=0.f;
        cur=r; interior=1;
        qd = *(const unsigned*)&qbf[(size_t)cur*HDIM + j0];
      }
      int s = ssnd[el];
      const char* dbase = (const char*)BD + el*1024;
      int sw_ = (el&7)<<4;
      unsigned kd  = *(const unsigned*)&kbf[(size_t)s*HDIM + j0];
      unsigned dkd = *(const unsigned*)(dbase + ((4*l)^sw_));
      float p = bflo(qd)*bflo(kd)*bflo(dkd) + bfhi(qd)*bfhi(kd)*bfhi(dkd);
      p += __shfl_xor(p,1); p += __shfl_xor(p,2); p += __shfl_xor(p,4);
      float attn = siluf(p)*scw[el];
      unsigned b0d = *(const unsigned*)(dbase + ((256+2*hc0)^sw_));
      unsigned b1d = *(const unsigned*)(dbase + ((288+2*hc0)^sw_));
      unsigned b2d = *(const unsigned*)(dbase + ((320+2*hc0)^sw_));
      const unsigned short* vs = vbf + (size_t)s*384;
      unsigned v0d = *(const unsigned*)&vs[hc0];
      unsigned v1d = *(const unsigned*)&vs[hc0+16];
      unsigned v2d = *(const unsigned*)&vs[hc0+32];
      ax0 += bflo(v0d)*bflo(b0d)*attn;
      ax1 += bfhi(v0d)*bfhi(b0d)*attn;
      float s10 = bflo(v1d)*bflo(b1d), s11 = bfhi(v1d)*bfhi(b1d);
      float s20 = bflo(v2d)*bflo(b2d), s21 = bfhi(v2d)*bfhi(b2d);
      float ev0=sev[el*3+0], ev1=sev[el*3+1], ev2=sev[el*3+2];
      unsigned w0 = *(const unsigned*)&vecbf[((size_t)s*3+0)*HDIM+j0];
      unsigned w1 = *(const unsigned*)&vecbf[((size_t)s*3+1)*HDIM+j0];
      unsigned w2 = *(const unsigned*)&vecbf[((size_t)s*3+2)*HDIM+j0];
      va00 += bflo(w0)*s10 + s20*ev0;  va01 += bfhi(w0)*s11 + s21*ev0;
      va10 += bflo(w1)*s10 + s20*ev1;  va11 += bfhi(w1)*s11 + s21*ev1;
      va20 += bflo(w2)*s10 + s20*ev2;  va21 += bfhi(w2)*s11 + s21*ev2;
    }
    atomicAdd(&xagg[(size_t)cur*HDIM+j0],ax0);
    atomicAdd(&xagg[(size_t)cur*HDIM+j0+1],ax1);
    atomicAdd(&vecagg[((size_t)cur*3+0)*HDIM+j0],va00);
    atomicAdd(&vecagg[((size_t)cur*3+0)*HDIM+j0+1],va01);
    atomicAdd(&vecagg[((size_t)cur*3+1)*HDIM+j0],va10);
    atomicAdd(&vecagg[((size_t)cur*3+1)*HDIM+j0+1],va11);
    atomicAdd(&vecagg[((size_t)cur*3+2)*HDIM+j0],va20);
    atomicAdd(&vecagg[((size_t)cur*3+2)*HDIM+j0+1],va21);
  }
}

// ---------------- node update: MFMA, 32 nodes/block ----------------
__global__ __launch_bounds__(256) void k_node_update_m(
    const float* __restrict__ xagg, const float* __restrict__ vdot,
    const float* __restrict__ vec3, const float* __restrict__ vecagg,
    const unsigned short* __restrict__ WoT, const float* __restrict__ bo,
    float* __restrict__ x, float* __restrict__ vec,
    unsigned short* __restrict__ vecbf, int l){
  __shared__ unsigned short sxa[32][PADR];
  int t = threadIdx.x, w = t>>6, lane = t&63;
  int n0 = blockIdx.x*32;
  #pragma unroll
  for(int i=0;i<16;i++){
    int idx = i*256+t; int nn = idx>>7, j2 = idx&127;
    sxa[nn][j2] = f2bf(xagg[(size_t)(n0+nn)*HDIM + j2]);
  }
  __syncthreads();
  int lr = lane&15, lg = lane>>4;
  int mt = w>>1, par = w&1;
  int rbase = mt*16;
  short8 a[4];
  #pragma unroll
  for(int kk=0;kk<4;kk++)
    a[kk] = *(const short8*)&sxa[rbase+lr][kk*32+lg*8];
  const unsigned short* Bo = WoT + (size_t)l*384*128;
  for(int jj=0;jj<4;jj++){
    int j = jj*2+par;
    int col = j*16+lr;
    f32x4 ac1={0.f,0.f,0.f,0.f}, ac2={0.f,0.f,0.f,0.f}, ac3={0.f,0.f,0.f,0.f};
    #pragma unroll
    for(int kk=0;kk<4;kk++){
      ac1 = __builtin_amdgcn_mfma_f32_16x16x32_bf16(a[kk], *(const short8*)(Bo+(size_t)(col    )*128+kk*32+lg*8), ac1, 0,0,0);
      ac2 = __builtin_amdgcn_mfma_f32_16x16x32_bf16(a[kk], *(const short8*)(Bo+(size_t)(col+128)*128+kk*32+lg*8), ac2, 0,0,0);
      ac3 = __builtin_amdgcn_mfma_f32_16x16x32_bf16(a[kk], *(const short8*)(Bo+(size_t)(col+256)*128+kk*32+lg*8), ac3, 0,0,0);
    }
    float b1=bo[l*384+col], b2=bo[l*384+128+col], b3=bo[l*384+256+col];
    #pragma unroll
    for(int r=0;r<4;r++){
      int node = n0+rbase+lg*4+r;
      float o1=ac1[r]+b1, o2=ac2[r]+b2, o3=ac3[r]+b3;
      size_t xi = (size_t)node*HDIM+col;
      x[xi] += vdot[xi]*o2 + o3;
      #pragma unroll
      for(int sp=0;sp<3;sp++){
        size_t idx=((size_t)node*3+sp)*HDIM+col;
        float nv = vec[idx] + vec3[idx]*o1 + vecagg[idx];
        vec[idx]=nv; vecbf[idx]=f2bf(nv);
      }
    }
  }
}

// ---------------- final layernorm + output ----------------
__global__ void k_final(const float* __restrict__ x, const float* __restrict__ vec,
                        const float* __restrict__ g, const float* __restrict__ b,
                        float* __restrict__ out){
  int n=blockIdx.x; int t=threadIdx.x;
  float x0=x[(size_t)n*HDIM+t], x1=x[(size_t)n*HDIM+64+t];
  float sum=x0+x1;
  #pragma unroll
  for(int m=1;m<=32;m<<=1) sum += __shfl_xor(sum,m);
  float mean=sum*(1.f/128.f);
  float d0=x0-mean, d1=x1-mean;
  float vs=d0*d0+d1*d1;
  #pragma unroll
  for(int m=1;m<=32;m<<=1) vs += __shfl_xor(vs,m);
  float rstd=rsqrtf(vs*(1.f/128.f)+1e-6f);
  out[(size_t)n*HDIM+t]    = d0*rstd*g[t]+b[t];
  out[(size_t)n*HDIM+64+t] = d1*rstd*g[64+t]+b[64+t];
  float* ov = out + (size_t)NN*HDIM;
  for(int sp=0;sp<3;sp++){
    size_t idx=((size_t)n*3+sp)*HDIM;
    ov[idx+t]    = vec[idx+t];
    ov[idx+64+t] = vec[idx+64+t];
  }
}

extern "C" void kernel_launch(void* const* d_in, const int* in_sizes, int n_in,
                              void* d_out, int out_size, void* d_ws, size_t ws_size,
                              hipStream_t stream){
  const int*   z      = (const int*)  d_in[0];
  const float* pos    = (const float*)d_in[1];
  const int*   snd    = (const int*)  d_in[2];
  const int*   rcv    = (const int*)  d_in[3];
  const float* embed1 = (const float*)d_in[4];
  const float* embed2 = (const float*)d_in[5];
  const float* nbWd   = (const float*)d_in[6];
  const float* nbbd   = (const float*)d_in[7];
  const float* nbWc   = (const float*)d_in[8];
  const float* nbbc   = (const float*)d_in[9];
  const float* lng    = (const float*)d_in[10];
  const float* lnb    = (const float*)d_in[11];
  const float* Wq     = (const float*)d_in[12];
  const float* bq     = (const float*)d_in[13];
  const float* Wk     = (const float*)d_in[14];
  const float* bk     = (const float*)d_in[15];
  const float* Wv     = (const float*)d_in[16];
  const float* bv     = (const float*)d_in[17];
  const float* Wvec   = (const float*)d_in[18];
  const float* Wdk    = (const float*)d_in[19];
  const float* bdk    = (const float*)d_in[20];
  const float* Wdv    = (const float*)d_in[21];
  const float* bdv    = (const float*)d_in[22];
  const float* Wo     = (const float*)d_in[23];
  const float* bo     = (const float*)d_in[24];
  const float* cscale = (const float*)d_in[25];
  const float* lnfg   = (const float*)d_in[26];
  const float* lnfb   = (const float*)d_in[27];
  float* out = (float*)d_out;

  float* ws = (float*)d_ws;
  // alias region: ew+evec (geometry) -> msgc (nb stage)
  unsigned short* region = (unsigned short*)ws;  ws += (size_t)NE*HDIM/2;  // 33.5 MB
  float* ew   = (float*)region;
  float* evec = ew + NE;
  unsigned short* msgc = region;

  float* ews   = ws;  ws += NE;
  float* cw    = ws;  ws += NE;
  float* evs   = ws;  ws += 3*NE;
  float* x     = ws;  ws += (size_t)NN*HDIM;
  float* vdot  = ws;  ws += (size_t)NN*HDIM;   // doubles as xnb pre-layers
  float* xagg  = ws;  ws += (size_t)NN*HDIM;
  float* vec3  = ws;  ws += (size_t)NN*384;
  float* vecagg= ws;  ws += (size_t)NN*384;
  float* vec   = ws;  ws += (size_t)NN*384;
  float* bias4 = ws;  ws += 4*512;
  int* deg    = (int*)ws; ws += NN;
  int* off    = (int*)ws; ws += NN+8;
  int* cursor = (int*)ws; ws += NN;
  int* eidx   = (int*)ws; ws += NE;
  int* snds   = (int*)ws; ws += NE;
  int* rcvs   = (int*)ws; ws += NE;
  unsigned short* qbf   = (unsigned short*)ws;
  unsigned short* kbf   = qbf  + (size_t)NN*HDIM;
  unsigned short* vbf   = kbf  + (size_t)NN*HDIM;
  unsigned short* vecbf = vbf  + (size_t)NN*384;
  unsigned short* WqkvT = vecbf+ (size_t)NN*384;
  unsigned short* WvecT = WqkvT + (size_t)4*640*128;
  unsigned short* WoT   = WvecT + (size_t)4*384*128;
  unsigned short* nbT   = WoT   + (size_t)4*384*128;
  unsigned short* wbT4  = nbT   + (size_t)HDIM*NRBF;

  float* xnb = vdot;

  k_edge_geom<<<(NE+255)/256,256,0,stream>>>(pos,snd,rcv,ew,evec);
  hipMemsetAsync(deg,0,NN*4,stream);
  k_hist<<<NE/256,256,0,stream>>>(rcv,deg);
  k_scan<<<1,1024,0,stream>>>(deg,off,cursor);
  k_scatter<<<NE/256,256,0,stream>>>(rcv,cursor,eidx);
  k_permute<<<NE/256,256,0,stream>>>(eidx,ew,evec,snd,rcv,ews,cw,evs,snds,rcvs);
  k_cvt_nbT<<<(HDIM*NRBF)/256,256,0,stream>>>(nbWd,nbT);
  k_nb_gemm<<<NE/64,256,0,stream>>>(ews,cw,snds,z,embed2,nbT,nbbd,msgc);
  k_nb_sweep<<<NN/8,128,0,stream>>>(off,msgc,xnb);
  k_combine_b<<<NN/16,256,0,stream>>>(z,embed1,xnb,nbWc,nbbc,x);
  hipMemsetAsync(vec,0,(size_t)NN*384*4,stream);
  hipMemsetAsync(vecbf,0,(size_t)NN*384*2,stream);
  k_cvt_qkvT<<<(4*640*128)/256,256,0,stream>>>(Wq,Wk,Wv,WqkvT);
  k_cvtT<<<(4*384*128)/256,256,0,stream>>>(Wvec,WvecT,384);
  k_cvtT<<<(4*384*128)/256,256,0,stream>>>(Wo,WoT,384);
  k_wcvt4<<<(4*512*64)/256,256,0,stream>>>(Wdk,Wdv,wbT4);
  k_bcvt4<<<8,256,0,stream>>>(bdk,bdv,bias4);
  for(int l=0;l<NL;l++){
    k_node_pre_m<<<NN/32,256,0,stream>>>(x,vec,lng,lnb,bq,bk,bv,WqkvT,WvecT,cscale,
                                         qbf,kbf,vbf,vdot,vec3,l);
    hipMemsetAsync(xagg,0,(size_t)NN*HDIM*4,stream);
    hipMemsetAsync(vecagg,0,(size_t)NN*384*4,stream);
    k_edge_fused2<<<NE/64,256,0,stream>>>(ews,cw,evs,snds,rcvs,qbf,kbf,vbf,vecbf,
                                          wbT4 + (size_t)l*512*64, bias4 + l*512,
                                          xagg,vecagg);
    k_node_update_m<<<NN/32,256,0,stream>>>(xagg,vdot,vec3,vecagg,WoT,bo,x,vec,vecbf,l);
  }
  k_final<<<NN,64,0,stream>>>(x,vec,lnfg,lnfb,out);
}

// Round 8
// 897.261 us; speedup vs baseline: 5.6405x; 1.0357x over previous
//
#include <hip/hip_runtime.h>
#include <math.h>

#define NN 16384
#define NE 131072
#define HDIM 128
#define NRBF 64
#define NL 4

typedef __attribute__((ext_vector_type(8))) short short8;
typedef __attribute__((ext_vector_type(4))) float f32x4;
typedef __attribute__((ext_vector_type(2))) float f32x2;

__device__ __forceinline__ float siluf(float x){ return x / (1.0f + expf(-x)); }
__device__ __forceinline__ float cutofff(float d){
  return (d < 10.0f) ? 0.5f*(cosf(d*0.31415926535897932f)+1.0f) : 0.0f;
}
__device__ __forceinline__ unsigned short f2bf(float f){
  union{float f; unsigned u;} v; v.f = f;
  unsigned r = v.u + 0x7FFF + ((v.u>>16)&1);
  return (unsigned short)(r>>16);
}
__device__ __forceinline__ float bf2f(unsigned short b){
  union{unsigned u; float f;} v; v.u = ((unsigned)b)<<16;
  return v.f;
}
__device__ __forceinline__ float bflo(unsigned u){
  union{unsigned x; float f;} v; v.x = u<<16; return v.f;
}
__device__ __forceinline__ float bfhi(unsigned u){
  union{unsigned x; float f;} v; v.x = u & 0xffff0000u; return v.f;
}

// ---------------- edge geometry ----------------
__global__ void k_edge_geom(const float* __restrict__ pos, const int* __restrict__ snd,
                            const int* __restrict__ rcv, float* __restrict__ ew,
                            float* __restrict__ evec){
  int e = blockIdx.x*blockDim.x + threadIdx.x;
  if(e >= NE) return;
  int s = snd[e], r = rcv[e];
  float dx = pos[r*3+0]-pos[s*3+0];
  float dy = pos[r*3+1]-pos[s*3+1];
  float dz = pos[r*3+2]-pos[s*3+2];
  const float eps = 1e-6f;
  float d = sqrtf((dx+eps)*(dx+eps)+(dy+eps)*(dy+eps)+(dz+eps)*(dz+eps));
  ew[e] = d;
  float mew = (s==r) ? 1.0f : d;
  mew = fmaxf(mew, 0.01f);
  float inv = 1.0f/mew;
  evec[e*3+0]=dx*inv; evec[e*3+1]=dy*inv; evec[e*3+2]=dz*inv;
}

// ---------------- CSR build ----------------
__global__ void k_hist(const int* __restrict__ rcv, int* __restrict__ deg){
  int e = blockIdx.x*256+threadIdx.x;
  if(e<NE) atomicAdd(&deg[rcv[e]],1);
}
__global__ __launch_bounds__(1024) void k_scan(const int* __restrict__ deg,
                                               int* __restrict__ off, int* __restrict__ cursor){
  __shared__ int part[1024];
  int t=threadIdx.x;
  int loc[16]; int s=0;
  #pragma unroll
  for(int i=0;i<16;i++){ loc[i]=s; s+=deg[t*16+i]; }
  part[t]=s; __syncthreads();
  for(int d=1;d<1024;d<<=1){
    int v=(t>=d)?part[t-d]:0; __syncthreads(); part[t]+=v; __syncthreads();
  }
  int excl = (t>0)?part[t-1]:0;
  #pragma unroll
  for(int i=0;i<16;i++){ int o=excl+loc[i]; off[t*16+i]=o; cursor[t*16+i]=o; }
  if(t==1023) off[NN]=part[1023];
}
__global__ void k_scatter(const int* __restrict__ rcv, int* __restrict__ cursor,
                          int* __restrict__ eidx){
  int e = blockIdx.x*256+threadIdx.x; if(e>=NE) return;
  int p = atomicAdd(&cursor[rcv[e]],1);
  eidx[p]=e;
}
__global__ void k_permute(const int* __restrict__ eidx, const float* __restrict__ ew,
                          const float* __restrict__ evec, const int* __restrict__ snd,
                          const int* __restrict__ rcv,
                          float* __restrict__ ews, float* __restrict__ cw,
                          float* __restrict__ evs, int* __restrict__ snds,
                          int* __restrict__ rcvs){
  int i = blockIdx.x*256+threadIdx.x; if(i>=NE) return;
  int e = eidx[i];
  float d = ew[e];
  ews[i]=d; cw[i]=cutofff(d);
  evs[i*3+0]=evec[e*3+0]; evs[i*3+1]=evec[e*3+1]; evs[i*3+2]=evec[e*3+2];
  snds[i]=snd[e]; rcvs[i]=rcv[e];
}

// ---------------- weight transposes to bf16 ----------------
__global__ void k_cvt_nbT(const float* __restrict__ Wd, unsigned short* __restrict__ dst){
  int o = blockIdx.x*256+threadIdx.x; if(o>=HDIM*NRBF) return;
  int n=o>>6, k=o&63;
  dst[o] = f2bf(Wd[k*HDIM+n]);
}
__global__ void k_cvt_qkvT(const float* __restrict__ Wq, const float* __restrict__ Wk,
                           const float* __restrict__ Wv, unsigned short* __restrict__ dst){
  int o = blockIdx.x*256+threadIdx.x;
  if(o >= 4*640*128) return;
  int l = o/81920; int rem = o - l*81920;
  int n = rem>>7, k = rem&127;
  float v;
  if(n<128)      v = Wq[(size_t)l*16384 + k*128 + n];
  else if(n<256) v = Wk[(size_t)l*16384 + k*128 + (n-128)];
  else           v = Wv[(size_t)l*49152 + k*384 + (n-256)];
  dst[o]=f2bf(v);
}
__global__ void k_cvtT(const float* __restrict__ src, unsigned short* __restrict__ dst, int NC){
  int o = blockIdx.x*256+threadIdx.x;
  int tot = 4*NC*128; if(o>=tot) return;
  int l = o/(NC*128); int rem = o - l*NC*128;
  int n = rem>>7, k = rem&127;
  dst[o] = f2bf(src[(size_t)l*128*NC + k*NC + n]);
}
__global__ void k_wcvt4(const float* __restrict__ Wdk, const float* __restrict__ Wdv,
                        unsigned short* __restrict__ wbT4){
  int o = blockIdx.x*blockDim.x + threadIdx.x;
  if(o >= 4*512*64) return;
  int l = o >> 15; int rem = o & 32767;
  int n = rem >> 6, kk = rem & 63;
  float v = (n < 128) ? Wdk[(size_t)l*NRBF*HDIM + kk*HDIM + n]
                      : Wdv[(size_t)l*NRBF*384 + kk*384 + (n-128)];
  wbT4[o] = f2bf(v);
}
__global__ void k_bcvt4(const float* __restrict__ bdk, const float* __restrict__ bdv,
                        float* __restrict__ bias4){
  int o = threadIdx.x + blockIdx.x*blockDim.x;
  if(o >= 4*512) return;
  int l = o >> 9, c = o & 511;
  bias4[o] = (c < 128) ? bdk[l*HDIM + c] : bdv[l*384 + (c-128)];
}

// ---------------- neighbor-embedding GEMM over sorted edges (no atomics) -----
__global__ __launch_bounds__(256) void k_nb_gemm(const float* __restrict__ ews,
    const float* __restrict__ cw, const int* __restrict__ snds,
    const int* __restrict__ z, const float* __restrict__ embed2,
    const unsigned short* __restrict__ nbT, const float* __restrict__ bd,
    unsigned short* __restrict__ msgc){
  __shared__ __align__(16) unsigned short Bl[HDIM*64];
  int t = threadIdx.x;
  int e0 = blockIdx.x*64;
  #pragma unroll
  for(int i=0;i<4;i++){
    int idx=i*256+t; int n=idx>>3, kc=idx&7;
    short8 val = *(const short8*)(nbT + n*64 + kc*8);
    *(short8*)((char*)Bl + n*128 + ((kc ^ (n&7))<<4)) = val;
  }
  int w=t>>6, l=t&63, lr=l&15, lg=l>>4;
  float d = ews[e0 + w*16 + lr];
  short8 a0, a1;
  {
    float edm = expf(-0.5f*d);
    float Cc = cutofff(d);
    const float start = expf(-10.0f);
    const float tmp = (2.0f/64.0f)*(1.0f-start);
    const float beta = 1.0f/(tmp*tmp);
    #pragma unroll
    for(int si=0;si<8;si++){
      float m0 = start + (1.0f-start)*((float)(lg*8+si)*(1.0f/63.0f));
      float m1 = start + (1.0f-start)*((float)(32+lg*8+si)*(1.0f/63.0f));
      float t0 = edm-m0, t1 = edm-m1;
      a0[si] = (short)f2bf(Cc*expf(-beta*t0*t0));
      a1[si] = (short)f2bf(Cc*expf(-beta*t1*t1));
    }
  }
  int sr[4]; float Cr[4]; int zz[4];
  #pragma unroll
  for(int r=0;r<4;r++){
    int i = e0 + w*16 + lg*4 + r;
    sr[r]=snds[i]; Cr[r]=cw[i]; zz[r]=z[sr[r]];
  }
  __syncthreads();
  #pragma unroll
  for(int nt=0;nt<8;nt++){
    int n=nt*16+lr;
    const char* bp=(const char*)Bl + n*128;
    short8 b0 = *(const short8*)(bp + (((lg  )^(n&7))<<4));
    short8 b1 = *(const short8*)(bp + (((4+lg)^(n&7))<<4));
    f32x4 acc={0.f,0.f,0.f,0.f};
    acc = __builtin_amdgcn_mfma_f32_16x16x32_bf16(a0,b0,acc,0,0,0);
    acc = __builtin_amdgcn_mfma_f32_16x16x32_bf16(a1,b1,acc,0,0,0);
    float bdn = bd[n];
    #pragma unroll
    for(int r=0;r<4;r++){
      float m = (acc[r]+bdn)*Cr[r]*embed2[(size_t)zz[r]*HDIM+n];
      msgc[(size_t)(e0+w*16+lg*4+r)*HDIM + n] = f2bf(m);
    }
  }
}
__global__ void k_nb_sweep(const int* __restrict__ off,
                           const unsigned short* __restrict__ msgc,
                           float* __restrict__ xnb){
  int j = threadIdx.x;                 // 128
  int n0 = blockIdx.x*8;
  for(int nn=0;nn<8;nn++){
    int node=n0+nn;
    float acc=0.f;
    int ib=off[node], ie=off[node+1];
    for(int i=ib;i<ie;i++) acc += bf2f(msgc[(size_t)i*HDIM+j]);
    xnb[(size_t)node*HDIM+j]=acc;
  }
}

// ---------------- combine, 16 nodes/block ----------------
__global__ __launch_bounds__(256) void k_combine_b(
    const int* __restrict__ z, const float* __restrict__ embed1,
    const float* __restrict__ xnb, const float* __restrict__ Wc,
    const float* __restrict__ bc, float* __restrict__ x){
  __shared__ float sx[16][2*HDIM];
  int t = threadIdx.x; int n0 = blockIdx.x*16;
  #pragma unroll
  for(int i=0;i<16;i++){
    int idx = i*256+t; int nn = idx>>8, c = idx&255;
    int n = n0+nn;
    sx[nn][c] = (c<128) ? embed1[(size_t)z[n]*HDIM + c]
                        : xnb[(size_t)n*HDIM + (c-128)];
  }
  __syncthreads();
  int j = t&127, g = t>>7;
  float bcj = bc[j];
  float acc[8];
  #pragma unroll
  for(int r=0;r<8;r++) acc[r]=bcj;
  for(int i=0;i<2*HDIM;i++){
    float wv = Wc[i*HDIM+j];
    #pragma unroll
    for(int r=0;r<8;r++) acc[r] += sx[2*r+g][i]*wv;
  }
  #pragma unroll
  for(int r=0;r<8;r++) x[(size_t)(n0+2*r+g)*HDIM+j] = acc[r];
}

// ---------------- node pre: LN/coorsnorm + MFMA GEMMs, 32 nodes/block ---------
#define PADR 136   // 128 + 8 ushorts pad
__global__ __launch_bounds__(256) void k_node_pre_m(
    const float* __restrict__ x, const float* __restrict__ vec,
    const float* __restrict__ lng, const float* __restrict__ lnb,
    const float* __restrict__ bq, const float* __restrict__ bk,
    const float* __restrict__ bv, const unsigned short* __restrict__ WqkvT,
    const unsigned short* __restrict__ WvecT, const float* __restrict__ cscale,
    unsigned short* __restrict__ qbf, unsigned short* __restrict__ kbf,
    unsigned short* __restrict__ vbf, float* __restrict__ vdot,
    float* __restrict__ vec3, int l){
  __shared__ unsigned short sxn[32][PADR];
  __shared__ unsigned short svn[3][32][PADR];
  int t = threadIdx.x, w = t>>6, lane = t&63;
  int n0 = blockIdx.x*32;
  float cs = cscale[l];
  float g0 = lng[l*HDIM+lane], g1 = lng[l*HDIM+64+lane];
  float be0 = lnb[l*HDIM+lane], be1 = lnb[l*HDIM+64+lane];
  for(int rr=0; rr<8; rr++){
    int nn = w*8+rr; int n = n0+nn;
    float x0 = x[(size_t)n*HDIM+lane], x1 = x[(size_t)n*HDIM+64+lane];
    float sum = x0+x1;
    #pragma unroll
    for(int m=1;m<=32;m<<=1) sum += __shfl_xor(sum,m);
    float mean = sum*(1.f/128.f);
    float d0 = x0-mean, d1 = x1-mean;
    float vs = d0*d0+d1*d1;
    #pragma unroll
    for(int m=1;m<=32;m<<=1) vs += __shfl_xor(vs,m);
    float rstd = rsqrtf(vs*(1.f/128.f)+1e-6f);
    sxn[nn][lane]    = f2bf(d0*rstd*g0 + be0);
    sxn[nn][64+lane] = f2bf(d1*rstd*g1 + be1);
    float va0 = vec[((size_t)n*3+0)*HDIM+lane], vb0 = vec[((size_t)n*3+0)*HDIM+64+lane];
    float va1 = vec[((size_t)n*3+1)*HDIM+lane], vb1 = vec[((size_t)n*3+1)*HDIM+64+lane];
    float va2 = vec[((size_t)n*3+2)*HDIM+lane], vb2 = vec[((size_t)n*3+2)*HDIM+64+lane];
    float iA = rsqrtf(fmaxf(va0*va0+va1*va1+va2*va2,1e-8f))*cs;
    float iB = rsqrtf(fmaxf(vb0*vb0+vb1*vb1+vb2*vb2,1e-8f))*cs;
    svn[0][nn][lane]=f2bf(va0*iA); svn[0][nn][64+lane]=f2bf(vb0*iB);
    svn[1][nn][lane]=f2bf(va1*iA); svn[1][nn][64+lane]=f2bf(vb1*iB);
    svn[2][nn][lane]=f2bf(va2*iA); svn[2][nn][64+lane]=f2bf(vb2*iB);
  }
  __syncthreads();
  int lr = lane&15, lg = lane>>4;
  int mt = w>>1, par = w&1;
  int rbase = mt*16;
  short8 a1[4];
  #pragma unroll
  for(int kk=0;kk<4;kk++) a1[kk] = *(const short8*)&sxn[rbase+lr][kk*32+lg*8];
  short8 a2[3][4];
  #pragma unroll
  for(int sp=0;sp<3;sp++)
    #pragma unroll
    for(int kk=0;kk<4;kk++) a2[sp][kk] = *(const short8*)&svn[sp][rbase+lr][kk*32+lg*8];

  const unsigned short* Bq = WqkvT + (size_t)l*640*128;
  for(int jj=0;jj<20;jj++){
    int j = jj*2+par;
    int col = j*16+lr;
    const unsigned short* bp = Bq + (size_t)col*128 + lg*8;
    f32x4 acc={0.f,0.f,0.f,0.f};
    #pragma unroll
    for(int kk=0;kk<4;kk++) acc = __builtin_amdgcn_mfma_f32_16x16x32_bf16(a1[kk], *(const short8*)(bp+kk*32), acc, 0,0,0);
    if(j < 16){
      float bias = (j<8) ? bq[l*HDIM+col] : bk[l*HDIM+col-128];
      float vv[4], s2[4];
      #pragma unroll
      for(int r=0;r<4;r++){ vv[r]=acc[r]+bias; s2[r]=vv[r]*vv[r]; }
      #pragma unroll
      for(int mm=1;mm<=8;mm<<=1){
        #pragma unroll
        for(int r=0;r<4;r++) s2[r] += __shfl_xor(s2[r],mm);
      }
      #pragma unroll
      for(int r=0;r<4;r++){
        int node = n0+rbase+lg*4+r;
        float vn_ = vv[r]/(sqrtf(s2[r])+1e-6f);
        if(j<8) qbf[(size_t)node*HDIM+col]     = f2bf(vn_);
        else    kbf[(size_t)node*HDIM+col-128] = f2bf(vn_);
      }
    } else {
      int c = col-256;
      float bias = bv[l*384+c];
      #pragma unroll
      for(int r=0;r<4;r++){
        int node = n0+rbase+lg*4+r;
        vbf[(size_t)node*384+c] = f2bf(acc[r]+bias);
      }
    }
  }
  const unsigned short* Bv = WvecT + (size_t)l*384*128;
  for(int jj=0;jj<4;jj++){
    int j = jj*2+par;
    int col = j*16+lr;
    short8 b1[4],b2[4],b3[4];
    #pragma unroll
    for(int kk=0;kk<4;kk++){
      b1[kk] = *(const short8*)(Bv + (size_t)(col    )*128 + kk*32+lg*8);
      b2[kk] = *(const short8*)(Bv + (size_t)(col+128)*128 + kk*32+lg*8);
      b3[kk] = *(const short8*)(Bv + (size_t)(col+256)*128 + kk*32+lg*8);
    }
    f32x4 vd={0.f,0.f,0.f,0.f};
    #pragma unroll
    for(int sp=0;sp<3;sp++){
      f32x4 p1={0.f,0.f,0.f,0.f}, p2={0.f,0.f,0.f,0.f}, p3={0.f,0.f,0.f,0.f};
      #pragma unroll
      for(int kk=0;kk<4;kk++){
        p1 = __builtin_amdgcn_mfma_f32_16x16x32_bf16(a2[sp][kk], b1[kk], p1, 0,0,0);
        p2 = __builtin_amdgcn_mfma_f32_16x16x32_bf16(a2[sp][kk], b2[kk], p2, 0,0,0);
        p3 = __builtin_amdgcn_mfma_f32_16x16x32_bf16(a2[sp][kk], b3[kk], p3, 0,0,0);
      }
      #pragma unroll
      for(int r=0;r<4;r++){
        vd[r] += p1[r]*p2[r];
        int node = n0+rbase+lg*4+r;
        vec3[((size_t)node*3+sp)*HDIM+col] = p3[r];
      }
    }
    #pragma unroll
    for(int r=0;r<4;r++){
      int node = n0+rbase+lg*4+r;
      vdot[(size_t)node*HDIM+col] = vd[r];
    }
  }
}

// ------- fused dk/dv GEMM + attention + segmented scatter, 32 sorted edges ----
// LDS peak 35 KB -> 4 blocks/CU (vs 69 KB -> 2)
__global__ __launch_bounds__(256) void k_edge_fused3(
    const float* __restrict__ ews, const float* __restrict__ cw,
    const float* __restrict__ evs, const int* __restrict__ snds,
    const int* __restrict__ rcvs,
    const unsigned short* __restrict__ qbf, const unsigned short* __restrict__ kbf,
    const unsigned short* __restrict__ vbf, const unsigned short* __restrict__ vecbf,
    const unsigned short* __restrict__ wbT, const float* __restrict__ bias,
    float* __restrict__ xagg, float* __restrict__ vecagg){
  __shared__ __align__(16) unsigned short R[256*64];   // 32 KB: B half-panel -> dkv[32][512]
  __shared__ float sbias[512];
  __shared__ float scw[32];
  __shared__ float sev[96];
  __shared__ int   ssnd[32];
  __shared__ int   srcv[32];
  int t = threadIdx.x;
  int e0 = blockIdx.x*32;
  if(t < 32){ scw[t]=cw[e0+t]; ssnd[t]=snds[e0+t]; srcv[t]=rcvs[e0+t]; }
  if(t < 96) sev[t] = evs[e0*3 + t];
  sbias[t]=bias[t]; sbias[256+t]=bias[256+t];

  int w=t>>6, l=t&63, lr=l&15, lg=l>>4;
  int rt = w&1, ch = w>>1;              // row-tile (16 edges), col-quarter (128 cols)
  int row = rt*16 + lr;                 // edge row within block [0,32)
  float d = ews[e0 + row];
  short8 a0, a1;
  {
    float edm = expf(-0.5f*d);
    float Cc = cutofff(d);
    const float start = expf(-10.0f);
    const float tmp = (2.0f/64.0f)*(1.0f-start);
    const float beta = 1.0f/(tmp*tmp);
    #pragma unroll
    for(int si=0;si<8;si++){
      float m0 = start + (1.0f-start)*((float)(lg*8+si)*(1.0f/63.0f));
      float m1 = start + (1.0f-start)*((float)(32+lg*8+si)*(1.0f/63.0f));
      float t0 = edm-m0, t1 = edm-m1;
      a0[si] = (short)f2bf(Cc*expf(-beta*t0*t0));
      a1[si] = (short)f2bf(Cc*expf(-beta*t1*t1));
    }
  }
  unsigned pk[32];
  #pragma unroll
  for(int h=0; h<2; h++){
    __syncthreads();     // h=0: after scalar staging; h=1: all reads of prev half done
    // stage B half h: cols [h*256, h*256+256) as [n_local][64k], swizzled 16B chunks
    #pragma unroll
    for(int i=0;i<8;i++){
      int idx = i*256+t; int nl = idx>>3, kc = idx&7;
      short8 val = *(const short8*)(wbT + (size_t)(h*256+nl)*64 + kc*8);
      *(short8*)((char*)R + nl*128 + ((kc ^ (nl&7))<<4)) = val;
    }
    __syncthreads();
    #pragma unroll
    for(int nt=0;nt<8;nt++){
      int nl = ch*128 + nt*16 + lr;     // local col [0,256)
      const char* bp=(const char*)R + nl*128;
      short8 b0 = *(const short8*)(bp + (((lg  )^(nl&7))<<4));
      short8 b1 = *(const short8*)(bp + (((4+lg)^(nl&7))<<4));
      f32x4 acc={0.f,0.f,0.f,0.f};
      acc = __builtin_amdgcn_mfma_f32_16x16x32_bf16(a0,b0,acc,0,0,0);
      acc = __builtin_amdgcn_mfma_f32_16x16x32_bf16(a1,b1,acc,0,0,0);
      float bs=sbias[h*256+nl];
      pk[(h*8+nt)*2+0] = ((unsigned)f2bf(siluf(acc[1]+bs))<<16)|f2bf(siluf(acc[0]+bs));
      pk[(h*8+nt)*2+1] = ((unsigned)f2bf(siluf(acc[3]+bs))<<16)|f2bf(siluf(acc[2]+bs));
    }
  }
  __syncthreads();
  // write dkv[el][512] bf16 into R (rows of 1024B), row-swizzled
  #pragma unroll
  for(int h=0;h<2;h++){
    #pragma unroll
    for(int nt=0;nt<8;nt++){
      int n = h*256 + ch*128 + nt*16 + lr;
      #pragma unroll
      for(int rr=0;rr<4;rr++){
        int el = rt*16+lg*4+rr;
        unsigned short val = (unsigned short)(pk[(h*8+nt)*2+(rr>>1)]>>((rr&1)*16));
        *(unsigned short*)((char*)R + el*1024 + ((n*2) ^ ((el&7)<<4))) = val;
      }
    }
  }
  __syncthreads();
  // sweep: wave w handles edges [w*8, w*8+8); 2 j's per lane (j0=2l, j0+1)
  {
    int j0 = 2*l;
    int hc0 = (l>>3)*48 + (j0&15);
    float ax0=0.f, ax1=0.f;
    float va00=0.f,va01=0.f, va10=0.f,va11=0.f, va20=0.f,va21=0.f;
    int cur = srcv[w*8];
    unsigned qd = *(const unsigned*)&qbf[(size_t)cur*HDIM + j0];
    int interior = 0;
    for(int e=0;e<8;e++){
      int el = w*8+e;
      int r = srcv[el];
      if(r != cur){
        if(interior){
          *(f32x2*)&xagg[(size_t)cur*HDIM+j0] = (f32x2){ax0,ax1};
          *(f32x2*)&vecagg[((size_t)cur*3+0)*HDIM+j0] = (f32x2){va00,va01};
          *(f32x2*)&vecagg[((size_t)cur*3+1)*HDIM+j0] = (f32x2){va10,va11};
          *(f32x2*)&vecagg[((size_t)cur*3+2)*HDIM+j0] = (f32x2){va20,va21};
        } else {
          atomicAdd(&xagg[(size_t)cur*HDIM+j0],ax0);
          atomicAdd(&xagg[(size_t)cur*HDIM+j0+1],ax1);
          atomicAdd(&vecagg[((size_t)cur*3+0)*HDIM+j0],va00);
          atomicAdd(&vecagg[((size_t)cur*3+0)*HDIM+j0+1],va01);
          atomicAdd(&vecagg[((size_t)cur*3+1)*HDIM+j0],va10);
          atomicAdd(&vecagg[((size_t)cur*3+1)*HDIM+j0+1],va11);
          atomicAdd(&vecagg[((size_t)cur*3+2)*HDIM+j0],va20);
          atomicAdd(&vecagg[((size_t)cur*3+2)*HDIM+j0+1],va21);
        }
        ax0=ax1=va00=va01=va10=va11=va20=va21=0.f;
        cur=r; interior=1;
        qd = *(const unsigned*)&qbf[(size_t)cur*HDIM + j0];
      }
      int s = ssnd[el];
      const char* dbase = (const char*)R + el*1024;
      int sw_ = (el&7)<<4;
      unsigned kd  = *(const unsigned*)&kbf[(size_t)s*HDIM + j0];
      unsigned dkd = *(const unsigned*)(dbase + ((4*l)^sw_));
      float p = bflo(qd)*bflo(kd)*bflo(dkd) + bfhi(qd)*bfhi(kd)*bfhi(dkd);
      p += __shfl_xor(p,1); p += __shfl_xor(p,2); p += __shfl_xor(p,4);
      float attn = siluf(p)*scw[el];
      unsigned b0d = *(const unsigned*)(dbase + ((256+2*hc0)^sw_));
      unsigned b1d = *(const unsigned*)(dbase + ((288+2*hc0)^sw_));
      unsigned b2d = *(const unsigned*)(dbase + ((320+2*hc0)^sw_));
      const unsigned short* vs = vbf + (size_t)s*384;
      unsigned v0d = *(const unsigned*)&vs[hc0];
      unsigned v1d = *(const unsigned*)&vs[hc0+16];
      unsigned v2d = *(const unsigned*)&vs[hc0+32];
      ax0 += bflo(v0d)*bflo(b0d)*attn;
      ax1 += bfhi(v0d)*bfhi(b0d)*attn;
      float s10 = bflo(v1d)*bflo(b1d), s11 = bfhi(v1d)*bfhi(b1d);
      float s20 = bflo(v2d)*bflo(b2d), s21 = bfhi(v2d)*bfhi(b2d);
      float ev0=sev[el*3+0], ev1=sev[el*3+1], ev2=sev[el*3+2];
      unsigned w0 = *(const unsigned*)&vecbf[((size_t)s*3+0)*HDIM+j0];
      unsigned w1 = *(const unsigned*)&vecbf[((size_t)s*3+1)*HDIM+j0];
      unsigned w2 = *(const unsigned*)&vecbf[((size_t)s*3+2)*HDIM+j0];
      va00 += bflo(w0)*s10 + s20*ev0;  va01 += bfhi(w0)*s11 + s21*ev0;
      va10 += bflo(w1)*s10 + s20*ev1;  va11 += bfhi(w1)*s11 + s21*ev1;
      va20 += bflo(w2)*s10 + s20*ev2;  va21 += bfhi(w2)*s11 + s21*ev2;
    }
    atomicAdd(&xagg[(size_t)cur*HDIM+j0],ax0);
    atomicAdd(&xagg[(size_t)cur*HDIM+j0+1],ax1);
    atomicAdd(&vecagg[((size_t)cur*3+0)*HDIM+j0],va00);
    atomicAdd(&vecagg[((size_t)cur*3+0)*HDIM+j0+1],va01);
    atomicAdd(&vecagg[((size_t)cur*3+1)*HDIM+j0],va10);
    atomicAdd(&vecagg[((size_t)cur*3+1)*HDIM+j0+1],va11);
    atomicAdd(&vecagg[((size_t)cur*3+2)*HDIM+j0],va20);
    atomicAdd(&vecagg[((size_t)cur*3+2)*HDIM+j0+1],va21);
  }
}

// ---------------- node update: MFMA, 32 nodes/block ----------------
__global__ __launch_bounds__(256) void k_node_update_m(
    const float* __restrict__ xagg, const float* __restrict__ vdot,
    const float* __restrict__ vec3, const float* __restrict__ vecagg,
    const unsigned short* __restrict__ WoT, const float* __restrict__ bo,
    float* __restrict__ x, float* __restrict__ vec,
    unsigned short* __restrict__ vecbf, int l){
  __shared__ unsigned short sxa[32][PADR];
  int t = threadIdx.x, w = t>>6, lane = t&63;
  int n0 = blockIdx.x*32;
  #pragma unroll
  for(int i=0;i<16;i++){
    int idx = i*256+t; int nn = idx>>7, j2 = idx&127;
    sxa[nn][j2] = f2bf(xagg[(size_t)(n0+nn)*HDIM + j2]);
  }
  __syncthreads();
  int lr = lane&15, lg = lane>>4;
  int mt = w>>1, par = w&1;
  int rbase = mt*16;
  short8 a[4];
  #pragma unroll
  for(int kk=0;kk<4;kk++)
    a[kk] = *(const short8*)&sxa[rbase+lr][kk*32+lg*8];
  const unsigned short* Bo = WoT + (size_t)l*384*128;
  for(int jj=0;jj<4;jj++){
    int j = jj*2+par;
    int col = j*16+lr;
    f32x4 ac1={0.f,0.f,0.f,0.f}, ac2={0.f,0.f,0.f,0.f}, ac3={0.f,0.f,0.f,0.f};
    #pragma unroll
    for(int kk=0;kk<4;kk++){
      ac1 = __builtin_amdgcn_mfma_f32_16x16x32_bf16(a[kk], *(const short8*)(Bo+(size_t)(col    )*128+kk*32+lg*8), ac1, 0,0,0);
      ac2 = __builtin_amdgcn_mfma_f32_16x16x32_bf16(a[kk], *(const short8*)(Bo+(size_t)(col+128)*128+kk*32+lg*8), ac2, 0,0,0);
      ac3 = __builtin_amdgcn_mfma_f32_16x16x32_bf16(a[kk], *(const short8*)(Bo+(size_t)(col+256)*128+kk*32+lg*8), ac3, 0,0,0);
    }
    float b1=bo[l*384+col], b2=bo[l*384+128+col], b3=bo[l*384+256+col];
    #pragma unroll
    for(int r=0;r<4;r++){
      int node = n0+rbase+lg*4+r;
      float o1=ac1[r]+b1, o2=ac2[r]+b2, o3=ac3[r]+b3;
      size_t xi = (size_t)node*HDIM+col;
      x[xi] += vdot[xi]*o2 + o3;
      #pragma unroll
      for(int sp=0;sp<3;sp++){
        size_t idx=((size_t)node*3+sp)*HDIM+col;
        float nv = vec[idx] + vec3[idx]*o1 + vecagg[idx];
        vec[idx]=nv; vecbf[idx]=f2bf(nv);
      }
    }
  }
}

// ---------------- final layernorm + output ----------------
__global__ void k_final(const float* __restrict__ x, const float* __restrict__ vec,
                        const float* __restrict__ g, const float* __restrict__ b,
                        float* __restrict__ out){
  int n=blockIdx.x; int t=threadIdx.x;
  float x0=x[(size_t)n*HDIM+t], x1=x[(size_t)n*HDIM+64+t];
  float sum=x0+x1;
  #pragma unroll
  for(int m=1;m<=32;m<<=1) sum += __shfl_xor(sum,m);
  float mean=sum*(1.f/128.f);
  float d0=x0-mean, d1=x1-mean;
  float vs=d0*d0+d1*d1;
  #pragma unroll
  for(int m=1;m<=32;m<<=1) vs += __shfl_xor(vs,m);
  float rstd=rsqrtf(vs*(1.f/128.f)+1e-6f);
  out[(size_t)n*HDIM+t]    = d0*rstd*g[t]+b[t];
  out[(size_t)n*HDIM+64+t] = d1*rstd*g[64+t]+b[64+t];
  float* ov = out + (size_t)NN*HDIM;
  for(int sp=0;sp<3;sp++){
    size_t idx=((size_t)n*3+sp)*HDIM;
    ov[idx+t]    = vec[idx+t];
    ov[idx+64+t] = vec[idx+64+t];
  }
}

extern "C" void kernel_launch(void* const* d_in, const int* in_sizes, int n_in,
                              void* d_out, int out_size, void* d_ws, size_t ws_size,
                              hipStream_t stream){
  const int*   z      = (const int*)  d_in[0];
  const float* pos    = (const float*)d_in[1];
  const int*   snd    = (const int*)  d_in[2];
  const int*   rcv    = (const int*)  d_in[3];
  const float* embed1 = (const float*)d_in[4];
  const float* embed2 = (const float*)d_in[5];
  const float* nbWd   = (const float*)d_in[6];
  const float* nbbd   = (const float*)d_in[7];
  const float* nbWc   = (const float*)d_in[8];
  const float* nbbc   = (const float*)d_in[9];
  const float* lng    = (const float*)d_in[10];
  const float* lnb    = (const float*)d_in[11];
  const float* Wq     = (const float*)d_in[12];
  const float* bq     = (const float*)d_in[13];
  const float* Wk     = (const float*)d_in[14];
  const float* bk     = (const float*)d_in[15];
  const float* Wv     = (const float*)d_in[16];
  const float* bv     = (const float*)d_in[17];
  const float* Wvec   = (const float*)d_in[18];
  const float* Wdk    = (const float*)d_in[19];
  const float* bdk    = (const float*)d_in[20];
  const float* Wdv    = (const float*)d_in[21];
  const float* bdv    = (const float*)d_in[22];
  const float* Wo     = (const float*)d_in[23];
  const float* bo     = (const float*)d_in[24];
  const float* cscale = (const float*)d_in[25];
  const float* lnfg   = (const float*)d_in[26];
  const float* lnfb   = (const float*)d_in[27];
  float* out = (float*)d_out;

  float* ws = (float*)d_ws;
  // alias region: ew+evec (geometry) -> msgc (nb stage)
  unsigned short* region = (unsigned short*)ws;  ws += (size_t)NE*HDIM/2;  // 33.5 MB
  float* ew   = (float*)region;
  float* evec = ew + NE;
  unsigned short* msgc = region;

  float* ews   = ws;  ws += NE;
  float* cw    = ws;  ws += NE;
  float* evs   = ws;  ws += 3*NE;
  float* x     = ws;  ws += (size_t)NN*HDIM;
  float* vdot  = ws;  ws += (size_t)NN*HDIM;   // doubles as xnb pre-layers
  float* xagg  = ws;  ws += (size_t)NN*HDIM;
  float* vec3  = ws;  ws += (size_t)NN*384;
  float* vecagg= ws;  ws += (size_t)NN*384;
  float* vec   = ws;  ws += (size_t)NN*384;
  float* bias4 = ws;  ws += 4*512;
  int* deg    = (int*)ws; ws += NN;
  int* off    = (int*)ws; ws += NN+8;
  int* cursor = (int*)ws; ws += NN;
  int* eidx   = (int*)ws; ws += NE;
  int* snds   = (int*)ws; ws += NE;
  int* rcvs   = (int*)ws; ws += NE;
  unsigned short* qbf   = (unsigned short*)ws;
  unsigned short* kbf   = qbf  + (size_t)NN*HDIM;
  unsigned short* vbf   = kbf  + (size_t)NN*HDIM;
  unsigned short* vecbf = vbf  + (size_t)NN*384;
  unsigned short* WqkvT = vecbf+ (size_t)NN*384;
  unsigned short* WvecT = WqkvT + (size_t)4*640*128;
  unsigned short* WoT   = WvecT + (size_t)4*384*128;
  unsigned short* nbT   = WoT   + (size_t)4*384*128;
  unsigned short* wbT4  = nbT   + (size_t)HDIM*NRBF;

  float* xnb = vdot;

  k_edge_geom<<<(NE+255)/256,256,0,stream>>>(pos,snd,rcv,ew,evec);
  hipMemsetAsync(deg,0,NN*4,stream);
  k_hist<<<NE/256,256,0,stream>>>(rcv,deg);
  k_scan<<<1,1024,0,stream>>>(deg,off,cursor);
  k_scatter<<<NE/256,256,0,stream>>>(rcv,cursor,eidx);
  k_permute<<<NE/256,256,0,stream>>>(eidx,ew,evec,snd,rcv,ews,cw,evs,snds,rcvs);
  k_cvt_nbT<<<(HDIM*NRBF)/256,256,0,stream>>>(nbWd,nbT);
  k_nb_gemm<<<NE/64,256,0,stream>>>(ews,cw,snds,z,embed2,nbT,nbbd,msgc);
  k_nb_sweep<<<NN/8,128,0,stream>>>(off,msgc,xnb);
  k_combine_b<<<NN/16,256,0,stream>>>(z,embed1,xnb,nbWc,nbbc,x);
  hipMemsetAsync(vec,0,(size_t)NN*384*4,stream);
  hipMemsetAsync(vecbf,0,(size_t)NN*384*2,stream);
  k_cvt_qkvT<<<(4*640*128)/256,256,0,stream>>>(Wq,Wk,Wv,WqkvT);
  k_cvtT<<<(4*384*128)/256,256,0,stream>>>(Wvec,WvecT,384);
  k_cvtT<<<(4*384*128)/256,256,0,stream>>>(Wo,WoT,384);
  k_wcvt4<<<(4*512*64)/256,256,0,stream>>>(Wdk,Wdv,wbT4);
  k_bcvt4<<<8,256,0,stream>>>(bdk,bdv,bias4);
  for(int l=0;l<NL;l++){
    k_node_pre_m<<<NN/32,256,0,stream>>>(x,vec,lng,lnb,bq,bk,bv,WqkvT,WvecT,cscale,
                                         qbf,kbf,vbf,vdot,vec3,l);
    hipMemsetAsync(xagg,0,(size_t)NN*HDIM*4,stream);
    hipMemsetAsync(vecagg,0,(size_t)NN*384*4,stream);
    k_edge_fused3<<<NE/32,256,0,stream>>>(ews,cw,evs,snds,rcvs,qbf,kbf,vbf,vecbf,
                                          wbT4 + (size_t)l*512*64, bias4 + l*512,
                                          xagg,vecagg);
    k_node_update_m<<<NN/32,256,0,stream>>>(xagg,vdot,vec3,vecagg,WoT,bo,x,vec,vecbf,l);
  }
  k_final<<<NN,64,0,stream>>>(x,vec,lnfg,lnfb,out);
}